// Round 10
// baseline (276.387 us; speedup 1.0000x reference)
//
#include <hip/hip_runtime.h>
#include <math.h>

#define DIMC 128
#define LSEQ 12288
#define NB 2
#define BLR 24576   // NB*LSEQ
#define EPSV 1e-5f
#define NCH 384     // scan chunks per row
#define LC 32       // chunk length (NCH*LC = LSEQ)
#define KP 132      // LDS row pad (ushorts) for MFMA staging
#define FBP 20      // fbuf row pad (floats, 16B-aligned rows)

typedef __bf16 bf16x8 __attribute__((ext_vector_type(8)));
typedef __attribute__((ext_vector_type(4))) float f4_t;

__device__ __forceinline__ float sigf(float x){ return 1.f/(1.f+__expf(-x)); }
__device__ __forceinline__ float softplusf(float x){
    return fmaxf(x,0.f) + __logf(1.f + __expf(-fabsf(x)));
}
__device__ __forceinline__ float bf2f(unsigned short u){
    union { unsigned int i; float f; } v; v.i = ((unsigned int)u) << 16; return v.f;
}
__device__ __forceinline__ unsigned short f2bf(float f){
    union { float f; unsigned int i; } v; v.f = f;
    unsigned int b = v.i + 0x7FFFu + ((v.i >> 16) & 1u);
    return (unsigned short)(b >> 16);
}
__device__ __forceinline__ bf16x8 ld_frag8(const unsigned short* p){   // 8B-aligned LDS
    union { uint2 u[2]; bf16x8 v; } r;
    r.u[0] = *(const uint2*)(p);
    r.u[1] = *(const uint2*)(p+4);
    return r.v;
}
__device__ __forceinline__ bf16x8 ld_frag16g(const unsigned short* p){ // 16B-aligned global
    union { uint4 u; bf16x8 v; } r; r.u = *(const uint4*)p; return r.v;
}

// a[n] = exp(dtv*Av[n]).  FAST: Av[n] == (n+1)*Av[0] (detected at runtime) ->
// 1 transcendental + 7 muls instead of 8 transcendentals.
template<bool FAST>
__device__ __forceinline__ void comp_a8(float dtv, const float* Av, float* a){
    if (FAST){
        float e1 = __expf(dtv*Av[0]);
        float e2 = e1*e1, e4 = e2*e2;
        a[0]=e1; a[1]=e2; a[2]=e2*e1; a[3]=e4;
        a[4]=e4*e1; a[5]=e4*e2; a[6]=a[5]*e1; a[7]=e4*e4;
    } else {
        #pragma unroll
        for (int n = 0; n < 8; n++) a[n] = __expf(dtv*Av[n]);
    }
}

// ---------------------------------------------------------------- W_all (bf16) + lam + wi/ow->bf16 + LN1 stats
// grid 1152 x 128: [0,576) build wallb; [576,768) convert wi/ow; [768,1152) LN stats -> stt_g.
__global__ __launch_bounds__(128) void k_wall(const float* __restrict__ dtw, const float* __restrict__ xpw,
                       const float* __restrict__ lq, const float* __restrict__ wi, const float* __restrict__ ow,
                       const float* __restrict__ x,
                       unsigned short* __restrict__ wallb, float* __restrict__ lam,
                       unsigned short* __restrict__ wib, unsigned short* __restrict__ owb,
                       float* __restrict__ stt_g){
    __shared__ float red[256];
    int b = blockIdx.x, k = threadIdx.x;
    if (b < 576){
        int inst = b & 3, j = b >> 2;
        const float* xp = xpw + (size_t)inst*24*128;
        float v;
        if (j < 128){
            const float* dw = dtw + (size_t)inst*128*8 + (size_t)j*8;
            v = 0.f;
            #pragma unroll
            for (int r = 0; r < 8; r++) v += dw[r]*xp[r*128 + k];
        } else {
            v = xp[(8 + (j-128))*128 + k];
        }
        wallb[((size_t)inst*144 + j)*128 + k] = f2bf(v);
        if (b == 0 && k < 64){
            float s = lq[k] + lq[k+64];
            for (int m = 32; m; m >>= 1) s += __shfl_xor(s, m);
            if (k == 0) *lam = 1.f/(1.f+__expf(-s));
        }
    } else if (b < 768){
        int idx = ((b-576)*128 + k)*4;   // 192 blocks -> 98304 elems
        const float* src; unsigned short* dst; int off;
        if (idx < 65536){ src = wi;  dst = wib; off = idx; }
        else            { src = ow;  dst = owb; off = idx - 65536; }
        float4 v = *(const float4*)&src[off];
        ushort4 o; o.x=f2bf(v.x); o.y=f2bf(v.y); o.z=f2bf(v.z); o.w=f2bf(v.w);
        *(ushort4*)&dst[off] = o;
    } else {
        // LN1 stats for 64 rows: t in [0,384), bb = t/192, l0 = (t%192)*64
        int t = b - 768;
        int bb = t / 192, l0 = (t % 192) * 64;
        int li = k & 63, cg = k >> 6;   // cg in {0,1}
        const float* xb = x + (size_t)bb*DIMC*LSEQ + l0 + li;
        float s = 0.f, s2 = 0.f;
        #pragma unroll
        for (int p = 0; p < 64; p++){
            float v = xb[(size_t)(p*2 + cg)*LSEQ];
            s += v; s2 += v*v;
        }
        red[cg*64 + li] = s; red[128 + cg*64 + li] = s2;
        __syncthreads();
        if (k < 64){
            float ss  = red[k]       + red[64 + k];
            float ss2 = red[128 + k] + red[192 + k];
            float mu = ss*(1.f/128.f);
            float var = ss2*(1.f/128.f) - mu*mu;
            size_t o = (size_t)(bb*LSEQ + l0 + k)*2;
            stt_g[o]   = mu;
            stt_g[o+1] = rsqrtf(var + EPSV);
        }
    }
}

// ---------------------------------------------------------------- FUSED: LN1-normalize + transpose + in_proj MFMA
// Stats precomputed in k_wall (stt_g) -> single normalize pass, no reductions.
__global__ __launch_bounds__(256,4) void k_inproj(const float* __restrict__ x,
    const float* __restrict__ w1, const float* __restrict__ b1, const float* __restrict__ stt_g,
    const unsigned short* __restrict__ wib, unsigned short* __restrict__ xz)
{
    __shared__ __align__(16) unsigned short As[64*KP];   // 16896 B
    const int row0 = blockIdx.x * 64;   // grid.x = 384  (row0 == bb*LSEQ + l0)
    const int bb = blockIdx.x / 192;
    const int l0 = (blockIdx.x % 192) * 64;
    const int j0 = blockIdx.y * 128;    // grid.y = 4
    const int tid = threadIdx.x;
    const int li = tid & 63, cg = tid >> 6;
    const float* xb = x + (size_t)bb*DIMC*LSEQ + l0 + li;
    {
        float2 st2 = *(const float2*)&stt_g[(size_t)(row0 + li)*2];
        float mu = st2.x, rs = st2.y;
        #pragma unroll
        for (int p = 0; p < 32; p++){
            int c = p*4 + cg;
            float v = (xb[(size_t)c*LSEQ] - mu)*rs*w1[c] + b1[c];
            As[li*KP + c] = f2bf(v);
        }
    }
    __syncthreads();
    // ---- GEMM
    const int lane = tid & 63, w = tid >> 6;
    const int m15 = lane & 15, q = lane >> 4;
    const unsigned short* wb = wib + ((size_t)j0 + m15)*DIMC + q*8;
    bf16x8 bc[8], bn[8];
    #pragma unroll
    for (int nt = 0; nt < 8; nt++) bc[nt] = ld_frag16g(wb + nt*2048);
    f4_t zf = {0.f,0.f,0.f,0.f};
    f4_t acc[8];
    #pragma unroll
    for (int j = 0; j < 8; j++) acc[j] = zf;
    #pragma unroll
    for (int ks = 0; ks < 4; ks++){
        if (ks < 3){
            #pragma unroll
            for (int nt = 0; nt < 8; nt++) bn[nt] = ld_frag16g(wb + nt*2048 + (ks+1)*32);
        }
        bf16x8 a0 = ld_frag8(&As[(w*16 + m15)*KP + ks*32 + q*8]);
        #pragma unroll
        for (int nt = 0; nt < 8; nt++)
            acc[nt] = __builtin_amdgcn_mfma_f32_16x16x32_bf16(a0, bc[nt], acc[nt], 0,0,0);
        #pragma unroll
        for (int nt = 0; nt < 8; nt++) bc[nt] = bn[nt];
    }
    __syncthreads();
    unsigned short* ep = As;             // reuse
    #pragma unroll
    for (int nt = 0; nt < 8; nt++){
        int row = w*16 + q*4;
        int col = nt*16 + m15;
        #pragma unroll
        for (int i = 0; i < 4; i++)
            ep[(row+i)*KP + col] = f2bf(acc[nt][i]);
    }
    __syncthreads();
    #pragma unroll
    for (int p = 0; p < 4; p++){
        int idx = p*256 + tid; int li2 = idx >> 4; int g = (idx & 15)*8;
        uint2 u0 = *(const uint2*)&ep[li2*KP + g];
        uint2 u1 = *(const uint2*)&ep[li2*KP + g + 4];
        uint4 o; o.x=u0.x; o.y=u0.y; o.z=u1.x; o.w=u1.y;
        *(uint4*)&xz[(size_t)(row0+li2)*512 + j0 + g] = o;
    }
}

// ---------------------------------------------------------------- fused scan-chunk reduce (reads LDS only)
// 1-deep software pipeline: step s+1's LDS operands loaded before step s compute.
template<bool FAST>
__device__ __forceinline__ void fscan(const unsigned short* __restrict__ As,
    const unsigned short* __restrict__ Ep, const float* __restrict__ fbuf,
    const float* Av, int ch, int d, int dim, float* Ac, float* Bc)
{
    float dts = 0.f;
    int r0 = ch*32 + (d ? 31 : 0);
    float dtv = bf2f(Ep[r0*KP + dim]);
    float uv  = bf2f(As[r0*KP + dim]);
    float4 b0 = *(const float4*)&fbuf[r0*FBP];
    float4 b1 = *(const float4*)&fbuf[r0*FBP + 4];
    #pragma unroll 8
    for (int s = 0; s < LC; s++){
        float dtc = dtv, uvc = uv;
        float4 b0c = b0, b1c = b1;
        if (s+1 < LC){
            int rn = ch*32 + (d ? 31-(s+1) : (s+1));
            dtv = bf2f(Ep[rn*KP + dim]);
            uv  = bf2f(As[rn*KP + dim]);
            b0  = *(const float4*)&fbuf[rn*FBP];
            b1  = *(const float4*)&fbuf[rn*FBP + 4];
        }
        float bv[8] = {b0c.x,b0c.y,b0c.z,b0c.w,b1c.x,b1c.y,b1c.z,b1c.w};
        float du = dtc*uvc;
        float a[8];
        comp_a8<FAST>(dtc, Av, a);
        #pragma unroll
        for (int n = 0; n < 8; n++)
            Bc[n] = a[n]*Bc[n] + du*bv[n];
        dts += dtc;
    }
    comp_a8<FAST>(dts, Av, Ac);
}

// ---------------------------------------------------------------- FUSED: conv+silu -> x_proj MFMA -> scan S1
__global__ __launch_bounds__(256,4) void k_xproj(const unsigned short* __restrict__ xz,
    const unsigned short* __restrict__ wallb, const float* __restrict__ dtb,
    const float* __restrict__ alog, const float* __restrict__ cw, const float* __restrict__ cbv,
    unsigned short* __restrict__ xc, unsigned short* __restrict__ dty,
    float* __restrict__ bcb, float* __restrict__ st)
{
    __shared__ __align__(16) unsigned short As[64*KP];   // 16896 B (u, stays intact)
    __shared__ __align__(16) unsigned short Zb[67*KP];   // 17688 B (xz halo tile; later Ep)
    __shared__ __align__(16) float fbuf[64*FBP];         //  5120 B (B,C f32)
    const int row0 = blockIdx.x * 64;    // grid.x = 192
    const int ib   = blockIdx.y;         // 0..7
    const int inst = ib >> 1;
    const int bb   = ib & 1;
    const int m    = inst >> 1;
    const int d    = inst & 1;
    const int tid = threadIdx.x;
    const size_t abase = (size_t)ib * LSEQ * DIMC;
    const int lane = tid & 63, w = tid >> 6;
    const int m15 = lane & 15, q = lane >> 4;
    const unsigned short* wb = wallb + ((size_t)inst*144 + m15)*DIMC + q*8;
    bf16x8 bc[9], bn[9];
    #pragma unroll
    for (int nt = 0; nt < 9; nt++) bc[nt] = ld_frag16g(wb + nt*2048);
    // ---- stage xz halo tile: rows [start, start+67)
    const int start = row0 - (d ? 0 : 3);
    for (int idx = tid; idx < 67*16; idx += 256){
        int r = idx >> 4, cq = idx & 15;
        int l = start + r;
        uint4 v = make_uint4(0,0,0,0);
        if (l >= 0 && l < LSEQ)
            v = *(const uint4*)&xz[((size_t)(bb*LSEQ + l))*512 + m*256 + cq*8];
        *(uint4*)&Zb[r*KP + cq*8] = v;
    }
    __syncthreads();
    // ---- conv + silu -> As, rolling window (li = lg*32 + p): 35 LDS reads not 128
    {
        const int dimi = tid & 127, lg = tid >> 7;
        float wk[4];
        #pragma unroll
        for (int k = 0; k < 4; k++){
            int kk = d ? 3-k : k;
            wk[k] = cw[((size_t)inst*DIMC + dimi)*4 + kk];
        }
        const float bsv = cbv[inst*DIMC + dimi];
        const int base = lg*32;
        float t0 = bf2f(Zb[(base  )*KP + dimi]);
        float t1 = bf2f(Zb[(base+1)*KP + dimi]);
        float t2 = bf2f(Zb[(base+2)*KP + dimi]);
        for (int p = 0; p < 32; p++){
            int li = base + p;
            float t3 = bf2f(Zb[(li+3)*KP + dimi]);
            float v = bsv + wk[0]*t0 + wk[1]*t1 + wk[2]*t2 + wk[3]*t3;
            v = v * sigf(v);
            As[li*KP + dimi] = f2bf(v);
            t0 = t1; t1 = t2; t2 = t3;
        }
    }
    __syncthreads();        // As ready; all Zb reads done (Ep alias safe after this)
    // coalesced xc store from As (fire-and-forget ahead of GEMM)
    #pragma unroll
    for (int p = 0; p < 4; p++){
        int idx = p*256 + tid; int li = idx >> 4; int g = (idx & 15)*8;
        uint2 u0 = *(const uint2*)&As[li*KP + g];
        uint2 u1 = *(const uint2*)&As[li*KP + g + 4];
        uint4 o; o.x=u0.x; o.y=u0.y; o.z=u1.x; o.w=u1.y;
        *(uint4*)&xc[abase + (size_t)(row0+li)*DIMC + g] = o;
    }
    f4_t zf = {0.f,0.f,0.f,0.f};
    f4_t acc[9];
    #pragma unroll
    for (int j = 0; j < 9; j++) acc[j] = zf;
    #pragma unroll
    for (int ks = 0; ks < 4; ks++){
        if (ks < 3){
            #pragma unroll
            for (int nt = 0; nt < 9; nt++) bn[nt] = ld_frag16g(wb + nt*2048 + (ks+1)*32);
        }
        bf16x8 a0 = ld_frag8(&As[(w*16 + m15)*KP + ks*32 + q*8]);
        #pragma unroll
        for (int nt = 0; nt < 9; nt++)
            acc[nt] = __builtin_amdgcn_mfma_f32_16x16x32_bf16(a0, bc[nt], acc[nt], 0,0,0);
        #pragma unroll
        for (int nt = 0; nt < 9; nt++) bc[nt] = bn[nt];
    }
    // stage B/C (acc[8]) -> fbuf ; dt (softplus) -> Ep (aliases Zb).
    unsigned short* Ep = Zb;
    {
        int row = w*16 + q*4;
        #pragma unroll
        for (int i = 0; i < 4; i++)
            fbuf[(row+i)*FBP + m15] = acc[8][i];
    }
    #pragma unroll
    for (int nt = 0; nt < 8; nt++){
        int col = nt*16 + m15;
        float bias = dtb[inst*DIMC + col];
        int row = w*16 + q*4;
        #pragma unroll
        for (int i = 0; i < 4; i++)
            Ep[(row+i)*KP + col] = f2bf(softplusf(acc[nt][i] + bias));
    }
    __syncthreads();
    {   // coalesced bcb store
        int row = tid >> 2, j = (tid & 3)*4;
        float4 v = { fbuf[row*FBP + j], fbuf[row*FBP + j + 1],
                     fbuf[row*FBP + j + 2], fbuf[row*FBP + j + 3] };
        *(float4*)&bcb[((size_t)ib*LSEQ + row0 + row)*16 + j] = v;
    }
    #pragma unroll
    for (int p = 0; p < 4; p++){   // dty store from Ep
        int idx = p*256 + tid; int li = idx >> 4; int g = (idx & 15)*8;
        uint2 u0 = *(const uint2*)&Ep[li*KP + g];
        uint2 u1 = *(const uint2*)&Ep[li*KP + g + 4];
        uint4 o; o.x=u0.x; o.y=u0.y; o.z=u1.x; o.w=u1.y;
        *(uint4*)&dty[abase + (size_t)(row0+li)*DIMC + g] = o;
    }
    // ---- fused scan stage 1: thread = (chunk-half, dim)
    const int ch  = tid >> 7;            // 0..1
    const int dim = tid & 127;
    const int bc2 = row0 >> 5;
    const int c   = d ? (NCH-1 - bc2 - ch) : (bc2 + ch);
    float Av[8];
    #pragma unroll
    for (int n = 0; n < 8; n++)
        Av[n] = -__expf(alog[((size_t)inst*DIMC + dim)*8 + n]);
    bool fast = true;
    #pragma unroll
    for (int n = 1; n < 8; n++)
        fast = fast && (fabsf(Av[n] - (float)(n+1)*Av[0]) <= 1e-5f*fabsf(Av[n]));
    float Ac[8], Bc[8];
    #pragma unroll
    for (int n = 0; n < 8; n++){ Ac[n] = 1.f; Bc[n] = 0.f; }
    if (fast) fscan<true >(As, Ep, fbuf, Av, ch, d, dim, Ac, Bc);
    else      fscan<false>(As, Ep, fbuf, Av, ch, d, dim, Ac, Bc);
    float* so = st + (((size_t)ib*NCH + c)*DIMC + dim)*16;
    float4 s0 = {Ac[0],Ac[1],Ac[2],Ac[3]};
    float4 s1 = {Ac[4],Ac[5],Ac[6],Ac[7]};
    float4 s2 = {Bc[0],Bc[1],Bc[2],Bc[3]};
    float4 s3 = {Bc[4],Bc[5],Bc[6],Bc[7]};
    *(float4*)&so[0]  = s0;
    *(float4*)&so[4]  = s1;
    *(float4*)&so[8]  = s2;
    *(float4*)&so[12] = s3;
}

// ---------------------------------------------------------------- scan S2 (cross-chunk exclusive prefix, in-place)
__global__ __launch_bounds__(512) void k_scan2(float* __restrict__ st){
    const int ib   = blockIdx.x >> 7;          // grid = 8*128 = 1024
    const int dim  = blockIdx.x & 127;
    const int n    = threadIdx.x >> 6;         // wave index = state index
    const int lane = threadIdx.x & 63;
    const size_t cstride = (size_t)DIMC*16;
    const size_t base = ((size_t)ib*NCH*DIMC + dim)*16 + n;
    float a[6], b[6];
    float Al = 1.f, Bl = 0.f;
    #pragma unroll
    for (int j = 0; j < 6; j++){
        size_t o = base + (size_t)(lane*6 + j)*cstride;
        float A  = st[o];
        float Bv = st[o + 8];
        a[j] = A; b[j] = Bv;
        Bl = A*Bl + Bv;
        Al *= A;
    }
    #pragma unroll
    for (int off = 1; off < 64; off <<= 1){
        float Ao = __shfl_up(Al, off, 64);
        float Bo = __shfl_up(Bl, off, 64);
        if (lane >= off){
            Bl = Al*Bo + Bl;
            Al = Al*Ao;
        }
    }
    float h = __shfl_up(Bl, 1, 64);            // exclusive carry
    if (lane == 0) h = 0.f;
    #pragma unroll
    for (int j = 0; j < 6; j++){
        size_t o = base + (size_t)(lane*6 + j)*cstride;
        st[o] = h;
        h = a[j]*h + b[j];
    }
}

// ---------------------------------------------------------------- scan S3 (replay, y in place over dt)
// 1-deep software pipeline: step s+1's LDS operands loaded before step s compute.
template<bool FAST>
__device__ __forceinline__ void scan3_body(unsigned short* __restrict__ dty,
    const unsigned short* __restrict__ sdt, const unsigned short* __restrict__ sxc,
    const unsigned short* __restrict__ sz, const float* __restrict__ sbc,
    const float* Av, float Dv, float* h,
    size_t rbase, size_t lbase, int d, int tid)
{
    int r0 = d ? 31 : 0;
    float dtv = bf2f(sdt[r0*128 + tid]);
    float uv  = bf2f(sxc[r0*128 + tid]);
    float zv  = bf2f(sz [r0*128 + tid]);
    float4 bA = *(const float4*)&sbc[r0*16];
    float4 bB = *(const float4*)&sbc[r0*16 + 4];
    float4 cA = *(const float4*)&sbc[r0*16 + 8];
    float4 cB = *(const float4*)&sbc[r0*16 + 12];
    int rc = r0;
    #pragma unroll 8
    for (int s = 0; s < LC; s++){
        float dtc = dtv, uvc = uv, zvc = zv;
        float4 bAc = bA, bBc = bB, cAc = cA, cBc = cB;
        int rr = rc;
        if (s+1 < LC){
            int rn = d ? 31-(s+1) : (s+1);
            dtv = bf2f(sdt[rn*128 + tid]);
            uv  = bf2f(sxc[rn*128 + tid]);
            zv  = bf2f(sz [rn*128 + tid]);
            bA  = *(const float4*)&sbc[rn*16];
            bB  = *(const float4*)&sbc[rn*16 + 4];
            cA  = *(const float4*)&sbc[rn*16 + 8];
            cB  = *(const float4*)&sbc[rn*16 + 12];
            rc = rn;
        }
        float bv[8] = {bAc.x,bAc.y,bAc.z,bAc.w,bBc.x,bBc.y,bBc.z,bBc.w};
        float cv[8] = {cAc.x,cAc.y,cAc.z,cAc.w,cBc.x,cBc.y,cBc.z,cBc.w};
        float du = dtc*uvc;
        float y = uvc*Dv;
        float a[8];
        comp_a8<FAST>(dtc, Av, a);
        #pragma unroll
        for (int n = 0; n < 8; n++){
            h[n] = a[n]*h[n] + du*bv[n];
            y += h[n]*cv[n];
        }
        y *= zvc * sigf(zvc);
        dty[rbase + (lbase + rr)*DIMC + tid] = f2bf(y);
    }
}

__global__ __launch_bounds__(128) void k_scan3(unsigned short* __restrict__ dty,
    const unsigned short* __restrict__ xc, const float* __restrict__ bcb,
    const unsigned short* __restrict__ xz, const float* __restrict__ st,
    const float* __restrict__ alog, const float* __restrict__ dvec)
{
    __shared__ __align__(16) unsigned short sdt[32*128];   // 8 KB
    __shared__ __align__(16) unsigned short sxc[32*128];   // 8 KB
    __shared__ __align__(16) unsigned short sz [32*128];   // 8 KB
    __shared__ __align__(16) float sbc[32*16];             // 2 KB
    const int ib = blockIdx.x & 7;
    const int c  = blockIdx.x >> 3;
    const int inst = ib >> 1, bb = ib & 1;
    const int m = inst >> 1, d = inst & 1;
    const int tid = threadIdx.x;
    const size_t rbase = (size_t)ib*LSEQ*DIMC;
    const size_t zbase = (size_t)bb*LSEQ*512 + m*256 + 128;
    const size_t lbase = d ? (size_t)(LSEQ - 32 - c*32) : (size_t)(c*32);
    #pragma unroll
    for (int p = 0; p < 4; p++){
        int idx = p*128 + tid;          // 512 uint4 per 8KB array
        int r = idx >> 4, g = (idx & 15)*8;
        size_t go = rbase + (lbase + r)*DIMC + g;
        *(uint4*)&sdt[r*128 + g] = *(const uint4*)&dty[go];
        *(uint4*)&sxc[r*128 + g] = *(const uint4*)&xc[go];
        *(uint4*)&sz [r*128 + g] = *(const uint4*)&xz[zbase + (lbase + r)*512 + g];
    }
    {   // bcb: 2KB = 128 x float4
        int r = tid >> 2, j = (tid & 3)*4;
        *(float4*)&sbc[r*16 + j] = *(const float4*)&bcb[((size_t)ib*LSEQ + lbase + r)*16 + j];
    }
    float Av[8];
    #pragma unroll
    for (int n = 0; n < 8; n++)
        Av[n] = -__expf(alog[((size_t)inst*DIMC + tid)*8 + n]);
    bool fast = true;
    #pragma unroll
    for (int n = 1; n < 8; n++)
        fast = fast && (fabsf(Av[n] - (float)(n+1)*Av[0]) <= 1e-5f*fabsf(Av[n]));
    const float Dv = dvec[inst*DIMC + tid];
    float h[8];
    const float* hp = st + (((size_t)ib*NCH + c)*DIMC + tid)*16;
    #pragma unroll
    for (int n = 0; n < 8; n++) h[n] = hp[n];
    __syncthreads();
    if (fast) scan3_body<true >(dty, sdt, sxc, sz, sbc, Av, Dv, h, rbase, lbase, d, tid);
    else      scan3_body<false>(dty, sdt, sxc, sz, sbc, Av, Dv, h, rbase, lbase, d, tid);
}

// ---------------------------------------------------------------- out_proj MFMA + diff + LN + add x + LN + T-store
__global__ __launch_bounds__(256,4) void k_final(const unsigned short* __restrict__ y,
    const unsigned short* __restrict__ owb, const float* __restrict__ x, const float* __restrict__ lamp,
    const float* __restrict__ sw, const float* __restrict__ sb,
    const float* __restrict__ n2w, const float* __restrict__ n2b, float* __restrict__ outp)
{
    __shared__ __align__(16) char smem[36352];
    unsigned short* Ast = (unsigned short*)smem;             // phase 1: [2*64][KP] = 33792 B
    float* yt            = (float*)smem;                     // phase 2: [64][129] f32 = 33024 B (aliases Ast)
    float* red1          = (float*)(smem + 33792);           // 1024 B
    float* red2          = (float*)(smem + 34816);           // 1024 B
    float* stt           = (float*)(smem + 35840);           //  512 B
    const int bb = blockIdx.y;
    const int l0 = blockIdx.x * 64;                  // grid.x = 192
    const int tid = threadIdx.x;
    const float lam = *lamp;
    #pragma unroll
    for (int p = 0; p < 8; p++){
        int idx = p*256 + tid; int mm = idx >> 10; int li = (idx >> 4) & 63; int g = (idx & 15)*8;
        uint4 vf = *(const uint4*)&y[(((size_t)(mm*2+0)*NB + bb)*LSEQ + l0 + li)*DIMC + g];
        uint4 vb = *(const uint4*)&y[(((size_t)(mm*2+1)*NB + bb)*LSEQ + l0 + li)*DIMC + g];
        const unsigned short* uf = (const unsigned short*)&vf;
        const unsigned short* ub = (const unsigned short*)&vb;
        unsigned short o[8];
        #pragma unroll
        for (int j = 0; j < 8; j++) o[j] = f2bf(bf2f(uf[j]) + bf2f(ub[j]));
        *(uint2*)&Ast[(mm*64 + li)*KP + g]     = *(uint2*)&o[0];
        *(uint2*)&Ast[(mm*64 + li)*KP + g + 4] = *(uint2*)&o[4];
    }
    __syncthreads();
    const int lane = tid & 63, w = tid >> 6;
    const int m15 = lane & 15, q = lane >> 4;
    f4_t zf = {0.f,0.f,0.f,0.f};
    f4_t acc[2][8];
    #pragma unroll
    for (int i = 0; i < 2; i++)
        #pragma unroll
        for (int j = 0; j < 8; j++) acc[i][j] = zf;
    #pragma unroll
    for (int ks = 0; ks < 4; ks++){
        int k0 = ks*32 + q*8;
        bf16x8 a0 = ld_frag8(&Ast[(       w*16 + m15)*KP + k0]);
        bf16x8 a1 = ld_frag8(&Ast[(64   + w*16 + m15)*KP + k0]);
        #pragma unroll
        for (int nt = 0; nt < 8; nt++){
            bf16x8 b0 = ld_frag16g(&owb[((size_t)0*DIMC + nt*16 + m15)*DIMC + k0]);
            bf16x8 b1 = ld_frag16g(&owb[((size_t)1*DIMC + nt*16 + m15)*DIMC + k0]);
            acc[0][nt] = __builtin_amdgcn_mfma_f32_16x16x32_bf16(a0, b0, acc[0][nt], 0,0,0);
            acc[1][nt] = __builtin_amdgcn_mfma_f32_16x16x32_bf16(a1, b1, acc[1][nt], 0,0,0);
        }
    }
    __syncthreads();
    #pragma unroll
    for (int nt = 0; nt < 8; nt++){
        int row = w*16 + q*4;
        int col = nt*16 + m15;
        #pragma unroll
        for (int i = 0; i < 4; i++)
            yt[(row+i)*129 + col] = acc[0][nt][i] - lam*acc[1][nt][i];
    }
    __syncthreads();
    const int r = tid & 63, g = tid >> 6;
    float s = 0.f, s2 = 0.f;
    #pragma unroll
    for (int k = 0; k < 32; k++){ float v = yt[r*129 + g*32 + k]; s += v; s2 += v*v; }
    red1[g*64 + r] = s; red2[g*64 + r] = s2;
    __syncthreads();
    if (tid < 64){
        float ss = 0.f, ss2 = 0.f;
        #pragma unroll
        for (int gg = 0; gg < 4; gg++){ ss += red1[gg*64 + tid]; ss2 += red2[gg*64 + tid]; }
        float mu = ss*(1.f/128.f);
        float var = ss2*(1.f/128.f) - mu*mu;
        stt[tid*2] = mu; stt[tid*2+1] = rsqrtf(var + EPSV);
    }
    __syncthreads();
    float mu1 = stt[r*2], rs1 = stt[r*2+1];
    s = 0.f; s2 = 0.f;
    #pragma unroll
    for (int k = 0; k < 32; k++){
        int c = g*32 + k;
        float v = (yt[r*129+c] - mu1)*rs1*sw[c] + sb[c]
                + x[(size_t)bb*DIMC*LSEQ + (size_t)c*LSEQ + l0 + r];
        yt[r*129+c] = v;
        s += v; s2 += v*v;
    }
    __syncthreads();
    red1[g*64 + r] = s; red2[g*64 + r] = s2;
    __syncthreads();
    if (tid < 64){
        float ss = 0.f, ss2 = 0.f;
        #pragma unroll
        for (int gg = 0; gg < 4; gg++){ ss += red1[gg*64 + tid]; ss2 += red2[gg*64 + tid]; }
        float mu = ss*(1.f/128.f);
        float var = ss2*(1.f/128.f) - mu*mu;
        stt[tid*2] = mu; stt[tid*2+1] = rsqrtf(var + EPSV);
    }
    __syncthreads();
    float mu2 = stt[r*2], rs2 = stt[r*2+1];
    #pragma unroll
    for (int k = 0; k < 32; k++){
        int c = g*32 + k;
        float o = (yt[r*129+c] - mu2)*rs2*n2w[c] + n2b[c];
        outp[(size_t)bb*DIMC*LSEQ + (size_t)c*LSEQ + l0 + r] = o;
    }
}

// ----------------------------------------------------------------
extern "C" void kernel_launch(void* const* d_in, const int* in_sizes, int n_in,
                              void* d_out, int out_size, void* d_ws, size_t ws_size,
                              hipStream_t stream)
{
    const float* x    = (const float*)d_in[0];
    const float* n1w  = (const float*)d_in[1];
    const float* n1b  = (const float*)d_in[2];
    const float* n2w  = (const float*)d_in[3];
    const float* n2b  = (const float*)d_in[4];
    const float* slw  = (const float*)d_in[5];
    const float* slb  = (const float*)d_in[6];
    const float* lq   = (const float*)d_in[7];
    const float* wi   = (const float*)d_in[8];
    const float* cw   = (const float*)d_in[9];
    const float* cb   = (const float*)d_in[10];
    const float* xpw  = (const float*)d_in[11];
    const float* dtw  = (const float*)d_in[12];
    const float* dtb  = (const float*)d_in[13];
    const float* alog = (const float*)d_in[14];
    const float* dvec = (const float*)d_in[15];
    const float* ow   = (const float*)d_in[16];

    float* ws = (float*)d_ws;
    float*          sttg  = ws;                                //    49,152 f (BLR*2)
    unsigned short* xz    = (unsigned short*)(ws + 1572864);   // 6,291,456 f
    unsigned short* xc    = (unsigned short*)(ws + 7864320);   // 6,291,456 f
    unsigned short* dty   = (unsigned short*)(ws + 14155776);  // 6,291,456 f
    float*          bcb   = ws + 20447232;                     // 1,572,864 f
    float*          st1   = ws + 22020096;                     // 6,291,456 f (8*NCH*128*16)
    unsigned short* wallb = (unsigned short*)(ws + 28311552);  //    36,864 f
    unsigned short* wib   = (unsigned short*)(ws + 28348416);  //    32,768 f
    unsigned short* owb   = (unsigned short*)(ws + 28381184);  //    16,384 f
    float*          lam   = ws + 28397568;                     //         1

    k_wall  <<<1152, 128, 0, stream>>>(dtw, xpw, lq, wi, ow, x, wallb, lam, wib, owb, sttg);
    k_inproj<<<dim3(384, 4), 256, 0, stream>>>(x, n1w, n1b, sttg, wib, xz);
    k_xproj <<<dim3(192, 8), 256, 0, stream>>>(xz, wallb, dtb, alog, cw, cb, xc, dty, bcb, st1);
    k_scan2 <<<1024, 512, 0, stream>>>(st1);
    k_scan3 <<<8*NCH, 128, 0, stream>>>(dty, xc, bcb, xz, st1, alog, dvec);
    k_final <<<dim3(192, 2), 256, 0, stream>>>(dty, owb, x, lam, slw, slb, n2w, n2b, (float*)d_out);
}

// Round 11
// 270.294 us; speedup vs baseline: 1.0225x; 1.0225x over previous
//
#include <hip/hip_runtime.h>
#include <math.h>

#define DIMC 128
#define LSEQ 12288
#define NB 2
#define BLR 24576   // NB*LSEQ
#define EPSV 1e-5f
#define NCH 384     // scan chunks per row
#define LC 32       // chunk length (NCH*LC = LSEQ)
#define KP 132      // LDS row pad (ushorts) for MFMA staging
#define FBP 20      // fbuf row pad (floats, 16B-aligned rows)

typedef __bf16 bf16x8 __attribute__((ext_vector_type(8)));
typedef __attribute__((ext_vector_type(4))) float f4_t;

__device__ __forceinline__ float sigf(float x){ return 1.f/(1.f+__expf(-x)); }
__device__ __forceinline__ float softplusf(float x){
    return fmaxf(x,0.f) + __logf(1.f + __expf(-fabsf(x)));
}
__device__ __forceinline__ float bf2f(unsigned short u){
    union { unsigned int i; float f; } v; v.i = ((unsigned int)u) << 16; return v.f;
}
__device__ __forceinline__ unsigned short f2bf(float f){
    union { float f; unsigned int i; } v; v.f = f;
    unsigned int b = v.i + 0x7FFFu + ((v.i >> 16) & 1u);
    return (unsigned short)(b >> 16);
}
__device__ __forceinline__ bf16x8 ld_frag8(const unsigned short* p){   // 8B-aligned LDS
    union { uint2 u[2]; bf16x8 v; } r;
    r.u[0] = *(const uint2*)(p);
    r.u[1] = *(const uint2*)(p+4);
    return r.v;
}
__device__ __forceinline__ bf16x8 ld_frag16g(const unsigned short* p){ // 16B-aligned global
    union { uint4 u; bf16x8 v; } r; r.u = *(const uint4*)p; return r.v;
}

// a[n] = exp(dtv*Av[n]).  FAST: Av[n] == (n+1)*Av[0] (detected at runtime) ->
// 1 transcendental + 7 muls instead of 8 transcendentals.
template<bool FAST>
__device__ __forceinline__ void comp_a8(float dtv, const float* Av, float* a){
    if (FAST){
        float e1 = __expf(dtv*Av[0]);
        float e2 = e1*e1, e4 = e2*e2;
        a[0]=e1; a[1]=e2; a[2]=e2*e1; a[3]=e4;
        a[4]=e4*e1; a[5]=e4*e2; a[6]=a[5]*e1; a[7]=e4*e4;
    } else {
        #pragma unroll
        for (int n = 0; n < 8; n++) a[n] = __expf(dtv*Av[n]);
    }
}

// ---------------------------------------------------------------- W_all (bf16) + lam + wi/ow->bf16 (merged)
// grid 768 x 128: blocks [0,576) build wallb; [576,768) convert wi/ow.
__global__ __launch_bounds__(128) void k_wall(const float* __restrict__ dtw, const float* __restrict__ xpw,
                       const float* __restrict__ lq, const float* __restrict__ wi, const float* __restrict__ ow,
                       unsigned short* __restrict__ wallb, float* __restrict__ lam,
                       unsigned short* __restrict__ wib, unsigned short* __restrict__ owb){
    int b = blockIdx.x, k = threadIdx.x;
    if (b < 576){
        int inst = b & 3, j = b >> 2;
        const float* xp = xpw + (size_t)inst*24*128;
        float v;
        if (j < 128){
            const float* dw = dtw + (size_t)inst*128*8 + (size_t)j*8;
            v = 0.f;
            #pragma unroll
            for (int r = 0; r < 8; r++) v += dw[r]*xp[r*128 + k];
        } else {
            v = xp[(8 + (j-128))*128 + k];
        }
        wallb[((size_t)inst*144 + j)*128 + k] = f2bf(v);
        if (b == 0 && k < 64){
            float s = lq[k] + lq[k+64];
            for (int m = 32; m; m >>= 1) s += __shfl_xor(s, m);
            if (k == 0) *lam = 1.f/(1.f+__expf(-s));
        }
    } else {
        int idx = ((b-576)*128 + k)*4;   // 192 blocks -> 98304 elems
        const float* src; unsigned short* dst; int off;
        if (idx < 65536){ src = wi;  dst = wib; off = idx; }
        else            { src = ow;  dst = owb; off = idx - 65536; }
        float4 v = *(const float4*)&src[off];
        ushort4 o; o.x=f2bf(v.x); o.y=f2bf(v.y); o.z=f2bf(v.z); o.w=f2bf(v.w);
        *(ushort4*)&dst[off] = o;
    }
}

// ---------------------------------------------------------------- FUSED: LN1 + transpose + in_proj MFMA (2-pass N)
// grid (384,2): each block stages+normalizes the A-tile ONCE, then runs two
// sequential 128-col GEMM passes (jj = j0, j0+128) reusing As. Halves the
// redundant LN/staging work vs the old (384,4) layout. Epilogue uses a separate
// ep buffer so As survives pass 2. LDS 36.2KB -> 4 blocks/CU.
__global__ __launch_bounds__(256,4) void k_inproj(const float* __restrict__ x,
    const float* __restrict__ w1, const float* __restrict__ b1,
    const unsigned short* __restrict__ wib, unsigned short* __restrict__ xz)
{
    __shared__ __align__(16) unsigned short As[64*KP];   // 16896 B
    __shared__ __align__(16) unsigned short ep[64*KP];   // 16896 B
    __shared__ float red1[256], red2[256];
    __shared__ float stt[128];
    const int row0 = blockIdx.x * 64;   // grid.x = 384  (row0 == bb*LSEQ + l0)
    const int bb = blockIdx.x / 192;
    const int l0 = (blockIdx.x % 192) * 64;
    const int j0 = blockIdx.y * 256;    // grid.y = 2
    const int tid = threadIdx.x;
    const int li = tid & 63, cg = tid >> 6;
    const float* xb = x + (size_t)bb*DIMC*LSEQ + l0 + li;
    // pass 1: stats (coalesced, values discarded)
    {
        float s = 0.f, s2 = 0.f;
        #pragma unroll
        for (int p = 0; p < 32; p++){
            float v = xb[(size_t)(p*4 + cg)*LSEQ];
            s += v; s2 += v*v;
        }
        red1[cg*64 + li] = s; red2[cg*64 + li] = s2;
    }
    __syncthreads();
    if (tid < 64){
        float ss = 0.f, ss2 = 0.f;
        #pragma unroll
        for (int g = 0; g < 4; g++){ ss += red1[g*64 + tid]; ss2 += red2[g*64 + tid]; }
        float mu = ss*(1.f/128.f);
        float var = ss2*(1.f/128.f) - mu*mu;
        stt[tid*2] = mu; stt[tid*2+1] = rsqrtf(var + EPSV);
    }
    __syncthreads();
    // pass 2: re-read (cache-hot), normalize, write As bf16
    {
        float mu = stt[li*2], rs = stt[li*2+1];
        #pragma unroll
        for (int p = 0; p < 32; p++){
            int c = p*4 + cg;
            float v = (xb[(size_t)c*LSEQ] - mu)*rs*w1[c] + b1[c];
            As[li*KP + c] = f2bf(v);
        }
    }
    __syncthreads();
    // ---- GEMM: two sequential 128-col passes over the same As
    const int lane = tid & 63, w = tid >> 6;
    const int m15 = lane & 15, q = lane >> 4;
    #pragma unroll
    for (int half = 0; half < 2; half++){
        const int jj = j0 + half*128;
        const unsigned short* wb = wib + ((size_t)jj + m15)*DIMC + q*8;
        bf16x8 bc[8], bn[8];
        #pragma unroll
        for (int nt = 0; nt < 8; nt++) bc[nt] = ld_frag16g(wb + nt*2048);
        f4_t zf = {0.f,0.f,0.f,0.f};
        f4_t acc[8];
        #pragma unroll
        for (int j = 0; j < 8; j++) acc[j] = zf;
        #pragma unroll
        for (int ks = 0; ks < 4; ks++){
            if (ks < 3){
                #pragma unroll
                for (int nt = 0; nt < 8; nt++) bn[nt] = ld_frag16g(wb + nt*2048 + (ks+1)*32);
            }
            bf16x8 a0 = ld_frag8(&As[(w*16 + m15)*KP + ks*32 + q*8]);
            #pragma unroll
            for (int nt = 0; nt < 8; nt++)
                acc[nt] = __builtin_amdgcn_mfma_f32_16x16x32_bf16(a0, bc[nt], acc[nt], 0,0,0);
            #pragma unroll
            for (int nt = 0; nt < 8; nt++) bc[nt] = bn[nt];
        }
        __syncthreads();   // half 0: no-op ordering; half 1: prior ep stores complete
        #pragma unroll
        for (int nt = 0; nt < 8; nt++){
            int row = w*16 + q*4;
            int col = nt*16 + m15;
            #pragma unroll
            for (int i = 0; i < 4; i++)
                ep[(row+i)*KP + col] = f2bf(acc[nt][i]);
        }
        __syncthreads();
        #pragma unroll
        for (int p = 0; p < 4; p++){
            int idx = p*256 + tid; int li2 = idx >> 4; int g = (idx & 15)*8;
            uint2 u0 = *(const uint2*)&ep[li2*KP + g];
            uint2 u1 = *(const uint2*)&ep[li2*KP + g + 4];
            uint4 o; o.x=u0.x; o.y=u0.y; o.z=u1.x; o.w=u1.y;
            *(uint4*)&xz[(size_t)(row0+li2)*512 + jj + g] = o;
        }
    }
}

// ---------------------------------------------------------------- fused scan-chunk reduce (reads LDS only)
// Ac via exp-of-sum: dts accumulates dtv (1 add/step); Ac reconstructed once.
template<bool FAST>
__device__ __forceinline__ void fscan(const unsigned short* __restrict__ As,
    const unsigned short* __restrict__ Ep, const float* __restrict__ fbuf,
    const float* Av, int ch, int d, int dim, float* Ac, float* Bc)
{
    float dts = 0.f;
    #pragma unroll 8
    for (int s = 0; s < LC; s++){
        int r = ch*32 + (d ? 31-s : s);
        float dtv = bf2f(Ep[r*KP + dim]);
        float uv  = bf2f(As[r*KP + dim]);
        float4 b0 = *(const float4*)&fbuf[r*FBP];
        float4 b1 = *(const float4*)&fbuf[r*FBP + 4];
        float bv[8] = {b0.x,b0.y,b0.z,b0.w,b1.x,b1.y,b1.z,b1.w};
        float du = dtv*uv;
        float a[8];
        comp_a8<FAST>(dtv, Av, a);
        #pragma unroll
        for (int n = 0; n < 8; n++)
            Bc[n] = a[n]*Bc[n] + du*bv[n];
        dts += dtv;
    }
    comp_a8<FAST>(dts, Av, Ac);
}

// ---------------------------------------------------------------- FUSED: conv+silu -> x_proj MFMA -> scan S1
__global__ __launch_bounds__(256,4) void k_xproj(const unsigned short* __restrict__ xz,
    const unsigned short* __restrict__ wallb, const float* __restrict__ dtb,
    const float* __restrict__ alog, const float* __restrict__ cw, const float* __restrict__ cbv,
    unsigned short* __restrict__ xc, unsigned short* __restrict__ dty,
    float* __restrict__ bcb, float* __restrict__ st)
{
    __shared__ __align__(16) unsigned short As[64*KP];   // 16896 B (u, stays intact)
    __shared__ __align__(16) unsigned short Zb[67*KP];   // 17688 B (xz halo tile; later Ep)
    __shared__ __align__(16) float fbuf[64*FBP];         //  5120 B (B,C f32)
    const int row0 = blockIdx.x * 64;    // grid.x = 192
    const int ib   = blockIdx.y;         // 0..7
    const int inst = ib >> 1;
    const int bb   = ib & 1;
    const int m    = inst >> 1;
    const int d    = inst & 1;
    const int tid = threadIdx.x;
    const size_t abase = (size_t)ib * LSEQ * DIMC;
    const int lane = tid & 63, w = tid >> 6;
    const int m15 = lane & 15, q = lane >> 4;
    const unsigned short* wb = wallb + ((size_t)inst*144 + m15)*DIMC + q*8;
    bf16x8 bc[9], bn[9];
    #pragma unroll
    for (int nt = 0; nt < 9; nt++) bc[nt] = ld_frag16g(wb + nt*2048);
    // ---- stage xz halo tile: rows [start, start+67)
    const int start = row0 - (d ? 0 : 3);
    for (int idx = tid; idx < 67*16; idx += 256){
        int r = idx >> 4, cq = idx & 15;
        int l = start + r;
        uint4 v = make_uint4(0,0,0,0);
        if (l >= 0 && l < LSEQ)
            v = *(const uint4*)&xz[((size_t)(bb*LSEQ + l))*512 + m*256 + cq*8];
        *(uint4*)&Zb[r*KP + cq*8] = v;
    }
    __syncthreads();
    // ---- conv + silu -> As, rolling window (li = lg*32 + p): 35 LDS reads not 128
    {
        const int dimi = tid & 127, lg = tid >> 7;
        float wk[4];
        #pragma unroll
        for (int k = 0; k < 4; k++){
            int kk = d ? 3-k : k;
            wk[k] = cw[((size_t)inst*DIMC + dimi)*4 + kk];
        }
        const float bsv = cbv[inst*DIMC + dimi];
        const int base = lg*32;
        float t0 = bf2f(Zb[(base  )*KP + dimi]);
        float t1 = bf2f(Zb[(base+1)*KP + dimi]);
        float t2 = bf2f(Zb[(base+2)*KP + dimi]);
        for (int p = 0; p < 32; p++){
            int li = base + p;
            float t3 = bf2f(Zb[(li+3)*KP + dimi]);
            float v = bsv + wk[0]*t0 + wk[1]*t1 + wk[2]*t2 + wk[3]*t3;
            v = v * sigf(v);
            As[li*KP + dimi] = f2bf(v);
            t0 = t1; t1 = t2; t2 = t3;
        }
    }
    __syncthreads();        // As ready; all Zb reads done (Ep alias safe after this)
    // coalesced xc store from As (fire-and-forget ahead of GEMM)
    #pragma unroll
    for (int p = 0; p < 4; p++){
        int idx = p*256 + tid; int li = idx >> 4; int g = (idx & 15)*8;
        uint2 u0 = *(const uint2*)&As[li*KP + g];
        uint2 u1 = *(const uint2*)&As[li*KP + g + 4];
        uint4 o; o.x=u0.x; o.y=u0.y; o.z=u1.x; o.w=u1.y;
        *(uint4*)&xc[abase + (size_t)(row0+li)*DIMC + g] = o;
    }
    f4_t zf = {0.f,0.f,0.f,0.f};
    f4_t acc[9];
    #pragma unroll
    for (int j = 0; j < 9; j++) acc[j] = zf;
    #pragma unroll
    for (int ks = 0; ks < 4; ks++){
        if (ks < 3){
            #pragma unroll
            for (int nt = 0; nt < 9; nt++) bn[nt] = ld_frag16g(wb + nt*2048 + (ks+1)*32);
        }
        bf16x8 a0 = ld_frag8(&As[(w*16 + m15)*KP + ks*32 + q*8]);
        #pragma unroll
        for (int nt = 0; nt < 9; nt++)
            acc[nt] = __builtin_amdgcn_mfma_f32_16x16x32_bf16(a0, bc[nt], acc[nt], 0,0,0);
        #pragma unroll
        for (int nt = 0; nt < 9; nt++) bc[nt] = bn[nt];
    }
    // stage B/C (acc[8]) -> fbuf ; dt (softplus) -> Ep (aliases Zb).
    unsigned short* Ep = Zb;
    {
        int row = w*16 + q*4;
        #pragma unroll
        for (int i = 0; i < 4; i++)
            fbuf[(row+i)*FBP + m15] = acc[8][i];
    }
    #pragma unroll
    for (int nt = 0; nt < 8; nt++){
        int col = nt*16 + m15;
        float bias = dtb[inst*DIMC + col];
        int row = w*16 + q*4;
        #pragma unroll
        for (int i = 0; i < 4; i++)
            Ep[(row+i)*KP + col] = f2bf(softplusf(acc[nt][i] + bias));
    }
    __syncthreads();
    {   // coalesced bcb store
        int row = tid >> 2, j = (tid & 3)*4;
        float4 v = { fbuf[row*FBP + j], fbuf[row*FBP + j + 1],
                     fbuf[row*FBP + j + 2], fbuf[row*FBP + j + 3] };
        *(float4*)&bcb[((size_t)ib*LSEQ + row0 + row)*16 + j] = v;
    }
    #pragma unroll
    for (int p = 0; p < 4; p++){   // dty store from Ep
        int idx = p*256 + tid; int li = idx >> 4; int g = (idx & 15)*8;
        uint2 u0 = *(const uint2*)&Ep[li*KP + g];
        uint2 u1 = *(const uint2*)&Ep[li*KP + g + 4];
        uint4 o; o.x=u0.x; o.y=u0.y; o.z=u1.x; o.w=u1.y;
        *(uint4*)&dty[abase + (size_t)(row0+li)*DIMC + g] = o;
    }
    // ---- fused scan stage 1: thread = (chunk-half, dim)
    const int ch  = tid >> 7;            // 0..1
    const int dim = tid & 127;
    const int bc2 = row0 >> 5;
    const int c   = d ? (NCH-1 - bc2 - ch) : (bc2 + ch);
    float Av[8];
    #pragma unroll
    for (int n = 0; n < 8; n++)
        Av[n] = -__expf(alog[((size_t)inst*DIMC + dim)*8 + n]);
    bool fast = true;
    #pragma unroll
    for (int n = 1; n < 8; n++)
        fast = fast && (fabsf(Av[n] - (float)(n+1)*Av[0]) <= 1e-5f*fabsf(Av[n]));
    float Ac[8], Bc[8];
    #pragma unroll
    for (int n = 0; n < 8; n++){ Ac[n] = 1.f; Bc[n] = 0.f; }
    if (fast) fscan<true >(As, Ep, fbuf, Av, ch, d, dim, Ac, Bc);
    else      fscan<false>(As, Ep, fbuf, Av, ch, d, dim, Ac, Bc);
    float* so = st + (((size_t)ib*NCH + c)*DIMC + dim)*16;
    float4 s0 = {Ac[0],Ac[1],Ac[2],Ac[3]};
    float4 s1 = {Ac[4],Ac[5],Ac[6],Ac[7]};
    float4 s2 = {Bc[0],Bc[1],Bc[2],Bc[3]};
    float4 s3 = {Bc[4],Bc[5],Bc[6],Bc[7]};
    *(float4*)&so[0]  = s0;
    *(float4*)&so[4]  = s1;
    *(float4*)&so[8]  = s2;
    *(float4*)&so[12] = s3;
}

// ---------------------------------------------------------------- scan S2 (cross-chunk exclusive prefix, in-place)
__global__ __launch_bounds__(512) void k_scan2(float* __restrict__ st){
    const int ib   = blockIdx.x >> 7;          // grid = 8*128 = 1024
    const int dim  = blockIdx.x & 127;
    const int n    = threadIdx.x >> 6;         // wave index = state index
    const int lane = threadIdx.x & 63;
    const size_t cstride = (size_t)DIMC*16;
    const size_t base = ((size_t)ib*NCH*DIMC + dim)*16 + n;
    float a[6], b[6];
    float Al = 1.f, Bl = 0.f;
    #pragma unroll
    for (int j = 0; j < 6; j++){
        size_t o = base + (size_t)(lane*6 + j)*cstride;
        float A  = st[o];
        float Bv = st[o + 8];
        a[j] = A; b[j] = Bv;
        Bl = A*Bl + Bv;
        Al *= A;
    }
    #pragma unroll
    for (int off = 1; off < 64; off <<= 1){
        float Ao = __shfl_up(Al, off, 64);
        float Bo = __shfl_up(Bl, off, 64);
        if (lane >= off){
            Bl = Al*Bo + Bl;
            Al = Al*Ao;
        }
    }
    float h = __shfl_up(Bl, 1, 64);            // exclusive carry
    if (lane == 0) h = 0.f;
    #pragma unroll
    for (int j = 0; j < 6; j++){
        size_t o = base + (size_t)(lane*6 + j)*cstride;
        st[o] = h;
        h = a[j]*h + b[j];
    }
}

// ---------------------------------------------------------------- scan S3 (replay, y in place over dt)
template<bool FAST>
__device__ __forceinline__ void scan3_body(unsigned short* __restrict__ dty,
    const unsigned short* __restrict__ sdt, const unsigned short* __restrict__ sxc,
    const unsigned short* __restrict__ sz, const float* __restrict__ sbc,
    const float* Av, float Dv, float* h,
    size_t rbase, size_t lbase, int d, int tid)
{
    #pragma unroll 8
    for (int s = 0; s < LC; s++){
        int r = d ? 31-s : s;
        float dtv = bf2f(sdt[r*128 + tid]);
        float uv  = bf2f(sxc[r*128 + tid]);
        float zv  = bf2f(sz [r*128 + tid]);
        float4 bA = *(const float4*)&sbc[r*16];
        float4 bB = *(const float4*)&sbc[r*16 + 4];
        float4 cA = *(const float4*)&sbc[r*16 + 8];
        float4 cB = *(const float4*)&sbc[r*16 + 12];
        float bv[8] = {bA.x,bA.y,bA.z,bA.w,bB.x,bB.y,bB.z,bB.w};
        float cv[8] = {cA.x,cA.y,cA.z,cA.w,cB.x,cB.y,cB.z,cB.w};
        float du = dtv*uv;
        float y = uv*Dv;
        float a[8];
        comp_a8<FAST>(dtv, Av, a);
        #pragma unroll
        for (int n = 0; n < 8; n++){
            h[n] = a[n]*h[n] + du*bv[n];
            y += h[n]*cv[n];
        }
        y *= zv * sigf(zv);
        dty[rbase + (lbase + r)*DIMC + tid] = f2bf(y);
    }
}

__global__ __launch_bounds__(128) void k_scan3(unsigned short* __restrict__ dty,
    const unsigned short* __restrict__ xc, const float* __restrict__ bcb,
    const unsigned short* __restrict__ xz, const float* __restrict__ st,
    const float* __restrict__ alog, const float* __restrict__ dvec)
{
    __shared__ __align__(16) unsigned short sdt[32*128];   // 8 KB
    __shared__ __align__(16) unsigned short sxc[32*128];   // 8 KB
    __shared__ __align__(16) unsigned short sz [32*128];   // 8 KB
    __shared__ __align__(16) float sbc[32*16];             // 2 KB
    const int ib = blockIdx.x & 7;
    const int c  = blockIdx.x >> 3;
    const int inst = ib >> 1, bb = ib & 1;
    const int m = inst >> 1, d = inst & 1;
    const int tid = threadIdx.x;
    const size_t rbase = (size_t)ib*LSEQ*DIMC;
    const size_t zbase = (size_t)bb*LSEQ*512 + m*256 + 128;
    const size_t lbase = d ? (size_t)(LSEQ - 32 - c*32) : (size_t)(c*32);
    #pragma unroll
    for (int p = 0; p < 4; p++){
        int idx = p*128 + tid;          // 512 uint4 per 8KB array
        int r = idx >> 4, g = (idx & 15)*8;
        size_t go = rbase + (lbase + r)*DIMC + g;
        *(uint4*)&sdt[r*128 + g] = *(const uint4*)&dty[go];
        *(uint4*)&sxc[r*128 + g] = *(const uint4*)&xc[go];
        *(uint4*)&sz [r*128 + g] = *(const uint4*)&xz[zbase + (lbase + r)*512 + g];
    }
    {   // bcb: 2KB = 128 x float4
        int r = tid >> 2, j = (tid & 3)*4;
        *(float4*)&sbc[r*16 + j] = *(const float4*)&bcb[((size_t)ib*LSEQ + lbase + r)*16 + j];
    }
    float Av[8];
    #pragma unroll
    for (int n = 0; n < 8; n++)
        Av[n] = -__expf(alog[((size_t)inst*DIMC + tid)*8 + n]);
    bool fast = true;
    #pragma unroll
    for (int n = 1; n < 8; n++)
        fast = fast && (fabsf(Av[n] - (float)(n+1)*Av[0]) <= 1e-5f*fabsf(Av[n]));
    const float Dv = dvec[inst*DIMC + tid];
    float h[8];
    const float* hp = st + (((size_t)ib*NCH + c)*DIMC + tid)*16;
    #pragma unroll
    for (int n = 0; n < 8; n++) h[n] = hp[n];
    __syncthreads();
    if (fast) scan3_body<true >(dty, sdt, sxc, sz, sbc, Av, Dv, h, rbase, lbase, d, tid);
    else      scan3_body<false>(dty, sdt, sxc, sz, sbc, Av, Dv, h, rbase, lbase, d, tid);
}

// ---------------------------------------------------------------- out_proj MFMA + diff + LN + add x + LN + T-store
__global__ __launch_bounds__(256,4) void k_final(const unsigned short* __restrict__ y,
    const unsigned short* __restrict__ owb, const float* __restrict__ x, const float* __restrict__ lamp,
    const float* __restrict__ sw, const float* __restrict__ sb,
    const float* __restrict__ n2w, const float* __restrict__ n2b, float* __restrict__ outp)
{
    __shared__ __align__(16) char smem[36352];
    unsigned short* Ast = (unsigned short*)smem;             // phase 1: [2*64][KP] = 33792 B
    float* yt            = (float*)smem;                     // phase 2: [64][129] f32 = 33024 B (aliases Ast)
    float* red1          = (float*)(smem + 33792);           // 1024 B
    float* red2          = (float*)(smem + 34816);           // 1024 B
    float* stt           = (float*)(smem + 35840);           //  512 B
    const int bb = blockIdx.y;
    const int l0 = blockIdx.x * 64;                  // grid.x = 192
    const int tid = threadIdx.x;
    const float lam = *lamp;
    #pragma unroll
    for (int p = 0; p < 8; p++){
        int idx = p*256 + tid; int mm = idx >> 10; int li = (idx >> 4) & 63; int g = (idx & 15)*8;
        uint4 vf = *(const uint4*)&y[(((size_t)(mm*2+0)*NB + bb)*LSEQ + l0 + li)*DIMC + g];
        uint4 vb = *(const uint4*)&y[(((size_t)(mm*2+1)*NB + bb)*LSEQ + l0 + li)*DIMC + g];
        const unsigned short* uf = (const unsigned short*)&vf;
        const unsigned short* ub = (const unsigned short*)&vb;
        unsigned short o[8];
        #pragma unroll
        for (int j = 0; j < 8; j++) o[j] = f2bf(bf2f(uf[j]) + bf2f(ub[j]));
        *(uint2*)&Ast[(mm*64 + li)*KP + g]     = *(uint2*)&o[0];
        *(uint2*)&Ast[(mm*64 + li)*KP + g + 4] = *(uint2*)&o[4];
    }
    __syncthreads();
    const int lane = tid & 63, w = tid >> 6;
    const int m15 = lane & 15, q = lane >> 4;
    f4_t zf = {0.f,0.f,0.f,0.f};
    f4_t acc[2][8];
    #pragma unroll
    for (int i = 0; i < 2; i++)
        #pragma unroll
        for (int j = 0; j < 8; j++) acc[i][j] = zf;
    #pragma unroll
    for (int ks = 0; ks < 4; ks++){
        int k0 = ks*32 + q*8;
        bf16x8 a0 = ld_frag8(&Ast[(       w*16 + m15)*KP + k0]);
        bf16x8 a1 = ld_frag8(&Ast[(64   + w*16 + m15)*KP + k0]);
        #pragma unroll
        for (int nt = 0; nt < 8; nt++){
            bf16x8 b0 = ld_frag16g(&owb[((size_t)0*DIMC + nt*16 + m15)*DIMC + k0]);
            bf16x8 b1 = ld_frag16g(&owb[((size_t)1*DIMC + nt*16 + m15)*DIMC + k0]);
            acc[0][nt] = __builtin_amdgcn_mfma_f32_16x16x32_bf16(a0, b0, acc[0][nt], 0,0,0);
            acc[1][nt] = __builtin_amdgcn_mfma_f32_16x16x32_bf16(a1, b1, acc[1][nt], 0,0,0);
        }
    }
    __syncthreads();
    #pragma unroll
    for (int nt = 0; nt < 8; nt++){
        int row = w*16 + q*4;
        int col = nt*16 + m15;
        #pragma unroll
        for (int i = 0; i < 4; i++)
            yt[(row+i)*129 + col] = acc[0][nt][i] - lam*acc[1][nt][i];
    }
    __syncthreads();
    const int r = tid & 63, g = tid >> 6;
    float s = 0.f, s2 = 0.f;
    #pragma unroll
    for (int k = 0; k < 32; k++){ float v = yt[r*129 + g*32 + k]; s += v; s2 += v*v; }
    red1[g*64 + r] = s; red2[g*64 + r] = s2;
    __syncthreads();
    if (tid < 64){
        float ss = 0.f, ss2 = 0.f;
        #pragma unroll
        for (int gg = 0; gg < 4; gg++){ ss += red1[gg*64 + tid]; ss2 += red2[gg*64 + tid]; }
        float mu = ss*(1.f/128.f);
        float var = ss2*(1.f/128.f) - mu*mu;
        stt[tid*2] = mu; stt[tid*2+1] = rsqrtf(var + EPSV);
    }
    __syncthreads();
    float mu1 = stt[r*2], rs1 = stt[r*2+1];
    s = 0.f; s2 = 0.f;
    #pragma unroll
    for (int k = 0; k < 32; k++){
        int c = g*32 + k;
        float v = (yt[r*129+c] - mu1)*rs1*sw[c] + sb[c]
                + x[(size_t)bb*DIMC*LSEQ + (size_t)c*LSEQ + l0 + r];
        yt[r*129+c] = v;
        s += v; s2 += v*v;
    }
    __syncthreads();
    red1[g*64 + r] = s; red2[g*64 + r] = s2;
    __syncthreads();
    if (tid < 64){
        float ss = 0.f, ss2 = 0.f;
        #pragma unroll
        for (int gg = 0; gg < 4; gg++){ ss += red1[gg*64 + tid]; ss2 += red2[gg*64 + tid]; }
        float mu = ss*(1.f/128.f);
        float var = ss2*(1.f/128.f) - mu*mu;
        stt[tid*2] = mu; stt[tid*2+1] = rsqrtf(var + EPSV);
    }
    __syncthreads();
    float mu2 = stt[r*2], rs2 = stt[r*2+1];
    #pragma unroll
    for (int k = 0; k < 32; k++){
        int c = g*32 + k;
        float o = (yt[r*129+c] - mu2)*rs2*n2w[c] + n2b[c];
        outp[(size_t)bb*DIMC*LSEQ + (size_t)c*LSEQ + l0 + r] = o;
    }
}

// ----------------------------------------------------------------
extern "C" void kernel_launch(void* const* d_in, const int* in_sizes, int n_in,
                              void* d_out, int out_size, void* d_ws, size_t ws_size,
                              hipStream_t stream)
{
    const float* x    = (const float*)d_in[0];
    const float* n1w  = (const float*)d_in[1];
    const float* n1b  = (const float*)d_in[2];
    const float* n2w  = (const float*)d_in[3];
    const float* n2b  = (const float*)d_in[4];
    const float* slw  = (const float*)d_in[5];
    const float* slb  = (const float*)d_in[6];
    const float* lq   = (const float*)d_in[7];
    const float* wi   = (const float*)d_in[8];
    const float* cw   = (const float*)d_in[9];
    const float* cb   = (const float*)d_in[10];
    const float* xpw  = (const float*)d_in[11];
    const float* dtw  = (const float*)d_in[12];
    const float* dtb  = (const float*)d_in[13];
    const float* alog = (const float*)d_in[14];
    const float* dvec = (const float*)d_in[15];
    const float* ow   = (const float*)d_in[16];

    float* ws = (float*)d_ws;
    unsigned short* xz    = (unsigned short*)(ws + 1572864);   // 6,291,456 f
    unsigned short* xc    = (unsigned short*)(ws + 7864320);   // 6,291,456 f
    unsigned short* dty   = (unsigned short*)(ws + 14155776);  // 6,291,456 f
    float*          bcb   = ws + 20447232;                     // 1,572,864 f
    float*          st1   = ws + 22020096;                     // 6,291,456 f (8*NCH*128*16)
    unsigned short* wallb = (unsigned short*)(ws + 28311552);  //    36,864 f
    unsigned short* wib   = (unsigned short*)(ws + 28348416);  //    32,768 f
    unsigned short* owb   = (unsigned short*)(ws + 28381184);  //    16,384 f
    float*          lam   = ws + 28397568;                     //         1

    k_wall  <<<768, 128, 0, stream>>>(dtw, xpw, lq, wi, ow, wallb, lam, wib, owb);
    k_inproj<<<dim3(384, 2), 256, 0, stream>>>(x, n1w, n1b, wib, xz);
    k_xproj <<<dim3(192, 8), 256, 0, stream>>>(xz, wallb, dtb, alog, cw, cb, xc, dty, bcb, st1);
    k_scan2 <<<1024, 512, 0, stream>>>(st1);
    k_scan3 <<<8*NCH, 128, 0, stream>>>(dty, xc, bcb, xz, st1, alog, dvec);
    k_final <<<dim3(192, 2), 256, 0, stream>>>(dty, owb, x, lam, slw, slb, n2w, n2b, (float*)d_out);
}

// Round 12
// 268.102 us; speedup vs baseline: 1.0309x; 1.0082x over previous
//
#include <hip/hip_runtime.h>
#include <math.h>

#define DIMC 128
#define LSEQ 12288
#define NB 2
#define BLR 24576   // NB*LSEQ
#define EPSV 1e-5f
#define NCH 384     // scan chunks per row
#define LC 32       // chunk length (NCH*LC = LSEQ)
#define KP 132      // LDS row pad (ushorts) for MFMA staging
#define FBP 20      // fbuf row pad (floats, 16B-aligned rows)

typedef __bf16 bf16x8 __attribute__((ext_vector_type(8)));
typedef __attribute__((ext_vector_type(4))) float f4_t;

__device__ __forceinline__ float sigf(float x){ return 1.f/(1.f+__expf(-x)); }
__device__ __forceinline__ float softplusf(float x){
    return fmaxf(x,0.f) + __logf(1.f + __expf(-fabsf(x)));
}
__device__ __forceinline__ float bf2f(unsigned short u){
    union { unsigned int i; float f; } v; v.i = ((unsigned int)u) << 16; return v.f;
}
__device__ __forceinline__ unsigned short f2bf(float f){
    union { float f; unsigned int i; } v; v.f = f;
    unsigned int b = v.i + 0x7FFFu + ((v.i >> 16) & 1u);
    return (unsigned short)(b >> 16);
}
__device__ __forceinline__ bf16x8 ld_frag8(const unsigned short* p){   // 8B-aligned LDS
    union { uint2 u[2]; bf16x8 v; } r;
    r.u[0] = *(const uint2*)(p);
    r.u[1] = *(const uint2*)(p+4);
    return r.v;
}
__device__ __forceinline__ bf16x8 ld_frag16g(const unsigned short* p){ // 16B-aligned global
    union { uint4 u; bf16x8 v; } r; r.u = *(const uint4*)p; return r.v;
}

// a[n] = exp(dtv*Av[n]).  FAST: Av[n] == (n+1)*Av[0] (detected at runtime) ->
// 1 transcendental + 7 muls instead of 8 transcendentals.
template<bool FAST>
__device__ __forceinline__ void comp_a8(float dtv, const float* Av, float* a){
    if (FAST){
        float e1 = __expf(dtv*Av[0]);
        float e2 = e1*e1, e4 = e2*e2;
        a[0]=e1; a[1]=e2; a[2]=e2*e1; a[3]=e4;
        a[4]=e4*e1; a[5]=e4*e2; a[6]=a[5]*e1; a[7]=e4*e4;
    } else {
        #pragma unroll
        for (int n = 0; n < 8; n++) a[n] = __expf(dtv*Av[n]);
    }
}

// ---------------------------------------------------------------- W_all (bf16) + lam + wi/ow->bf16 (merged)
// grid 768 x 128: blocks [0,576) build wallb; [576,768) convert wi/ow.
__global__ __launch_bounds__(128) void k_wall(const float* __restrict__ dtw, const float* __restrict__ xpw,
                       const float* __restrict__ lq, const float* __restrict__ wi, const float* __restrict__ ow,
                       unsigned short* __restrict__ wallb, float* __restrict__ lam,
                       unsigned short* __restrict__ wib, unsigned short* __restrict__ owb){
    int b = blockIdx.x, k = threadIdx.x;
    if (b < 576){
        int inst = b & 3, j = b >> 2;
        const float* xp = xpw + (size_t)inst*24*128;
        float v;
        if (j < 128){
            const float* dw = dtw + (size_t)inst*128*8 + (size_t)j*8;
            v = 0.f;
            #pragma unroll
            for (int r = 0; r < 8; r++) v += dw[r]*xp[r*128 + k];
        } else {
            v = xp[(8 + (j-128))*128 + k];
        }
        wallb[((size_t)inst*144 + j)*128 + k] = f2bf(v);
        if (b == 0 && k < 64){
            float s = lq[k] + lq[k+64];
            for (int m = 32; m; m >>= 1) s += __shfl_xor(s, m);
            if (k == 0) *lam = 1.f/(1.f+__expf(-s));
        }
    } else {
        int idx = ((b-576)*128 + k)*4;   // 192 blocks -> 98304 elems
        const float* src; unsigned short* dst; int off;
        if (idx < 65536){ src = wi;  dst = wib; off = idx; }
        else            { src = ow;  dst = owb; off = idx - 65536; }
        float4 v = *(const float4*)&src[off];
        ushort4 o; o.x=f2bf(v.x); o.y=f2bf(v.y); o.z=f2bf(v.z); o.w=f2bf(v.w);
        *(ushort4*)&dst[off] = o;
    }
}

// ---------------------------------------------------------------- FUSED: LN1 + transpose + in_proj MFMA (2-pass N)
__global__ __launch_bounds__(256,4) void k_inproj(const float* __restrict__ x,
    const float* __restrict__ w1, const float* __restrict__ b1,
    const unsigned short* __restrict__ wib, unsigned short* __restrict__ xz)
{
    __shared__ __align__(16) unsigned short As[64*KP];   // 16896 B
    __shared__ __align__(16) unsigned short ep[64*KP];   // 16896 B
    __shared__ float red1[256], red2[256];
    __shared__ float stt[128];
    const int row0 = blockIdx.x * 64;   // grid.x = 384  (row0 == bb*LSEQ + l0)
    const int bb = blockIdx.x / 192;
    const int l0 = (blockIdx.x % 192) * 64;
    const int j0 = blockIdx.y * 256;    // grid.y = 2
    const int tid = threadIdx.x;
    const int li = tid & 63, cg = tid >> 6;
    const float* xb = x + (size_t)bb*DIMC*LSEQ + l0 + li;
    // pass 1: stats (coalesced, values discarded)
    {
        float s = 0.f, s2 = 0.f;
        #pragma unroll
        for (int p = 0; p < 32; p++){
            float v = xb[(size_t)(p*4 + cg)*LSEQ];
            s += v; s2 += v*v;
        }
        red1[cg*64 + li] = s; red2[cg*64 + li] = s2;
    }
    __syncthreads();
    if (tid < 64){
        float ss = 0.f, ss2 = 0.f;
        #pragma unroll
        for (int g = 0; g < 4; g++){ ss += red1[g*64 + tid]; ss2 += red2[g*64 + tid]; }
        float mu = ss*(1.f/128.f);
        float var = ss2*(1.f/128.f) - mu*mu;
        stt[tid*2] = mu; stt[tid*2+1] = rsqrtf(var + EPSV);
    }
    __syncthreads();
    // pass 2: re-read (cache-hot), normalize, write As bf16
    {
        float mu = stt[li*2], rs = stt[li*2+1];
        #pragma unroll
        for (int p = 0; p < 32; p++){
            int c = p*4 + cg;
            float v = (xb[(size_t)c*LSEQ] - mu)*rs*w1[c] + b1[c];
            As[li*KP + c] = f2bf(v);
        }
    }
    __syncthreads();
    // ---- GEMM: two sequential 128-col passes over the same As
    const int lane = tid & 63, w = tid >> 6;
    const int m15 = lane & 15, q = lane >> 4;
    #pragma unroll
    for (int half = 0; half < 2; half++){
        const int jj = j0 + half*128;
        const unsigned short* wb = wib + ((size_t)jj + m15)*DIMC + q*8;
        bf16x8 bc[8], bn[8];
        #pragma unroll
        for (int nt = 0; nt < 8; nt++) bc[nt] = ld_frag16g(wb + nt*2048);
        f4_t zf = {0.f,0.f,0.f,0.f};
        f4_t acc[8];
        #pragma unroll
        for (int j = 0; j < 8; j++) acc[j] = zf;
        #pragma unroll
        for (int ks = 0; ks < 4; ks++){
            if (ks < 3){
                #pragma unroll
                for (int nt = 0; nt < 8; nt++) bn[nt] = ld_frag16g(wb + nt*2048 + (ks+1)*32);
            }
            bf16x8 a0 = ld_frag8(&As[(w*16 + m15)*KP + ks*32 + q*8]);
            #pragma unroll
            for (int nt = 0; nt < 8; nt++)
                acc[nt] = __builtin_amdgcn_mfma_f32_16x16x32_bf16(a0, bc[nt], acc[nt], 0,0,0);
            #pragma unroll
            for (int nt = 0; nt < 8; nt++) bc[nt] = bn[nt];
        }
        __syncthreads();   // half 0: no-op ordering; half 1: prior ep stores complete
        #pragma unroll
        for (int nt = 0; nt < 8; nt++){
            int row = w*16 + q*4;
            int col = nt*16 + m15;
            #pragma unroll
            for (int i = 0; i < 4; i++)
                ep[(row+i)*KP + col] = f2bf(acc[nt][i]);
        }
        __syncthreads();
        #pragma unroll
        for (int p = 0; p < 4; p++){
            int idx = p*256 + tid; int li2 = idx >> 4; int g = (idx & 15)*8;
            uint2 u0 = *(const uint2*)&ep[li2*KP + g];
            uint2 u1 = *(const uint2*)&ep[li2*KP + g + 4];
            uint4 o; o.x=u0.x; o.y=u0.y; o.z=u1.x; o.w=u1.y;
            *(uint4*)&xz[(size_t)(row0+li2)*512 + jj + g] = o;
        }
    }
}

// ---------------------------------------------------------------- fused scan-chunk reduce
// u from Zb LDS; dt from GLOBAL dty (coalesced 256B/step, L2-hot, same-block RAW
// made visible by the preceding __syncthreads). Ac via exp-of-sum.
template<bool FAST>
__device__ __forceinline__ void fscan(const unsigned short* __restrict__ Zb,
    const unsigned short* __restrict__ dtg, const float* __restrict__ fbuf,
    const float* Av, int ch, int d, int dim, float* Ac, float* Bc)
{
    float dts = 0.f;
    #pragma unroll 8
    for (int s = 0; s < LC; s++){
        int r = ch*32 + (d ? 31-s : s);
        float dtv = bf2f(dtg[(size_t)r*DIMC + dim]);
        float uv  = bf2f(Zb[r*KP + dim]);
        float4 b0 = *(const float4*)&fbuf[r*FBP];
        float4 b1 = *(const float4*)&fbuf[r*FBP + 4];
        float bv[8] = {b0.x,b0.y,b0.z,b0.w,b1.x,b1.y,b1.z,b1.w};
        float du = dtv*uv;
        float a[8];
        comp_a8<FAST>(dtv, Av, a);
        #pragma unroll
        for (int n = 0; n < 8; n++)
            Bc[n] = a[n]*Bc[n] + du*bv[n];
        dts += dtv;
    }
    comp_a8<FAST>(dts, Av, Ac);
}

// ---------------------------------------------------------------- FUSED: conv+silu -> x_proj MFMA -> scan S1
// LDS slimmed to Zb+fbuf (22.8KB): conv writes u IN PLACE into Zb (boundary rows
// preloaded to regs), dt goes straight to global dty; As/Ep buffers eliminated.
// => 7 blocks/CU (was 4), single scheduling round for the 1536-block grid.
__global__ __launch_bounds__(256,6) void k_xproj(const unsigned short* __restrict__ xz,
    const unsigned short* __restrict__ wallb, const float* __restrict__ dtb,
    const float* __restrict__ alog, const float* __restrict__ cw, const float* __restrict__ cbv,
    unsigned short* __restrict__ xc, unsigned short* __restrict__ dty,
    float* __restrict__ bcb, float* __restrict__ st)
{
    __shared__ __align__(16) unsigned short Zb[67*KP];   // 17688 B (xz halo -> u in place)
    __shared__ __align__(16) float fbuf[64*FBP];         //  5120 B (B,C f32)
    const int row0 = blockIdx.x * 64;    // grid.x = 192
    const int ib   = blockIdx.y;         // 0..7
    const int inst = ib >> 1;
    const int bb   = ib & 1;
    const int m    = inst >> 1;
    const int d    = inst & 1;
    const int tid = threadIdx.x;
    const size_t abase = (size_t)ib * LSEQ * DIMC;
    const int lane = tid & 63, w = tid >> 6;
    const int m15 = lane & 15, q = lane >> 4;
    const unsigned short* wb = wallb + ((size_t)inst*144 + m15)*DIMC + q*8;
    bf16x8 bc[9], bn[9];
    #pragma unroll
    for (int nt = 0; nt < 9; nt++) bc[nt] = ld_frag16g(wb + nt*2048);
    // ---- stage xz halo tile: rows [start, start+67)
    const int start = row0 - (d ? 0 : 3);
    for (int idx = tid; idx < 67*16; idx += 256){
        int r = idx >> 4, cq = idx & 15;
        int l = start + r;
        uint4 v = make_uint4(0,0,0,0);
        if (l >= 0 && l < LSEQ)
            v = *(const uint4*)&xz[((size_t)(bb*LSEQ + l))*512 + m*256 + cq*8];
        *(uint4*)&Zb[r*KP + cq*8] = v;
    }
    __syncthreads();
    // ---- conv + silu IN PLACE: u[li] overwrites Zb row li.
    // Safe: output li uses input rows li..li+3 (all > rows written so far within
    // the group); the 3 cross-group boundary rows (base+32..34) are preloaded to
    // regs before a barrier, so the next group's in-place writes can't race them.
    {
        const int dimi = tid & 127, lg = tid >> 7;
        float wk[4];
        #pragma unroll
        for (int k = 0; k < 4; k++){
            int kk = d ? 3-k : k;
            wk[k] = cw[((size_t)inst*DIMC + dimi)*4 + kk];
        }
        const float bsv = cbv[inst*DIMC + dimi];
        const int base = lg*32;
        float t0 = bf2f(Zb[(base   )*KP + dimi]);
        float t1 = bf2f(Zb[(base+1 )*KP + dimi]);
        float t2 = bf2f(Zb[(base+2 )*KP + dimi]);
        float e0 = bf2f(Zb[(base+32)*KP + dimi]);
        float e1 = bf2f(Zb[(base+33)*KP + dimi]);
        float e2 = bf2f(Zb[(base+34)*KP + dimi]);
        __syncthreads();     // all preloads done before any in-place write
        for (int p = 0; p < 29; p++){
            int li = base + p;
            float t3 = bf2f(Zb[(li+3)*KP + dimi]);
            float v = bsv + wk[0]*t0 + wk[1]*t1 + wk[2]*t2 + wk[3]*t3;
            v = v * sigf(v);
            Zb[li*KP + dimi] = f2bf(v);
            t0 = t1; t1 = t2; t2 = t3;
        }
        #pragma unroll
        for (int p = 29; p < 32; p++){
            int li = base + p;
            float t3 = (p == 29) ? e0 : (p == 30 ? e1 : e2);
            float v = bsv + wk[0]*t0 + wk[1]*t1 + wk[2]*t2 + wk[3]*t3;
            v = v * sigf(v);
            Zb[li*KP + dimi] = f2bf(v);
            t0 = t1; t1 = t2; t2 = t3;
        }
    }
    __syncthreads();        // u complete in Zb rows 0..63
    // coalesced xc store from Zb (fire-and-forget ahead of GEMM)
    #pragma unroll
    for (int p = 0; p < 4; p++){
        int idx = p*256 + tid; int li = idx >> 4; int g = (idx & 15)*8;
        uint2 u0 = *(const uint2*)&Zb[li*KP + g];
        uint2 u1 = *(const uint2*)&Zb[li*KP + g + 4];
        uint4 o; o.x=u0.x; o.y=u0.y; o.z=u1.x; o.w=u1.y;
        *(uint4*)&xc[abase + (size_t)(row0+li)*DIMC + g] = o;
    }
    f4_t zf = {0.f,0.f,0.f,0.f};
    f4_t acc[9];
    #pragma unroll
    for (int j = 0; j < 9; j++) acc[j] = zf;
    #pragma unroll
    for (int ks = 0; ks < 4; ks++){
        if (ks < 3){
            #pragma unroll
            for (int nt = 0; nt < 9; nt++) bn[nt] = ld_frag16g(wb + nt*2048 + (ks+1)*32);
        }
        bf16x8 a0 = ld_frag8(&Zb[(w*16 + m15)*KP + ks*32 + q*8]);
        #pragma unroll
        for (int nt = 0; nt < 9; nt++)
            acc[nt] = __builtin_amdgcn_mfma_f32_16x16x32_bf16(a0, bc[nt], acc[nt], 0,0,0);
        #pragma unroll
        for (int nt = 0; nt < 9; nt++) bc[nt] = bn[nt];
    }
    // B/C (acc[8]) -> fbuf ; dt (softplus) -> DIRECT global dty (32B segments)
    {
        int row = w*16 + q*4;
        #pragma unroll
        for (int i = 0; i < 4; i++)
            fbuf[(row+i)*FBP + m15] = acc[8][i];
    }
    #pragma unroll
    for (int nt = 0; nt < 8; nt++){
        int col = nt*16 + m15;
        float bias = dtb[inst*DIMC + col];
        int row = w*16 + q*4;
        #pragma unroll
        for (int i = 0; i < 4; i++)
            dty[abase + (size_t)(row0+row+i)*DIMC + col] = f2bf(softplusf(acc[nt][i] + bias));
    }
    __syncthreads();   // fbuf visible; dty stores drained (vmcnt) -> L2 RAW safe
    {   // coalesced bcb store
        int row = tid >> 2, j = (tid & 3)*4;
        float4 v = { fbuf[row*FBP + j], fbuf[row*FBP + j + 1],
                     fbuf[row*FBP + j + 2], fbuf[row*FBP + j + 3] };
        *(float4*)&bcb[((size_t)ib*LSEQ + row0 + row)*16 + j] = v;
    }
    // ---- fused scan stage 1: thread = (chunk-half, dim)
    const int ch  = tid >> 7;            // 0..1
    const int dim = tid & 127;
    const int bc2 = row0 >> 5;
    const int c   = d ? (NCH-1 - bc2 - ch) : (bc2 + ch);
    float Av[8];
    #pragma unroll
    for (int n = 0; n < 8; n++)
        Av[n] = -__expf(alog[((size_t)inst*DIMC + dim)*8 + n]);
    bool fast = true;
    #pragma unroll
    for (int n = 1; n < 8; n++)
        fast = fast && (fabsf(Av[n] - (float)(n+1)*Av[0]) <= 1e-5f*fabsf(Av[n]));
    float Ac[8], Bc[8];
    #pragma unroll
    for (int n = 0; n < 8; n++){ Ac[n] = 1.f; Bc[n] = 0.f; }
    const unsigned short* dtg = dty + abase + (size_t)row0*DIMC;
    if (fast) fscan<true >(Zb, dtg, fbuf, Av, ch, d, dim, Ac, Bc);
    else      fscan<false>(Zb, dtg, fbuf, Av, ch, d, dim, Ac, Bc);
    float* so = st + (((size_t)ib*NCH + c)*DIMC + dim)*16;
    float4 s0 = {Ac[0],Ac[1],Ac[2],Ac[3]};
    float4 s1 = {Ac[4],Ac[5],Ac[6],Ac[7]};
    float4 s2 = {Bc[0],Bc[1],Bc[2],Bc[3]};
    float4 s3 = {Bc[4],Bc[5],Bc[6],Bc[7]};
    *(float4*)&so[0]  = s0;
    *(float4*)&so[4]  = s1;
    *(float4*)&so[8]  = s2;
    *(float4*)&so[12] = s3;
}

// ---------------------------------------------------------------- scan S2 (cross-chunk exclusive prefix, in-place)
__global__ __launch_bounds__(512) void k_scan2(float* __restrict__ st){
    const int ib   = blockIdx.x >> 7;          // grid = 8*128 = 1024
    const int dim  = blockIdx.x & 127;
    const int n    = threadIdx.x >> 6;         // wave index = state index
    const int lane = threadIdx.x & 63;
    const size_t cstride = (size_t)DIMC*16;
    const size_t base = ((size_t)ib*NCH*DIMC + dim)*16 + n;
    float a[6], b[6];
    float Al = 1.f, Bl = 0.f;
    #pragma unroll
    for (int j = 0; j < 6; j++){
        size_t o = base + (size_t)(lane*6 + j)*cstride;
        float A  = st[o];
        float Bv = st[o + 8];
        a[j] = A; b[j] = Bv;
        Bl = A*Bl + Bv;
        Al *= A;
    }
    #pragma unroll
    for (int off = 1; off < 64; off <<= 1){
        float Ao = __shfl_up(Al, off, 64);
        float Bo = __shfl_up(Bl, off, 64);
        if (lane >= off){
            Bl = Al*Bo + Bl;
            Al = Al*Ao;
        }
    }
    float h = __shfl_up(Bl, 1, 64);            // exclusive carry
    if (lane == 0) h = 0.f;
    #pragma unroll
    for (int j = 0; j < 6; j++){
        size_t o = base + (size_t)(lane*6 + j)*cstride;
        st[o] = h;
        h = a[j]*h + b[j];
    }
}

// ---------------------------------------------------------------- scan S3 (replay, y in place over dt)
template<bool FAST>
__device__ __forceinline__ void scan3_body(unsigned short* __restrict__ dty,
    const unsigned short* __restrict__ sdt, const unsigned short* __restrict__ sxc,
    const unsigned short* __restrict__ sz, const float* __restrict__ sbc,
    const float* Av, float Dv, float* h,
    size_t rbase, size_t lbase, int d, int tid)
{
    #pragma unroll 8
    for (int s = 0; s < LC; s++){
        int r = d ? 31-s : s;
        float dtv = bf2f(sdt[r*128 + tid]);
        float uv  = bf2f(sxc[r*128 + tid]);
        float zv  = bf2f(sz [r*128 + tid]);
        float4 bA = *(const float4*)&sbc[r*16];
        float4 bB = *(const float4*)&sbc[r*16 + 4];
        float4 cA = *(const float4*)&sbc[r*16 + 8];
        float4 cB = *(const float4*)&sbc[r*16 + 12];
        float bv[8] = {bA.x,bA.y,bA.z,bA.w,bB.x,bB.y,bB.z,bB.w};
        float cv[8] = {cA.x,cA.y,cA.z,cA.w,cB.x,cB.y,cB.z,cB.w};
        float du = dtv*uv;
        float y = uv*Dv;
        float a[8];
        comp_a8<FAST>(dtv, Av, a);
        #pragma unroll
        for (int n = 0; n < 8; n++){
            h[n] = a[n]*h[n] + du*bv[n];
            y += h[n]*cv[n];
        }
        y *= zv * sigf(zv);
        dty[rbase + (lbase + r)*DIMC + tid] = f2bf(y);
    }
}

__global__ __launch_bounds__(128) void k_scan3(unsigned short* __restrict__ dty,
    const unsigned short* __restrict__ xc, const float* __restrict__ bcb,
    const unsigned short* __restrict__ xz, const float* __restrict__ st,
    const float* __restrict__ alog, const float* __restrict__ dvec)
{
    __shared__ __align__(16) unsigned short sdt[32*128];   // 8 KB
    __shared__ __align__(16) unsigned short sxc[32*128];   // 8 KB
    __shared__ __align__(16) unsigned short sz [32*128];   // 8 KB
    __shared__ __align__(16) float sbc[32*16];             // 2 KB
    const int ib = blockIdx.x & 7;
    const int c  = blockIdx.x >> 3;
    const int inst = ib >> 1, bb = ib & 1;
    const int m = inst >> 1, d = inst & 1;
    const int tid = threadIdx.x;
    const size_t rbase = (size_t)ib*LSEQ*DIMC;
    const size_t zbase = (size_t)bb*LSEQ*512 + m*256 + 128;
    const size_t lbase = d ? (size_t)(LSEQ - 32 - c*32) : (size_t)(c*32);
    #pragma unroll
    for (int p = 0; p < 4; p++){
        int idx = p*128 + tid;          // 512 uint4 per 8KB array
        int r = idx >> 4, g = (idx & 15)*8;
        size_t go = rbase + (lbase + r)*DIMC + g;
        *(uint4*)&sdt[r*128 + g] = *(const uint4*)&dty[go];
        *(uint4*)&sxc[r*128 + g] = *(const uint4*)&xc[go];
        *(uint4*)&sz [r*128 + g] = *(const uint4*)&xz[zbase + (lbase + r)*512 + g];
    }
    {   // bcb: 2KB = 128 x float4
        int r = tid >> 2, j = (tid & 3)*4;
        *(float4*)&sbc[r*16 + j] = *(const float4*)&bcb[((size_t)ib*LSEQ + lbase + r)*16 + j];
    }
    float Av[8];
    #pragma unroll
    for (int n = 0; n < 8; n++)
        Av[n] = -__expf(alog[((size_t)inst*DIMC + tid)*8 + n]);
    bool fast = true;
    #pragma unroll
    for (int n = 1; n < 8; n++)
        fast = fast && (fabsf(Av[n] - (float)(n+1)*Av[0]) <= 1e-5f*fabsf(Av[n]));
    const float Dv = dvec[inst*DIMC + tid];
    float h[8];
    const float* hp = st + (((size_t)ib*NCH + c)*DIMC + tid)*16;
    #pragma unroll
    for (int n = 0; n < 8; n++) h[n] = hp[n];
    __syncthreads();
    if (fast) scan3_body<true >(dty, sdt, sxc, sz, sbc, Av, Dv, h, rbase, lbase, d, tid);
    else      scan3_body<false>(dty, sdt, sxc, sz, sbc, Av, Dv, h, rbase, lbase, d, tid);
}

// ---------------------------------------------------------------- out_proj MFMA + diff + LN + add x + LN + T-store
__global__ __launch_bounds__(256,4) void k_final(const unsigned short* __restrict__ y,
    const unsigned short* __restrict__ owb, const float* __restrict__ x, const float* __restrict__ lamp,
    const float* __restrict__ sw, const float* __restrict__ sb,
    const float* __restrict__ n2w, const float* __restrict__ n2b, float* __restrict__ outp)
{
    __shared__ __align__(16) char smem[36352];
    unsigned short* Ast = (unsigned short*)smem;             // phase 1: [2*64][KP] = 33792 B
    float* yt            = (float*)smem;                     // phase 2: [64][129] f32 = 33024 B (aliases Ast)
    float* red1          = (float*)(smem + 33792);           // 1024 B
    float* red2          = (float*)(smem + 34816);           // 1024 B
    float* stt           = (float*)(smem + 35840);           //  512 B
    const int bb = blockIdx.y;
    const int l0 = blockIdx.x * 64;                  // grid.x = 192
    const int tid = threadIdx.x;
    const float lam = *lamp;
    #pragma unroll
    for (int p = 0; p < 8; p++){
        int idx = p*256 + tid; int mm = idx >> 10; int li = (idx >> 4) & 63; int g = (idx & 15)*8;
        uint4 vf = *(const uint4*)&y[(((size_t)(mm*2+0)*NB + bb)*LSEQ + l0 + li)*DIMC + g];
        uint4 vb = *(const uint4*)&y[(((size_t)(mm*2+1)*NB + bb)*LSEQ + l0 + li)*DIMC + g];
        const unsigned short* uf = (const unsigned short*)&vf;
        const unsigned short* ub = (const unsigned short*)&vb;
        unsigned short o[8];
        #pragma unroll
        for (int j = 0; j < 8; j++) o[j] = f2bf(bf2f(uf[j]) + bf2f(ub[j]));
        *(uint2*)&Ast[(mm*64 + li)*KP + g]     = *(uint2*)&o[0];
        *(uint2*)&Ast[(mm*64 + li)*KP + g + 4] = *(uint2*)&o[4];
    }
    __syncthreads();
    const int lane = tid & 63, w = tid >> 6;
    const int m15 = lane & 15, q = lane >> 4;
    f4_t zf = {0.f,0.f,0.f,0.f};
    f4_t acc[2][8];
    #pragma unroll
    for (int i = 0; i < 2; i++)
        #pragma unroll
        for (int j = 0; j < 8; j++) acc[i][j] = zf;
    #pragma unroll
    for (int ks = 0; ks < 4; ks++){
        int k0 = ks*32 + q*8;
        bf16x8 a0 = ld_frag8(&Ast[(       w*16 + m15)*KP + k0]);
        bf16x8 a1 = ld_frag8(&Ast[(64   + w*16 + m15)*KP + k0]);
        #pragma unroll
        for (int nt = 0; nt < 8; nt++){
            bf16x8 b0 = ld_frag16g(&owb[((size_t)0*DIMC + nt*16 + m15)*DIMC + k0]);
            bf16x8 b1 = ld_frag16g(&owb[((size_t)1*DIMC + nt*16 + m15)*DIMC + k0]);
            acc[0][nt] = __builtin_amdgcn_mfma_f32_16x16x32_bf16(a0, b0, acc[0][nt], 0,0,0);
            acc[1][nt] = __builtin_amdgcn_mfma_f32_16x16x32_bf16(a1, b1, acc[1][nt], 0,0,0);
        }
    }
    __syncthreads();
    #pragma unroll
    for (int nt = 0; nt < 8; nt++){
        int row = w*16 + q*4;
        int col = nt*16 + m15;
        #pragma unroll
        for (int i = 0; i < 4; i++)
            yt[(row+i)*129 + col] = acc[0][nt][i] - lam*acc[1][nt][i];
    }
    __syncthreads();
    const int r = tid & 63, g = tid >> 6;
    float s = 0.f, s2 = 0.f;
    #pragma unroll
    for (int k = 0; k < 32; k++){ float v = yt[r*129 + g*32 + k]; s += v; s2 += v*v; }
    red1[g*64 + r] = s; red2[g*64 + r] = s2;
    __syncthreads();
    if (tid < 64){
        float ss = 0.f, ss2 = 0.f;
        #pragma unroll
        for (int gg = 0; gg < 4; gg++){ ss += red1[gg*64 + tid]; ss2 += red2[gg*64 + tid]; }
        float mu = ss*(1.f/128.f);
        float var = ss2*(1.f/128.f) - mu*mu;
        stt[tid*2] = mu; stt[tid*2+1] = rsqrtf(var + EPSV);
    }
    __syncthreads();
    float mu1 = stt[r*2], rs1 = stt[r*2+1];
    s = 0.f; s2 = 0.f;
    #pragma unroll
    for (int k = 0; k < 32; k++){
        int c = g*32 + k;
        float v = (yt[r*129+c] - mu1)*rs1*sw[c] + sb[c]
                + x[(size_t)bb*DIMC*LSEQ + (size_t)c*LSEQ + l0 + r];
        yt[r*129+c] = v;
        s += v; s2 += v*v;
    }
    __syncthreads();
    red1[g*64 + r] = s; red2[g*64 + r] = s2;
    __syncthreads();
    if (tid < 64){
        float ss = 0.f, ss2 = 0.f;
        #pragma unroll
        for (int gg = 0; gg < 4; gg++){ ss += red1[gg*64 + tid]; ss2 += red2[gg*64 + tid]; }
        float mu = ss*(1.f/128.f);
        float var = ss2*(1.f/128.f) - mu*mu;
        stt[tid*2] = mu; stt[tid*2+1] = rsqrtf(var + EPSV);
    }
    __syncthreads();
    float mu2 = stt[r*2], rs2 = stt[r*2+1];
    #pragma unroll
    for (int k = 0; k < 32; k++){
        int c = g*32 + k;
        float o = (yt[r*129+c] - mu2)*rs2*n2w[c] + n2b[c];
        outp[(size_t)bb*DIMC*LSEQ + (size_t)c*LSEQ + l0 + r] = o;
    }
}

// ----------------------------------------------------------------
extern "C" void kernel_launch(void* const* d_in, const int* in_sizes, int n_in,
                              void* d_out, int out_size, void* d_ws, size_t ws_size,
                              hipStream_t stream)
{
    const float* x    = (const float*)d_in[0];
    const float* n1w  = (const float*)d_in[1];
    const float* n1b  = (const float*)d_in[2];
    const float* n2w  = (const float*)d_in[3];
    const float* n2b  = (const float*)d_in[4];
    const float* slw  = (const float*)d_in[5];
    const float* slb  = (const float*)d_in[6];
    const float* lq   = (const float*)d_in[7];
    const float* wi   = (const float*)d_in[8];
    const float* cw   = (const float*)d_in[9];
    const float* cb   = (const float*)d_in[10];
    const float* xpw  = (const float*)d_in[11];
    const float* dtw  = (const float*)d_in[12];
    const float* dtb  = (const float*)d_in[13];
    const float* alog = (const float*)d_in[14];
    const float* dvec = (const float*)d_in[15];
    const float* ow   = (const float*)d_in[16];

    float* ws = (float*)d_ws;
    unsigned short* xz    = (unsigned short*)(ws + 1572864);   // 6,291,456 f
    unsigned short* xc    = (unsigned short*)(ws + 7864320);   // 6,291,456 f
    unsigned short* dty   = (unsigned short*)(ws + 14155776);  // 6,291,456 f
    float*          bcb   = ws + 20447232;                     // 1,572,864 f
    float*          st1   = ws + 22020096;                     // 6,291,456 f (8*NCH*128*16)
    unsigned short* wallb = (unsigned short*)(ws + 28311552);  //    36,864 f
    unsigned short* wib   = (unsigned short*)(ws + 28348416);  //    32,768 f
    unsigned short* owb   = (unsigned short*)(ws + 28381184);  //    16,384 f
    float*          lam   = ws + 28397568;                     //         1

    k_wall  <<<768, 128, 0, stream>>>(dtw, xpw, lq, wi, ow, wallb, lam, wib, owb);
    k_inproj<<<dim3(384, 2), 256, 0, stream>>>(x, n1w, n1b, wib, xz);
    k_xproj <<<dim3(192, 8), 256, 0, stream>>>(xz, wallb, dtb, alog, cw, cb, xc, dty, bcb, st1);
    k_scan2 <<<1024, 512, 0, stream>>>(st1);
    k_scan3 <<<8*NCH, 128, 0, stream>>>(dty, xc, bcb, xz, st1, alog, dvec);
    k_final <<<dim3(192, 2), 256, 0, stream>>>(dty, owb, x, lam, slw, slb, n2w, n2b, (float*)d_out);
}

// Round 13
// 266.925 us; speedup vs baseline: 1.0354x; 1.0044x over previous
//
#include <hip/hip_runtime.h>
#include <math.h>

#define DIMC 128
#define LSEQ 12288
#define NB 2
#define BLR 24576   // NB*LSEQ
#define EPSV 1e-5f
#define NCH 384     // scan chunks per row
#define LC 32       // chunk length (NCH*LC = LSEQ)
#define KP 132      // LDS row pad (ushorts) for MFMA staging
#define FBP 20      // fbuf row pad (floats, 16B-aligned rows)

typedef __bf16 bf16x8 __attribute__((ext_vector_type(8)));
typedef __attribute__((ext_vector_type(4))) float f4_t;

__device__ __forceinline__ float sigf(float x){ return 1.f/(1.f+__expf(-x)); }
__device__ __forceinline__ float softplusf(float x){
    return fmaxf(x,0.f) + __logf(1.f + __expf(-fabsf(x)));
}
__device__ __forceinline__ float bf2f(unsigned short u){
    union { unsigned int i; float f; } v; v.i = ((unsigned int)u) << 16; return v.f;
}
__device__ __forceinline__ unsigned short f2bf(float f){
    union { float f; unsigned int i; } v; v.f = f;
    unsigned int b = v.i + 0x7FFFu + ((v.i >> 16) & 1u);
    return (unsigned short)(b >> 16);
}
__device__ __forceinline__ bf16x8 ld_frag8(const unsigned short* p){   // 8B-aligned LDS
    union { uint2 u[2]; bf16x8 v; } r;
    r.u[0] = *(const uint2*)(p);
    r.u[1] = *(const uint2*)(p+4);
    return r.v;
}
__device__ __forceinline__ bf16x8 ld_frag16g(const unsigned short* p){ // 16B-aligned global
    union { uint4 u; bf16x8 v; } r; r.u = *(const uint4*)p; return r.v;
}

// a[n] = exp(dtv*Av[n]).  FAST: Av[n] == (n+1)*Av[0] (detected at runtime) ->
// 1 transcendental + 7 muls instead of 8 transcendentals.
template<bool FAST>
__device__ __forceinline__ void comp_a8(float dtv, const float* Av, float* a){
    if (FAST){
        float e1 = __expf(dtv*Av[0]);
        float e2 = e1*e1, e4 = e2*e2;
        a[0]=e1; a[1]=e2; a[2]=e2*e1; a[3]=e4;
        a[4]=e4*e1; a[5]=e4*e2; a[6]=a[5]*e1; a[7]=e4*e4;
    } else {
        #pragma unroll
        for (int n = 0; n < 8; n++) a[n] = __expf(dtv*Av[n]);
    }
}

// ---------------------------------------------------------------- W_all (bf16) + lam + wi/ow->bf16 (merged)
// grid 768 x 128: blocks [0,576) build wallb; [576,768) convert wi/ow.
__global__ __launch_bounds__(128) void k_wall(const float* __restrict__ dtw, const float* __restrict__ xpw,
                       const float* __restrict__ lq, const float* __restrict__ wi, const float* __restrict__ ow,
                       unsigned short* __restrict__ wallb, float* __restrict__ lam,
                       unsigned short* __restrict__ wib, unsigned short* __restrict__ owb){
    int b = blockIdx.x, k = threadIdx.x;
    if (b < 576){
        int inst = b & 3, j = b >> 2;
        const float* xp = xpw + (size_t)inst*24*128;
        float v;
        if (j < 128){
            const float* dw = dtw + (size_t)inst*128*8 + (size_t)j*8;
            v = 0.f;
            #pragma unroll
            for (int r = 0; r < 8; r++) v += dw[r]*xp[r*128 + k];
        } else {
            v = xp[(8 + (j-128))*128 + k];
        }
        wallb[((size_t)inst*144 + j)*128 + k] = f2bf(v);
        if (b == 0 && k < 64){
            float s = lq[k] + lq[k+64];
            for (int m = 32; m; m >>= 1) s += __shfl_xor(s, m);
            if (k == 0) *lam = 1.f/(1.f+__expf(-s));
        }
    } else {
        int idx = ((b-576)*128 + k)*4;   // 192 blocks -> 98304 elems
        const float* src; unsigned short* dst; int off;
        if (idx < 65536){ src = wi;  dst = wib; off = idx; }
        else            { src = ow;  dst = owb; off = idx - 65536; }
        float4 v = *(const float4*)&src[off];
        ushort4 o; o.x=f2bf(v.x); o.y=f2bf(v.y); o.z=f2bf(v.z); o.w=f2bf(v.w);
        *(ushort4*)&dst[off] = o;
    }
}

// ---------------------------------------------------------------- FUSED: LN1 + transpose + in_proj MFMA (2-pass N)
__global__ __launch_bounds__(256,4) void k_inproj(const float* __restrict__ x,
    const float* __restrict__ w1, const float* __restrict__ b1,
    const unsigned short* __restrict__ wib, unsigned short* __restrict__ xz)
{
    __shared__ __align__(16) unsigned short As[64*KP];   // 16896 B
    __shared__ __align__(16) unsigned short ep[64*KP];   // 16896 B
    __shared__ float red1[256], red2[256];
    __shared__ float stt[128];
    const int row0 = blockIdx.x * 64;   // grid.x = 384  (row0 == bb*LSEQ + l0)
    const int bb = blockIdx.x / 192;
    const int l0 = (blockIdx.x % 192) * 64;
    const int j0 = blockIdx.y * 256;    // grid.y = 2
    const int tid = threadIdx.x;
    const int li = tid & 63, cg = tid >> 6;
    const float* xb = x + (size_t)bb*DIMC*LSEQ + l0 + li;
    // pass 1: stats (coalesced, values discarded)
    {
        float s = 0.f, s2 = 0.f;
        #pragma unroll
        for (int p = 0; p < 32; p++){
            float v = xb[(size_t)(p*4 + cg)*LSEQ];
            s += v; s2 += v*v;
        }
        red1[cg*64 + li] = s; red2[cg*64 + li] = s2;
    }
    __syncthreads();
    if (tid < 64){
        float ss = 0.f, ss2 = 0.f;
        #pragma unroll
        for (int g = 0; g < 4; g++){ ss += red1[g*64 + tid]; ss2 += red2[g*64 + tid]; }
        float mu = ss*(1.f/128.f);
        float var = ss2*(1.f/128.f) - mu*mu;
        stt[tid*2] = mu; stt[tid*2+1] = rsqrtf(var + EPSV);
    }
    __syncthreads();
    // pass 2: re-read (cache-hot), normalize, write As bf16
    {
        float mu = stt[li*2], rs = stt[li*2+1];
        #pragma unroll
        for (int p = 0; p < 32; p++){
            int c = p*4 + cg;
            float v = (xb[(size_t)c*LSEQ] - mu)*rs*w1[c] + b1[c];
            As[li*KP + c] = f2bf(v);
        }
    }
    __syncthreads();
    // ---- GEMM: two sequential 128-col passes over the same As
    const int lane = tid & 63, w = tid >> 6;
    const int m15 = lane & 15, q = lane >> 4;
    #pragma unroll
    for (int half = 0; half < 2; half++){
        const int jj = j0 + half*128;
        const unsigned short* wb = wib + ((size_t)jj + m15)*DIMC + q*8;
        bf16x8 bc[8], bn[8];
        #pragma unroll
        for (int nt = 0; nt < 8; nt++) bc[nt] = ld_frag16g(wb + nt*2048);
        f4_t zf = {0.f,0.f,0.f,0.f};
        f4_t acc[8];
        #pragma unroll
        for (int j = 0; j < 8; j++) acc[j] = zf;
        #pragma unroll
        for (int ks = 0; ks < 4; ks++){
            if (ks < 3){
                #pragma unroll
                for (int nt = 0; nt < 8; nt++) bn[nt] = ld_frag16g(wb + nt*2048 + (ks+1)*32);
            }
            bf16x8 a0 = ld_frag8(&As[(w*16 + m15)*KP + ks*32 + q*8]);
            #pragma unroll
            for (int nt = 0; nt < 8; nt++)
                acc[nt] = __builtin_amdgcn_mfma_f32_16x16x32_bf16(a0, bc[nt], acc[nt], 0,0,0);
            #pragma unroll
            for (int nt = 0; nt < 8; nt++) bc[nt] = bn[nt];
        }
        __syncthreads();   // half 0: no-op ordering; half 1: prior ep stores complete
        #pragma unroll
        for (int nt = 0; nt < 8; nt++){
            int row = w*16 + q*4;
            int col = nt*16 + m15;
            #pragma unroll
            for (int i = 0; i < 4; i++)
                ep[(row+i)*KP + col] = f2bf(acc[nt][i]);
        }
        __syncthreads();
        #pragma unroll
        for (int p = 0; p < 4; p++){
            int idx = p*256 + tid; int li2 = idx >> 4; int g = (idx & 15)*8;
            uint2 u0 = *(const uint2*)&ep[li2*KP + g];
            uint2 u1 = *(const uint2*)&ep[li2*KP + g + 4];
            uint4 o; o.x=u0.x; o.y=u0.y; o.z=u1.x; o.w=u1.y;
            *(uint4*)&xz[(size_t)(row0+li2)*512 + jj + g] = o;
        }
    }
}

// ---------------------------------------------------------------- fused scan-chunk reduce (LDS only)
// u from Zb; dt from Ep (both LDS). Ac via exp-of-sum.
template<bool FAST>
__device__ __forceinline__ void fscan(const unsigned short* __restrict__ Zb,
    const unsigned short* __restrict__ Ep, const float* __restrict__ fbuf,
    const float* Av, int ch, int d, int dim, float* Ac, float* Bc)
{
    float dts = 0.f;
    #pragma unroll 8
    for (int s = 0; s < LC; s++){
        int r = ch*32 + (d ? 31-s : s);
        float dtv = bf2f(Ep[r*KP + dim]);
        float uv  = bf2f(Zb[r*KP + dim]);
        float4 b0 = *(const float4*)&fbuf[r*FBP];
        float4 b1 = *(const float4*)&fbuf[r*FBP + 4];
        float bv[8] = {b0.x,b0.y,b0.z,b0.w,b1.x,b1.y,b1.z,b1.w};
        float du = dtv*uv;
        float a[8];
        comp_a8<FAST>(dtv, Av, a);
        #pragma unroll
        for (int n = 0; n < 8; n++)
            Bc[n] = a[n]*Bc[n] + du*bv[n];
        dts += dtv;
    }
    comp_a8<FAST>(dts, Av, Ac);
}

// ---------------------------------------------------------------- FUSED: conv+silu -> x_proj MFMA -> scan S1
// In-place conv into Zb (no As buffer); Ep LDS restored for dt (R12's global
// read-back was a measured regression: FETCH 2x, fscan on L2 latency).
__global__ __launch_bounds__(256,4) void k_xproj(const unsigned short* __restrict__ xz,
    const unsigned short* __restrict__ wallb, const float* __restrict__ dtb,
    const float* __restrict__ alog, const float* __restrict__ cw, const float* __restrict__ cbv,
    unsigned short* __restrict__ xc, unsigned short* __restrict__ dty,
    float* __restrict__ bcb, float* __restrict__ st)
{
    __shared__ __align__(16) unsigned short Zb[67*KP];   // 17688 B (xz halo -> u in place)
    __shared__ __align__(16) unsigned short Ep[64*KP];   // 16896 B (dt bf16)
    __shared__ __align__(16) float fbuf[64*FBP];         //  5120 B (B,C f32)
    const int row0 = blockIdx.x * 64;    // grid.x = 192
    const int ib   = blockIdx.y;         // 0..7
    const int inst = ib >> 1;
    const int bb   = ib & 1;
    const int m    = inst >> 1;
    const int d    = inst & 1;
    const int tid = threadIdx.x;
    const size_t abase = (size_t)ib * LSEQ * DIMC;
    const int lane = tid & 63, w = tid >> 6;
    const int m15 = lane & 15, q = lane >> 4;
    const unsigned short* wb = wallb + ((size_t)inst*144 + m15)*DIMC + q*8;
    bf16x8 bc[9], bn[9];
    #pragma unroll
    for (int nt = 0; nt < 9; nt++) bc[nt] = ld_frag16g(wb + nt*2048);
    // ---- stage xz halo tile: rows [start, start+67)
    const int start = row0 - (d ? 0 : 3);
    for (int idx = tid; idx < 67*16; idx += 256){
        int r = idx >> 4, cq = idx & 15;
        int l = start + r;
        uint4 v = make_uint4(0,0,0,0);
        if (l >= 0 && l < LSEQ)
            v = *(const uint4*)&xz[((size_t)(bb*LSEQ + l))*512 + m*256 + cq*8];
        *(uint4*)&Zb[r*KP + cq*8] = v;
    }
    __syncthreads();
    // ---- conv + silu IN PLACE: u[li] overwrites Zb row li (boundary rows preloaded)
    {
        const int dimi = tid & 127, lg = tid >> 7;
        float wk[4];
        #pragma unroll
        for (int k = 0; k < 4; k++){
            int kk = d ? 3-k : k;
            wk[k] = cw[((size_t)inst*DIMC + dimi)*4 + kk];
        }
        const float bsv = cbv[inst*DIMC + dimi];
        const int base = lg*32;
        float t0 = bf2f(Zb[(base   )*KP + dimi]);
        float t1 = bf2f(Zb[(base+1 )*KP + dimi]);
        float t2 = bf2f(Zb[(base+2 )*KP + dimi]);
        float e0 = bf2f(Zb[(base+32)*KP + dimi]);
        float e1 = bf2f(Zb[(base+33)*KP + dimi]);
        float e2 = bf2f(Zb[(base+34)*KP + dimi]);
        __syncthreads();     // all preloads done before any in-place write
        for (int p = 0; p < 29; p++){
            int li = base + p;
            float t3 = bf2f(Zb[(li+3)*KP + dimi]);
            float v = bsv + wk[0]*t0 + wk[1]*t1 + wk[2]*t2 + wk[3]*t3;
            v = v * sigf(v);
            Zb[li*KP + dimi] = f2bf(v);
            t0 = t1; t1 = t2; t2 = t3;
        }
        #pragma unroll
        for (int p = 29; p < 32; p++){
            int li = base + p;
            float t3 = (p == 29) ? e0 : (p == 30 ? e1 : e2);
            float v = bsv + wk[0]*t0 + wk[1]*t1 + wk[2]*t2 + wk[3]*t3;
            v = v * sigf(v);
            Zb[li*KP + dimi] = f2bf(v);
            t0 = t1; t1 = t2; t2 = t3;
        }
    }
    __syncthreads();        // u complete in Zb rows 0..63
    // coalesced xc store from Zb (fire-and-forget ahead of GEMM)
    #pragma unroll
    for (int p = 0; p < 4; p++){
        int idx = p*256 + tid; int li = idx >> 4; int g = (idx & 15)*8;
        uint2 u0 = *(const uint2*)&Zb[li*KP + g];
        uint2 u1 = *(const uint2*)&Zb[li*KP + g + 4];
        uint4 o; o.x=u0.x; o.y=u0.y; o.z=u1.x; o.w=u1.y;
        *(uint4*)&xc[abase + (size_t)(row0+li)*DIMC + g] = o;
    }
    f4_t zf = {0.f,0.f,0.f,0.f};
    f4_t acc[9];
    #pragma unroll
    for (int j = 0; j < 9; j++) acc[j] = zf;
    #pragma unroll
    for (int ks = 0; ks < 4; ks++){
        if (ks < 3){
            #pragma unroll
            for (int nt = 0; nt < 9; nt++) bn[nt] = ld_frag16g(wb + nt*2048 + (ks+1)*32);
        }
        bf16x8 a0 = ld_frag8(&Zb[(w*16 + m15)*KP + ks*32 + q*8]);
        #pragma unroll
        for (int nt = 0; nt < 9; nt++)
            acc[nt] = __builtin_amdgcn_mfma_f32_16x16x32_bf16(a0, bc[nt], acc[nt], 0,0,0);
        #pragma unroll
        for (int nt = 0; nt < 9; nt++) bc[nt] = bn[nt];
    }
    // B/C (acc[8]) -> fbuf ; dt (softplus) -> Ep (LDS)
    {
        int row = w*16 + q*4;
        #pragma unroll
        for (int i = 0; i < 4; i++)
            fbuf[(row+i)*FBP + m15] = acc[8][i];
    }
    #pragma unroll
    for (int nt = 0; nt < 8; nt++){
        int col = nt*16 + m15;
        float bias = dtb[inst*DIMC + col];
        int row = w*16 + q*4;
        #pragma unroll
        for (int i = 0; i < 4; i++)
            Ep[(row+i)*KP + col] = f2bf(softplusf(acc[nt][i] + bias));
    }
    __syncthreads();
    {   // coalesced bcb store
        int row = tid >> 2, j = (tid & 3)*4;
        float4 v = { fbuf[row*FBP + j], fbuf[row*FBP + j + 1],
                     fbuf[row*FBP + j + 2], fbuf[row*FBP + j + 3] };
        *(float4*)&bcb[((size_t)ib*LSEQ + row0 + row)*16 + j] = v;
    }
    #pragma unroll
    for (int p = 0; p < 4; p++){   // dty store from Ep (coalesced)
        int idx = p*256 + tid; int li = idx >> 4; int g = (idx & 15)*8;
        uint2 u0 = *(const uint2*)&Ep[li*KP + g];
        uint2 u1 = *(const uint2*)&Ep[li*KP + g + 4];
        uint4 o; o.x=u0.x; o.y=u0.y; o.z=u1.x; o.w=u1.y;
        *(uint4*)&dty[abase + (size_t)(row0+li)*DIMC + g] = o;
    }
    // ---- fused scan stage 1: thread = (chunk-half, dim)
    const int ch  = tid >> 7;            // 0..1
    const int dim = tid & 127;
    const int bc2 = row0 >> 5;
    const int c   = d ? (NCH-1 - bc2 - ch) : (bc2 + ch);
    float Av[8];
    #pragma unroll
    for (int n = 0; n < 8; n++)
        Av[n] = -__expf(alog[((size_t)inst*DIMC + dim)*8 + n]);
    bool fast = true;
    #pragma unroll
    for (int n = 1; n < 8; n++)
        fast = fast && (fabsf(Av[n] - (float)(n+1)*Av[0]) <= 1e-5f*fabsf(Av[n]));
    float Ac[8], Bc[8];
    #pragma unroll
    for (int n = 0; n < 8; n++){ Ac[n] = 1.f; Bc[n] = 0.f; }
    if (fast) fscan<true >(Zb, Ep, fbuf, Av, ch, d, dim, Ac, Bc);
    else      fscan<false>(Zb, Ep, fbuf, Av, ch, d, dim, Ac, Bc);
    float* so = st + (((size_t)ib*NCH + c)*DIMC + dim)*16;
    float4 s0 = {Ac[0],Ac[1],Ac[2],Ac[3]};
    float4 s1 = {Ac[4],Ac[5],Ac[6],Ac[7]};
    float4 s2 = {Bc[0],Bc[1],Bc[2],Bc[3]};
    float4 s3 = {Bc[4],Bc[5],Bc[6],Bc[7]};
    *(float4*)&so[0]  = s0;
    *(float4*)&so[4]  = s1;
    *(float4*)&so[8]  = s2;
    *(float4*)&so[12] = s3;
}

// ---------------------------------------------------------------- scan S2 (cross-chunk exclusive prefix, in-place)
__global__ __launch_bounds__(512) void k_scan2(float* __restrict__ st){
    const int ib   = blockIdx.x >> 7;          // grid = 8*128 = 1024
    const int dim  = blockIdx.x & 127;
    const int n    = threadIdx.x >> 6;         // wave index = state index
    const int lane = threadIdx.x & 63;
    const size_t cstride = (size_t)DIMC*16;
    const size_t base = ((size_t)ib*NCH*DIMC + dim)*16 + n;
    float a[6], b[6];
    float Al = 1.f, Bl = 0.f;
    #pragma unroll
    for (int j = 0; j < 6; j++){
        size_t o = base + (size_t)(lane*6 + j)*cstride;
        float A  = st[o];
        float Bv = st[o + 8];
        a[j] = A; b[j] = Bv;
        Bl = A*Bl + Bv;
        Al *= A;
    }
    #pragma unroll
    for (int off = 1; off < 64; off <<= 1){
        float Ao = __shfl_up(Al, off, 64);
        float Bo = __shfl_up(Bl, off, 64);
        if (lane >= off){
            Bl = Al*Bo + Bl;
            Al = Al*Ao;
        }
    }
    float h = __shfl_up(Bl, 1, 64);            // exclusive carry
    if (lane == 0) h = 0.f;
    #pragma unroll
    for (int j = 0; j < 6; j++){
        size_t o = base + (size_t)(lane*6 + j)*cstride;
        st[o] = h;
        h = a[j]*h + b[j];
    }
}

// ---------------------------------------------------------------- scan S3 (replay, y in place over dt)
template<bool FAST>
__device__ __forceinline__ void scan3_body(unsigned short* __restrict__ dty,
    const unsigned short* __restrict__ sdt, const unsigned short* __restrict__ sxc,
    const unsigned short* __restrict__ sz, const float* __restrict__ sbc,
    const float* Av, float Dv, float* h,
    size_t rbase, size_t lbase, int d, int tid)
{
    #pragma unroll 8
    for (int s = 0; s < LC; s++){
        int r = d ? 31-s : s;
        float dtv = bf2f(sdt[r*128 + tid]);
        float uv  = bf2f(sxc[r*128 + tid]);
        float zv  = bf2f(sz [r*128 + tid]);
        float4 bA = *(const float4*)&sbc[r*16];
        float4 bB = *(const float4*)&sbc[r*16 + 4];
        float4 cA = *(const float4*)&sbc[r*16 + 8];
        float4 cB = *(const float4*)&sbc[r*16 + 12];
        float bv[8] = {bA.x,bA.y,bA.z,bA.w,bB.x,bB.y,bB.z,bB.w};
        float cv[8] = {cA.x,cA.y,cA.z,cA.w,cB.x,cB.y,cB.z,cB.w};
        float du = dtv*uv;
        float y = uv*Dv;
        float a[8];
        comp_a8<FAST>(dtv, Av, a);
        #pragma unroll
        for (int n = 0; n < 8; n++){
            h[n] = a[n]*h[n] + du*bv[n];
            y += h[n]*cv[n];
        }
        y *= zv * sigf(zv);
        dty[rbase + (lbase + r)*DIMC + tid] = f2bf(y);
    }
}

__global__ __launch_bounds__(128) void k_scan3(unsigned short* __restrict__ dty,
    const unsigned short* __restrict__ xc, const float* __restrict__ bcb,
    const unsigned short* __restrict__ xz, const float* __restrict__ st,
    const float* __restrict__ alog, const float* __restrict__ dvec)
{
    __shared__ __align__(16) unsigned short sdt[32*128];   // 8 KB
    __shared__ __align__(16) unsigned short sxc[32*128];   // 8 KB
    __shared__ __align__(16) unsigned short sz [32*128];   // 8 KB
    __shared__ __align__(16) float sbc[32*16];             // 2 KB
    const int ib = blockIdx.x & 7;
    const int c  = blockIdx.x >> 3;
    const int inst = ib >> 1, bb = ib & 1;
    const int m = inst >> 1, d = inst & 1;
    const int tid = threadIdx.x;
    const size_t rbase = (size_t)ib*LSEQ*DIMC;
    const size_t zbase = (size_t)bb*LSEQ*512 + m*256 + 128;
    const size_t lbase = d ? (size_t)(LSEQ - 32 - c*32) : (size_t)(c*32);
    #pragma unroll
    for (int p = 0; p < 4; p++){
        int idx = p*128 + tid;          // 512 uint4 per 8KB array
        int r = idx >> 4, g = (idx & 15)*8;
        size_t go = rbase + (lbase + r)*DIMC + g;
        *(uint4*)&sdt[r*128 + g] = *(const uint4*)&dty[go];
        *(uint4*)&sxc[r*128 + g] = *(const uint4*)&xc[go];
        *(uint4*)&sz [r*128 + g] = *(const uint4*)&xz[zbase + (lbase + r)*512 + g];
    }
    {   // bcb: 2KB = 128 x float4
        int r = tid >> 2, j = (tid & 3)*4;
        *(float4*)&sbc[r*16 + j] = *(const float4*)&bcb[((size_t)ib*LSEQ + lbase + r)*16 + j];
    }
    float Av[8];
    #pragma unroll
    for (int n = 0; n < 8; n++)
        Av[n] = -__expf(alog[((size_t)inst*DIMC + tid)*8 + n]);
    bool fast = true;
    #pragma unroll
    for (int n = 1; n < 8; n++)
        fast = fast && (fabsf(Av[n] - (float)(n+1)*Av[0]) <= 1e-5f*fabsf(Av[n]));
    const float Dv = dvec[inst*DIMC + tid];
    float h[8];
    const float* hp = st + (((size_t)ib*NCH + c)*DIMC + tid)*16;
    #pragma unroll
    for (int n = 0; n < 8; n++) h[n] = hp[n];
    __syncthreads();
    if (fast) scan3_body<true >(dty, sdt, sxc, sz, sbc, Av, Dv, h, rbase, lbase, d, tid);
    else      scan3_body<false>(dty, sdt, sxc, sz, sbc, Av, Dv, h, rbase, lbase, d, tid);
}

// ---------------------------------------------------------------- out_proj MFMA + diff + LN + add x + LN + T-store
__global__ __launch_bounds__(256,4) void k_final(const unsigned short* __restrict__ y,
    const unsigned short* __restrict__ owb, const float* __restrict__ x, const float* __restrict__ lamp,
    const float* __restrict__ sw, const float* __restrict__ sb,
    const float* __restrict__ n2w, const float* __restrict__ n2b, float* __restrict__ outp)
{
    __shared__ __align__(16) char smem[36352];
    unsigned short* Ast = (unsigned short*)smem;             // phase 1: [2*64][KP] = 33792 B
    float* yt            = (float*)smem;                     // phase 2: [64][129] f32 = 33024 B (aliases Ast)
    float* red1          = (float*)(smem + 33792);           // 1024 B
    float* red2          = (float*)(smem + 34816);           // 1024 B
    float* stt           = (float*)(smem + 35840);           //  512 B
    const int bb = blockIdx.y;
    const int l0 = blockIdx.x * 64;                  // grid.x = 192
    const int tid = threadIdx.x;
    const float lam = *lamp;
    #pragma unroll
    for (int p = 0; p < 8; p++){
        int idx = p*256 + tid; int mm = idx >> 10; int li = (idx >> 4) & 63; int g = (idx & 15)*8;
        uint4 vf = *(const uint4*)&y[(((size_t)(mm*2+0)*NB + bb)*LSEQ + l0 + li)*DIMC + g];
        uint4 vb = *(const uint4*)&y[(((size_t)(mm*2+1)*NB + bb)*LSEQ + l0 + li)*DIMC + g];
        const unsigned short* uf = (const unsigned short*)&vf;
        const unsigned short* ub = (const unsigned short*)&vb;
        unsigned short o[8];
        #pragma unroll
        for (int j = 0; j < 8; j++) o[j] = f2bf(bf2f(uf[j]) + bf2f(ub[j]));
        *(uint2*)&Ast[(mm*64 + li)*KP + g]     = *(uint2*)&o[0];
        *(uint2*)&Ast[(mm*64 + li)*KP + g + 4] = *(uint2*)&o[4];
    }
    __syncthreads();
    const int lane = tid & 63, w = tid >> 6;
    const int m15 = lane & 15, q = lane >> 4;
    f4_t zf = {0.f,0.f,0.f,0.f};
    f4_t acc[2][8];
    #pragma unroll
    for (int i = 0; i < 2; i++)
        #pragma unroll
        for (int j = 0; j < 8; j++) acc[i][j] = zf;
    #pragma unroll
    for (int ks = 0; ks < 4; ks++){
        int k0 = ks*32 + q*8;
        bf16x8 a0 = ld_frag8(&Ast[(       w*16 + m15)*KP + k0]);
        bf16x8 a1 = ld_frag8(&Ast[(64   + w*16 + m15)*KP + k0]);
        #pragma unroll
        for (int nt = 0; nt < 8; nt++){
            bf16x8 b0 = ld_frag16g(&owb[((size_t)0*DIMC + nt*16 + m15)*DIMC + k0]);
            bf16x8 b1 = ld_frag16g(&owb[((size_t)1*DIMC + nt*16 + m15)*DIMC + k0]);
            acc[0][nt] = __builtin_amdgcn_mfma_f32_16x16x32_bf16(a0, b0, acc[0][nt], 0,0,0);
            acc[1][nt] = __builtin_amdgcn_mfma_f32_16x16x32_bf16(a1, b1, acc[1][nt], 0,0,0);
        }
    }
    __syncthreads();
    #pragma unroll
    for (int nt = 0; nt < 8; nt++){
        int row = w*16 + q*4;
        int col = nt*16 + m15;
        #pragma unroll
        for (int i = 0; i < 4; i++)
            yt[(row+i)*129 + col] = acc[0][nt][i] - lam*acc[1][nt][i];
    }
    __syncthreads();
    const int r = tid & 63, g = tid >> 6;
    float s = 0.f, s2 = 0.f;
    #pragma unroll
    for (int k = 0; k < 32; k++){ float v = yt[r*129 + g*32 + k]; s += v; s2 += v*v; }
    red1[g*64 + r] = s; red2[g*64 + r] = s2;
    __syncthreads();
    if (tid < 64){
        float ss = 0.f, ss2 = 0.f;
        #pragma unroll
        for (int gg = 0; gg < 4; gg++){ ss += red1[gg*64 + tid]; ss2 += red2[gg*64 + tid]; }
        float mu = ss*(1.f/128.f);
        float var = ss2*(1.f/128.f) - mu*mu;
        stt[tid*2] = mu; stt[tid*2+1] = rsqrtf(var + EPSV);
    }
    __syncthreads();
    float mu1 = stt[r*2], rs1 = stt[r*2+1];
    s = 0.f; s2 = 0.f;
    #pragma unroll
    for (int k = 0; k < 32; k++){
        int c = g*32 + k;
        float v = (yt[r*129+c] - mu1)*rs1*sw[c] + sb[c]
                + x[(size_t)bb*DIMC*LSEQ + (size_t)c*LSEQ + l0 + r];
        yt[r*129+c] = v;
        s += v; s2 += v*v;
    }
    __syncthreads();
    red1[g*64 + r] = s; red2[g*64 + r] = s2;
    __syncthreads();
    if (tid < 64){
        float ss = 0.f, ss2 = 0.f;
        #pragma unroll
        for (int gg = 0; gg < 4; gg++){ ss += red1[gg*64 + tid]; ss2 += red2[gg*64 + tid]; }
        float mu = ss*(1.f/128.f);
        float var = ss2*(1.f/128.f) - mu*mu;
        stt[tid*2] = mu; stt[tid*2+1] = rsqrtf(var + EPSV);
    }
    __syncthreads();
    float mu2 = stt[r*2], rs2 = stt[r*2+1];
    #pragma unroll
    for (int k = 0; k < 32; k++){
        int c = g*32 + k;
        float o = (yt[r*129+c] - mu2)*rs2*n2w[c] + n2b[c];
        outp[(size_t)bb*DIMC*LSEQ + (size_t)c*LSEQ + l0 + r] = o;
    }
}

// ----------------------------------------------------------------
extern "C" void kernel_launch(void* const* d_in, const int* in_sizes, int n_in,
                              void* d_out, int out_size, void* d_ws, size_t ws_size,
                              hipStream_t stream)
{
    const float* x    = (const float*)d_in[0];
    const float* n1w  = (const float*)d_in[1];
    const float* n1b  = (const float*)d_in[2];
    const float* n2w  = (const float*)d_in[3];
    const float* n2b  = (const float*)d_in[4];
    const float* slw  = (const float*)d_in[5];
    const float* slb  = (const float*)d_in[6];
    const float* lq   = (const float*)d_in[7];
    const float* wi   = (const float*)d_in[8];
    const float* cw   = (const float*)d_in[9];
    const float* cb   = (const float*)d_in[10];
    const float* xpw  = (const float*)d_in[11];
    const float* dtw  = (const float*)d_in[12];
    const float* dtb  = (const float*)d_in[13];
    const float* alog = (const float*)d_in[14];
    const float* dvec = (const float*)d_in[15];
    const float* ow   = (const float*)d_in[16];

    float* ws = (float*)d_ws;
    unsigned short* xz    = (unsigned short*)(ws + 1572864);   // 6,291,456 f
    unsigned short* xc    = (unsigned short*)(ws + 7864320);   // 6,291,456 f
    unsigned short* dty   = (unsigned short*)(ws + 14155776);  // 6,291,456 f
    float*          bcb   = ws + 20447232;                     // 1,572,864 f
    float*          st1   = ws + 22020096;                     // 6,291,456 f (8*NCH*128*16)
    unsigned short* wallb = (unsigned short*)(ws + 28311552);  //    36,864 f
    unsigned short* wib   = (unsigned short*)(ws + 28348416);  //    32,768 f
    unsigned short* owb   = (unsigned short*)(ws + 28381184);  //    16,384 f
    float*          lam   = ws + 28397568;                     //         1

    k_wall  <<<768, 128, 0, stream>>>(dtw, xpw, lq, wi, ow, wallb, lam, wib, owb);
    k_inproj<<<dim3(384, 2), 256, 0, stream>>>(x, n1w, n1b, wib, xz);
    k_xproj <<<dim3(192, 8), 256, 0, stream>>>(xz, wallb, dtb, alog, cw, cb, xc, dty, bcb, st1);
    k_scan2 <<<1024, 512, 0, stream>>>(st1);
    k_scan3 <<<8*NCH, 128, 0, stream>>>(dty, xc, bcb, xz, st1, alog, dvec);
    k_final <<<dim3(192, 2), 256, 0, stream>>>(dty, owb, x, lam, slw, slb, n2w, n2b, (float*)d_out);
}

// Round 14
// 265.795 us; speedup vs baseline: 1.0398x; 1.0043x over previous
//
#include <hip/hip_runtime.h>
#include <math.h>

#define DIMC 128
#define LSEQ 12288
#define NB 2
#define BLR 24576   // NB*LSEQ
#define EPSV 1e-5f
#define NCH 384     // scan chunks per row
#define LC 32       // chunk length (NCH*LC = LSEQ)
#define KP 132      // LDS row pad (ushorts) for MFMA staging
#define FBP 20      // fbuf row pad (floats, 16B-aligned rows)

typedef __bf16 bf16x8 __attribute__((ext_vector_type(8)));
typedef __attribute__((ext_vector_type(4))) float f4_t;

__device__ __forceinline__ float sigf(float x){ return 1.f/(1.f+__expf(-x)); }
__device__ __forceinline__ float softplusf(float x){
    return fmaxf(x,0.f) + __logf(1.f + __expf(-fabsf(x)));
}
__device__ __forceinline__ float bf2f(unsigned short u){
    union { unsigned int i; float f; } v; v.i = ((unsigned int)u) << 16; return v.f;
}
__device__ __forceinline__ unsigned short f2bf(float f){
    union { float f; unsigned int i; } v; v.f = f;
    unsigned int b = v.i + 0x7FFFu + ((v.i >> 16) & 1u);
    return (unsigned short)(b >> 16);
}
__device__ __forceinline__ bf16x8 ld_frag8(const unsigned short* p){   // 8B-aligned LDS
    union { uint2 u[2]; bf16x8 v; } r;
    r.u[0] = *(const uint2*)(p);
    r.u[1] = *(const uint2*)(p+4);
    return r.v;
}
__device__ __forceinline__ bf16x8 ld_frag16g(const unsigned short* p){ // 16B-aligned global
    union { uint4 u; bf16x8 v; } r; r.u = *(const uint4*)p; return r.v;
}

// a[n] = exp(dtv*Av[n]).  FAST: Av[n] == (n+1)*Av[0] (detected at runtime) ->
// 1 transcendental + 7 muls instead of 8 transcendentals.
template<bool FAST>
__device__ __forceinline__ void comp_a8(float dtv, const float* Av, float* a){
    if (FAST){
        float e1 = __expf(dtv*Av[0]);
        float e2 = e1*e1, e4 = e2*e2;
        a[0]=e1; a[1]=e2; a[2]=e2*e1; a[3]=e4;
        a[4]=e4*e1; a[5]=e4*e2; a[6]=a[5]*e1; a[7]=e4*e4;
    } else {
        #pragma unroll
        for (int n = 0; n < 8; n++) a[n] = __expf(dtv*Av[n]);
    }
}

// ---------------------------------------------------------------- W_all (bf16) + lam + wi/ow->bf16 (merged)
// grid 768 x 128: blocks [0,576) build wallb; [576,768) convert wi/ow.
__global__ __launch_bounds__(128) void k_wall(const float* __restrict__ dtw, const float* __restrict__ xpw,
                       const float* __restrict__ lq, const float* __restrict__ wi, const float* __restrict__ ow,
                       unsigned short* __restrict__ wallb, float* __restrict__ lam,
                       unsigned short* __restrict__ wib, unsigned short* __restrict__ owb){
    int b = blockIdx.x, k = threadIdx.x;
    if (b < 576){
        int inst = b & 3, j = b >> 2;
        const float* xp = xpw + (size_t)inst*24*128;
        float v;
        if (j < 128){
            const float* dw = dtw + (size_t)inst*128*8 + (size_t)j*8;
            v = 0.f;
            #pragma unroll
            for (int r = 0; r < 8; r++) v += dw[r]*xp[r*128 + k];
        } else {
            v = xp[(8 + (j-128))*128 + k];
        }
        wallb[((size_t)inst*144 + j)*128 + k] = f2bf(v);
        if (b == 0 && k < 64){
            float s = lq[k] + lq[k+64];
            for (int m = 32; m; m >>= 1) s += __shfl_xor(s, m);
            if (k == 0) *lam = 1.f/(1.f+__expf(-s));
        }
    } else {
        int idx = ((b-576)*128 + k)*4;   // 192 blocks -> 98304 elems
        const float* src; unsigned short* dst; int off;
        if (idx < 65536){ src = wi;  dst = wib; off = idx; }
        else            { src = ow;  dst = owb; off = idx - 65536; }
        float4 v = *(const float4*)&src[off];
        ushort4 o; o.x=f2bf(v.x); o.y=f2bf(v.y); o.z=f2bf(v.z); o.w=f2bf(v.w);
        *(ushort4*)&dst[off] = o;
    }
}

// ---------------------------------------------------------------- FUSED: LN1 + transpose + in_proj MFMA (2-pass N)
__global__ __launch_bounds__(256,4) void k_inproj(const float* __restrict__ x,
    const float* __restrict__ w1, const float* __restrict__ b1,
    const unsigned short* __restrict__ wib, unsigned short* __restrict__ xz)
{
    __shared__ __align__(16) unsigned short As[64*KP];   // 16896 B
    __shared__ __align__(16) unsigned short ep[64*KP];   // 16896 B
    __shared__ float red1[256], red2[256];
    __shared__ float stt[128];
    const int row0 = blockIdx.x * 64;   // grid.x = 384  (row0 == bb*LSEQ + l0)
    const int bb = blockIdx.x / 192;
    const int l0 = (blockIdx.x % 192) * 64;
    const int j0 = blockIdx.y * 256;    // grid.y = 2
    const int tid = threadIdx.x;
    const int li = tid & 63, cg = tid >> 6;
    const float* xb = x + (size_t)bb*DIMC*LSEQ + l0 + li;
    // pass 1: stats (coalesced, values discarded)
    {
        float s = 0.f, s2 = 0.f;
        #pragma unroll
        for (int p = 0; p < 32; p++){
            float v = xb[(size_t)(p*4 + cg)*LSEQ];
            s += v; s2 += v*v;
        }
        red1[cg*64 + li] = s; red2[cg*64 + li] = s2;
    }
    __syncthreads();
    if (tid < 64){
        float ss = 0.f, ss2 = 0.f;
        #pragma unroll
        for (int g = 0; g < 4; g++){ ss += red1[g*64 + tid]; ss2 += red2[g*64 + tid]; }
        float mu = ss*(1.f/128.f);
        float var = ss2*(1.f/128.f) - mu*mu;
        stt[tid*2] = mu; stt[tid*2+1] = rsqrtf(var + EPSV);
    }
    __syncthreads();
    // pass 2: re-read (cache-hot), normalize, write As bf16
    {
        float mu = stt[li*2], rs = stt[li*2+1];
        #pragma unroll
        for (int p = 0; p < 32; p++){
            int c = p*4 + cg;
            float v = (xb[(size_t)c*LSEQ] - mu)*rs*w1[c] + b1[c];
            As[li*KP + c] = f2bf(v);
        }
    }
    __syncthreads();
    // ---- GEMM: two sequential 128-col passes over the same As
    const int lane = tid & 63, w = tid >> 6;
    const int m15 = lane & 15, q = lane >> 4;
    #pragma unroll
    for (int half = 0; half < 2; half++){
        const int jj = j0 + half*128;
        const unsigned short* wb = wib + ((size_t)jj + m15)*DIMC + q*8;
        bf16x8 bc[8], bn[8];
        #pragma unroll
        for (int nt = 0; nt < 8; nt++) bc[nt] = ld_frag16g(wb + nt*2048);
        f4_t zf = {0.f,0.f,0.f,0.f};
        f4_t acc[8];
        #pragma unroll
        for (int j = 0; j < 8; j++) acc[j] = zf;
        #pragma unroll
        for (int ks = 0; ks < 4; ks++){
            if (ks < 3){
                #pragma unroll
                for (int nt = 0; nt < 8; nt++) bn[nt] = ld_frag16g(wb + nt*2048 + (ks+1)*32);
            }
            bf16x8 a0 = ld_frag8(&As[(w*16 + m15)*KP + ks*32 + q*8]);
            #pragma unroll
            for (int nt = 0; nt < 8; nt++)
                acc[nt] = __builtin_amdgcn_mfma_f32_16x16x32_bf16(a0, bc[nt], acc[nt], 0,0,0);
            #pragma unroll
            for (int nt = 0; nt < 8; nt++) bc[nt] = bn[nt];
        }
        __syncthreads();   // half 0: no-op ordering; half 1: prior ep stores complete
        #pragma unroll
        for (int nt = 0; nt < 8; nt++){
            int row = w*16 + q*4;
            int col = nt*16 + m15;
            #pragma unroll
            for (int i = 0; i < 4; i++)
                ep[(row+i)*KP + col] = f2bf(acc[nt][i]);
        }
        __syncthreads();
        #pragma unroll
        for (int p = 0; p < 4; p++){
            int idx = p*256 + tid; int li2 = idx >> 4; int g = (idx & 15)*8;
            uint2 u0 = *(const uint2*)&ep[li2*KP + g];
            uint2 u1 = *(const uint2*)&ep[li2*KP + g + 4];
            uint4 o; o.x=u0.x; o.y=u0.y; o.z=u1.x; o.w=u1.y;
            *(uint4*)&xz[(size_t)(row0+li2)*512 + jj + g] = o;
        }
    }
}

// ---------------------------------------------------------------- fused scan-chunk reduce (LDS only)
// u from As; dt from Ep (both LDS). Ac via exp-of-sum.
template<bool FAST>
__device__ __forceinline__ void fscan(const unsigned short* __restrict__ As,
    const unsigned short* __restrict__ Ep, const float* __restrict__ fbuf,
    const float* Av, int ch, int d, int dim, float* Ac, float* Bc)
{
    float dts = 0.f;
    #pragma unroll 8
    for (int s = 0; s < LC; s++){
        int r = ch*32 + (d ? 31-s : s);
        float dtv = bf2f(Ep[r*KP + dim]);
        float uv  = bf2f(As[r*KP + dim]);
        float4 b0 = *(const float4*)&fbuf[r*FBP];
        float4 b1 = *(const float4*)&fbuf[r*FBP + 4];
        float bv[8] = {b0.x,b0.y,b0.z,b0.w,b1.x,b1.y,b1.z,b1.w};
        float du = dtv*uv;
        float a[8];
        comp_a8<FAST>(dtv, Av, a);
        #pragma unroll
        for (int n = 0; n < 8; n++)
            Bc[n] = a[n]*Bc[n] + du*bv[n];
        dts += dtv;
    }
    comp_a8<FAST>(dts, Av, Ac);
}

// ---------------------------------------------------------------- FUSED: conv+silu -> x_proj MFMA -> scan S1
// R8 structure (best measured: 54.2us): rolling-window conv Zb->As (no mid-conv
// barrier), Ep aliases Zb after the last Zb read, fscan reads As/Ep/fbuf.
__global__ __launch_bounds__(256,4) void k_xproj(const unsigned short* __restrict__ xz,
    const unsigned short* __restrict__ wallb, const float* __restrict__ dtb,
    const float* __restrict__ alog, const float* __restrict__ cw, const float* __restrict__ cbv,
    unsigned short* __restrict__ xc, unsigned short* __restrict__ dty,
    float* __restrict__ bcb, float* __restrict__ st)
{
    __shared__ __align__(16) unsigned short As[64*KP];   // 16896 B (u, stays intact)
    __shared__ __align__(16) unsigned short Zb[67*KP];   // 17688 B (xz halo tile; later Ep)
    __shared__ __align__(16) float fbuf[64*FBP];         //  5120 B (B,C f32)
    const int row0 = blockIdx.x * 64;    // grid.x = 192
    const int ib   = blockIdx.y;         // 0..7
    const int inst = ib >> 1;
    const int bb   = ib & 1;
    const int m    = inst >> 1;
    const int d    = inst & 1;
    const int tid = threadIdx.x;
    const size_t abase = (size_t)ib * LSEQ * DIMC;
    const int lane = tid & 63, w = tid >> 6;
    const int m15 = lane & 15, q = lane >> 4;
    const unsigned short* wb = wallb + ((size_t)inst*144 + m15)*DIMC + q*8;
    bf16x8 bc[9], bn[9];
    #pragma unroll
    for (int nt = 0; nt < 9; nt++) bc[nt] = ld_frag16g(wb + nt*2048);
    // ---- stage xz halo tile: rows [start, start+67)
    const int start = row0 - (d ? 0 : 3);
    for (int idx = tid; idx < 67*16; idx += 256){
        int r = idx >> 4, cq = idx & 15;
        int l = start + r;
        uint4 v = make_uint4(0,0,0,0);
        if (l >= 0 && l < LSEQ)
            v = *(const uint4*)&xz[((size_t)(bb*LSEQ + l))*512 + m*256 + cq*8];
        *(uint4*)&Zb[r*KP + cq*8] = v;
    }
    __syncthreads();
    // ---- conv + silu -> As, rolling window (li = lg*32 + p): 35 LDS reads not 128
    {
        const int dimi = tid & 127, lg = tid >> 7;
        float wk[4];
        #pragma unroll
        for (int k = 0; k < 4; k++){
            int kk = d ? 3-k : k;
            wk[k] = cw[((size_t)inst*DIMC + dimi)*4 + kk];
        }
        const float bsv = cbv[inst*DIMC + dimi];
        const int base = lg*32;
        float t0 = bf2f(Zb[(base  )*KP + dimi]);
        float t1 = bf2f(Zb[(base+1)*KP + dimi]);
        float t2 = bf2f(Zb[(base+2)*KP + dimi]);
        for (int p = 0; p < 32; p++){
            int li = base + p;
            float t3 = bf2f(Zb[(li+3)*KP + dimi]);
            float v = bsv + wk[0]*t0 + wk[1]*t1 + wk[2]*t2 + wk[3]*t3;
            v = v * sigf(v);
            As[li*KP + dimi] = f2bf(v);
            t0 = t1; t1 = t2; t2 = t3;
        }
    }
    __syncthreads();        // As ready; all Zb reads done (Ep alias safe after this)
    // coalesced xc store from As (fire-and-forget ahead of GEMM)
    #pragma unroll
    for (int p = 0; p < 4; p++){
        int idx = p*256 + tid; int li = idx >> 4; int g = (idx & 15)*8;
        uint2 u0 = *(const uint2*)&As[li*KP + g];
        uint2 u1 = *(const uint2*)&As[li*KP + g + 4];
        uint4 o; o.x=u0.x; o.y=u0.y; o.z=u1.x; o.w=u1.y;
        *(uint4*)&xc[abase + (size_t)(row0+li)*DIMC + g] = o;
    }
    f4_t zf = {0.f,0.f,0.f,0.f};
    f4_t acc[9];
    #pragma unroll
    for (int j = 0; j < 9; j++) acc[j] = zf;
    #pragma unroll
    for (int ks = 0; ks < 4; ks++){
        if (ks < 3){
            #pragma unroll
            for (int nt = 0; nt < 9; nt++) bn[nt] = ld_frag16g(wb + nt*2048 + (ks+1)*32);
        }
        bf16x8 a0 = ld_frag8(&As[(w*16 + m15)*KP + ks*32 + q*8]);
        #pragma unroll
        for (int nt = 0; nt < 9; nt++)
            acc[nt] = __builtin_amdgcn_mfma_f32_16x16x32_bf16(a0, bc[nt], acc[nt], 0,0,0);
        #pragma unroll
        for (int nt = 0; nt < 9; nt++) bc[nt] = bn[nt];
    }
    // stage B/C (acc[8]) -> fbuf ; dt (softplus) -> Ep (aliases Zb).
    unsigned short* Ep = Zb;
    {
        int row = w*16 + q*4;
        #pragma unroll
        for (int i = 0; i < 4; i++)
            fbuf[(row+i)*FBP + m15] = acc[8][i];
    }
    #pragma unroll
    for (int nt = 0; nt < 8; nt++){
        int col = nt*16 + m15;
        float bias = dtb[inst*DIMC + col];
        int row = w*16 + q*4;
        #pragma unroll
        for (int i = 0; i < 4; i++)
            Ep[(row+i)*KP + col] = f2bf(softplusf(acc[nt][i] + bias));
    }
    __syncthreads();
    {   // coalesced bcb store
        int row = tid >> 2, j = (tid & 3)*4;
        float4 v = { fbuf[row*FBP + j], fbuf[row*FBP + j + 1],
                     fbuf[row*FBP + j + 2], fbuf[row*FBP + j + 3] };
        *(float4*)&bcb[((size_t)ib*LSEQ + row0 + row)*16 + j] = v;
    }
    #pragma unroll
    for (int p = 0; p < 4; p++){   // dty store from Ep (coalesced)
        int idx = p*256 + tid; int li = idx >> 4; int g = (idx & 15)*8;
        uint2 u0 = *(const uint2*)&Ep[li*KP + g];
        uint2 u1 = *(const uint2*)&Ep[li*KP + g + 4];
        uint4 o; o.x=u0.x; o.y=u0.y; o.z=u1.x; o.w=u1.y;
        *(uint4*)&dty[abase + (size_t)(row0+li)*DIMC + g] = o;
    }
    // ---- fused scan stage 1: thread = (chunk-half, dim)
    const int ch  = tid >> 7;            // 0..1
    const int dim = tid & 127;
    const int bc2 = row0 >> 5;
    const int c   = d ? (NCH-1 - bc2 - ch) : (bc2 + ch);
    float Av[8];
    #pragma unroll
    for (int n = 0; n < 8; n++)
        Av[n] = -__expf(alog[((size_t)inst*DIMC + dim)*8 + n]);
    bool fast = true;
    #pragma unroll
    for (int n = 1; n < 8; n++)
        fast = fast && (fabsf(Av[n] - (float)(n+1)*Av[0]) <= 1e-5f*fabsf(Av[n]));
    float Ac[8], Bc[8];
    #pragma unroll
    for (int n = 0; n < 8; n++){ Ac[n] = 1.f; Bc[n] = 0.f; }
    if (fast) fscan<true >(As, Ep, fbuf, Av, ch, d, dim, Ac, Bc);
    else      fscan<false>(As, Ep, fbuf, Av, ch, d, dim, Ac, Bc);
    float* so = st + (((size_t)ib*NCH + c)*DIMC + dim)*16;
    float4 s0 = {Ac[0],Ac[1],Ac[2],Ac[3]};
    float4 s1 = {Ac[4],Ac[5],Ac[6],Ac[7]};
    float4 s2 = {Bc[0],Bc[1],Bc[2],Bc[3]};
    float4 s3 = {Bc[4],Bc[5],Bc[6],Bc[7]};
    *(float4*)&so[0]  = s0;
    *(float4*)&so[4]  = s1;
    *(float4*)&so[8]  = s2;
    *(float4*)&so[12] = s3;
}

// ---------------------------------------------------------------- scan S2 (cross-chunk exclusive prefix, in-place)
__global__ __launch_bounds__(512) void k_scan2(float* __restrict__ st){
    const int ib   = blockIdx.x >> 7;          // grid = 8*128 = 1024
    const int dim  = blockIdx.x & 127;
    const int n    = threadIdx.x >> 6;         // wave index = state index
    const int lane = threadIdx.x & 63;
    const size_t cstride = (size_t)DIMC*16;
    const size_t base = ((size_t)ib*NCH*DIMC + dim)*16 + n;
    float a[6], b[6];
    float Al = 1.f, Bl = 0.f;
    #pragma unroll
    for (int j = 0; j < 6; j++){
        size_t o = base + (size_t)(lane*6 + j)*cstride;
        float A  = st[o];
        float Bv = st[o + 8];
        a[j] = A; b[j] = Bv;
        Bl = A*Bl + Bv;
        Al *= A;
    }
    #pragma unroll
    for (int off = 1; off < 64; off <<= 1){
        float Ao = __shfl_up(Al, off, 64);
        float Bo = __shfl_up(Bl, off, 64);
        if (lane >= off){
            Bl = Al*Bo + Bl;
            Al = Al*Ao;
        }
    }
    float h = __shfl_up(Bl, 1, 64);            // exclusive carry
    if (lane == 0) h = 0.f;
    #pragma unroll
    for (int j = 0; j < 6; j++){
        size_t o = base + (size_t)(lane*6 + j)*cstride;
        st[o] = h;
        h = a[j]*h + b[j];
    }
}

// ---------------------------------------------------------------- scan S3 (replay, y in place over dt)
template<bool FAST>
__device__ __forceinline__ void scan3_body(unsigned short* __restrict__ dty,
    const unsigned short* __restrict__ sdt, const unsigned short* __restrict__ sxc,
    const unsigned short* __restrict__ sz, const float* __restrict__ sbc,
    const float* Av, float Dv, float* h,
    size_t rbase, size_t lbase, int d, int tid)
{
    #pragma unroll 8
    for (int s = 0; s < LC; s++){
        int r = d ? 31-s : s;
        float dtv = bf2f(sdt[r*128 + tid]);
        float uv  = bf2f(sxc[r*128 + tid]);
        float zv  = bf2f(sz [r*128 + tid]);
        float4 bA = *(const float4*)&sbc[r*16];
        float4 bB = *(const float4*)&sbc[r*16 + 4];
        float4 cA = *(const float4*)&sbc[r*16 + 8];
        float4 cB = *(const float4*)&sbc[r*16 + 12];
        float bv[8] = {bA.x,bA.y,bA.z,bA.w,bB.x,bB.y,bB.z,bB.w};
        float cv[8] = {cA.x,cA.y,cA.z,cA.w,cB.x,cB.y,cB.z,cB.w};
        float du = dtv*uv;
        float y = uv*Dv;
        float a[8];
        comp_a8<FAST>(dtv, Av, a);
        #pragma unroll
        for (int n = 0; n < 8; n++){
            h[n] = a[n]*h[n] + du*bv[n];
            y += h[n]*cv[n];
        }
        y *= zv * sigf(zv);
        dty[rbase + (lbase + r)*DIMC + tid] = f2bf(y);
    }
}

__global__ __launch_bounds__(128) void k_scan3(unsigned short* __restrict__ dty,
    const unsigned short* __restrict__ xc, const float* __restrict__ bcb,
    const unsigned short* __restrict__ xz, const float* __restrict__ st,
    const float* __restrict__ alog, const float* __restrict__ dvec)
{
    __shared__ __align__(16) unsigned short sdt[32*128];   // 8 KB
    __shared__ __align__(16) unsigned short sxc[32*128];   // 8 KB
    __shared__ __align__(16) unsigned short sz [32*128];   // 8 KB
    __shared__ __align__(16) float sbc[32*16];             // 2 KB
    const int ib = blockIdx.x & 7;
    const int c  = blockIdx.x >> 3;
    const int inst = ib >> 1, bb = ib & 1;
    const int m = inst >> 1, d = inst & 1;
    const int tid = threadIdx.x;
    const size_t rbase = (size_t)ib*LSEQ*DIMC;
    const size_t zbase = (size_t)bb*LSEQ*512 + m*256 + 128;
    const size_t lbase = d ? (size_t)(LSEQ - 32 - c*32) : (size_t)(c*32);
    #pragma unroll
    for (int p = 0; p < 4; p++){
        int idx = p*128 + tid;          // 512 uint4 per 8KB array
        int r = idx >> 4, g = (idx & 15)*8;
        size_t go = rbase + (lbase + r)*DIMC + g;
        *(uint4*)&sdt[r*128 + g] = *(const uint4*)&dty[go];
        *(uint4*)&sxc[r*128 + g] = *(const uint4*)&xc[go];
        *(uint4*)&sz [r*128 + g] = *(const uint4*)&xz[zbase + (lbase + r)*512 + g];
    }
    {   // bcb: 2KB = 128 x float4
        int r = tid >> 2, j = (tid & 3)*4;
        *(float4*)&sbc[r*16 + j] = *(const float4*)&bcb[((size_t)ib*LSEQ + lbase + r)*16 + j];
    }
    float Av[8];
    #pragma unroll
    for (int n = 0; n < 8; n++)
        Av[n] = -__expf(alog[((size_t)inst*DIMC + tid)*8 + n]);
    bool fast = true;
    #pragma unroll
    for (int n = 1; n < 8; n++)
        fast = fast && (fabsf(Av[n] - (float)(n+1)*Av[0]) <= 1e-5f*fabsf(Av[n]));
    const float Dv = dvec[inst*DIMC + tid];
    float h[8];
    const float* hp = st + (((size_t)ib*NCH + c)*DIMC + tid)*16;
    #pragma unroll
    for (int n = 0; n < 8; n++) h[n] = hp[n];
    __syncthreads();
    if (fast) scan3_body<true >(dty, sdt, sxc, sz, sbc, Av, Dv, h, rbase, lbase, d, tid);
    else      scan3_body<false>(dty, sdt, sxc, sz, sbc, Av, Dv, h, rbase, lbase, d, tid);
}

// ---------------------------------------------------------------- out_proj MFMA + diff + LN + add x + LN + T-store
__global__ __launch_bounds__(256,4) void k_final(const unsigned short* __restrict__ y,
    const unsigned short* __restrict__ owb, const float* __restrict__ x, const float* __restrict__ lamp,
    const float* __restrict__ sw, const float* __restrict__ sb,
    const float* __restrict__ n2w, const float* __restrict__ n2b, float* __restrict__ outp)
{
    __shared__ __align__(16) char smem[36352];
    unsigned short* Ast = (unsigned short*)smem;             // phase 1: [2*64][KP] = 33792 B
    float* yt            = (float*)smem;                     // phase 2: [64][129] f32 = 33024 B (aliases Ast)
    float* red1          = (float*)(smem + 33792);           // 1024 B
    float* red2          = (float*)(smem + 34816);           // 1024 B
    float* stt           = (float*)(smem + 35840);           //  512 B
    const int bb = blockIdx.y;
    const int l0 = blockIdx.x * 64;                  // grid.x = 192
    const int tid = threadIdx.x;
    const float lam = *lamp;
    #pragma unroll
    for (int p = 0; p < 8; p++){
        int idx = p*256 + tid; int mm = idx >> 10; int li = (idx >> 4) & 63; int g = (idx & 15)*8;
        uint4 vf = *(const uint4*)&y[(((size_t)(mm*2+0)*NB + bb)*LSEQ + l0 + li)*DIMC + g];
        uint4 vb = *(const uint4*)&y[(((size_t)(mm*2+1)*NB + bb)*LSEQ + l0 + li)*DIMC + g];
        const unsigned short* uf = (const unsigned short*)&vf;
        const unsigned short* ub = (const unsigned short*)&vb;
        unsigned short o[8];
        #pragma unroll
        for (int j = 0; j < 8; j++) o[j] = f2bf(bf2f(uf[j]) + bf2f(ub[j]));
        *(uint2*)&Ast[(mm*64 + li)*KP + g]     = *(uint2*)&o[0];
        *(uint2*)&Ast[(mm*64 + li)*KP + g + 4] = *(uint2*)&o[4];
    }
    __syncthreads();
    const int lane = tid & 63, w = tid >> 6;
    const int m15 = lane & 15, q = lane >> 4;
    f4_t zf = {0.f,0.f,0.f,0.f};
    f4_t acc[2][8];
    #pragma unroll
    for (int i = 0; i < 2; i++)
        #pragma unroll
        for (int j = 0; j < 8; j++) acc[i][j] = zf;
    #pragma unroll
    for (int ks = 0; ks < 4; ks++){
        int k0 = ks*32 + q*8;
        bf16x8 a0 = ld_frag8(&Ast[(       w*16 + m15)*KP + k0]);
        bf16x8 a1 = ld_frag8(&Ast[(64   + w*16 + m15)*KP + k0]);
        #pragma unroll
        for (int nt = 0; nt < 8; nt++){
            bf16x8 b0 = ld_frag16g(&owb[((size_t)0*DIMC + nt*16 + m15)*DIMC + k0]);
            bf16x8 b1 = ld_frag16g(&owb[((size_t)1*DIMC + nt*16 + m15)*DIMC + k0]);
            acc[0][nt] = __builtin_amdgcn_mfma_f32_16x16x32_bf16(a0, b0, acc[0][nt], 0,0,0);
            acc[1][nt] = __builtin_amdgcn_mfma_f32_16x16x32_bf16(a1, b1, acc[1][nt], 0,0,0);
        }
    }
    __syncthreads();
    #pragma unroll
    for (int nt = 0; nt < 8; nt++){
        int row = w*16 + q*4;
        int col = nt*16 + m15;
        #pragma unroll
        for (int i = 0; i < 4; i++)
            yt[(row+i)*129 + col] = acc[0][nt][i] - lam*acc[1][nt][i];
    }
    __syncthreads();
    const int r = tid & 63, g = tid >> 6;
    float s = 0.f, s2 = 0.f;
    #pragma unroll
    for (int k = 0; k < 32; k++){ float v = yt[r*129 + g*32 + k]; s += v; s2 += v*v; }
    red1[g*64 + r] = s; red2[g*64 + r] = s2;
    __syncthreads();
    if (tid < 64){
        float ss = 0.f, ss2 = 0.f;
        #pragma unroll
        for (int gg = 0; gg < 4; gg++){ ss += red1[gg*64 + tid]; ss2 += red2[gg*64 + tid]; }
        float mu = ss*(1.f/128.f);
        float var = ss2*(1.f/128.f) - mu*mu;
        stt[tid*2] = mu; stt[tid*2+1] = rsqrtf(var + EPSV);
    }
    __syncthreads();
    float mu1 = stt[r*2], rs1 = stt[r*2+1];
    s = 0.f; s2 = 0.f;
    #pragma unroll
    for (int k = 0; k < 32; k++){
        int c = g*32 + k;
        float v = (yt[r*129+c] - mu1)*rs1*sw[c] + sb[c]
                + x[(size_t)bb*DIMC*LSEQ + (size_t)c*LSEQ + l0 + r];
        yt[r*129+c] = v;
        s += v; s2 += v*v;
    }
    __syncthreads();
    red1[g*64 + r] = s; red2[g*64 + r] = s2;
    __syncthreads();
    if (tid < 64){
        float ss = 0.f, ss2 = 0.f;
        #pragma unroll
        for (int gg = 0; gg < 4; gg++){ ss += red1[gg*64 + tid]; ss2 += red2[gg*64 + tid]; }
        float mu = ss*(1.f/128.f);
        float var = ss2*(1.f/128.f) - mu*mu;
        stt[tid*2] = mu; stt[tid*2+1] = rsqrtf(var + EPSV);
    }
    __syncthreads();
    float mu2 = stt[r*2], rs2 = stt[r*2+1];
    #pragma unroll
    for (int k = 0; k < 32; k++){
        int c = g*32 + k;
        float o = (yt[r*129+c] - mu2)*rs2*n2w[c] + n2b[c];
        outp[(size_t)bb*DIMC*LSEQ + (size_t)c*LSEQ + l0 + r] = o;
    }
}

// ----------------------------------------------------------------
extern "C" void kernel_launch(void* const* d_in, const int* in_sizes, int n_in,
                              void* d_out, int out_size, void* d_ws, size_t ws_size,
                              hipStream_t stream)
{
    const float* x    = (const float*)d_in[0];
    const float* n1w  = (const float*)d_in[1];
    const float* n1b  = (const float*)d_in[2];
    const float* n2w  = (const float*)d_in[3];
    const float* n2b  = (const float*)d_in[4];
    const float* slw  = (const float*)d_in[5];
    const float* slb  = (const float*)d_in[6];
    const float* lq   = (const float*)d_in[7];
    const float* wi   = (const float*)d_in[8];
    const float* cw   = (const float*)d_in[9];
    const float* cb   = (const float*)d_in[10];
    const float* xpw  = (const float*)d_in[11];
    const float* dtw  = (const float*)d_in[12];
    const float* dtb  = (const float*)d_in[13];
    const float* alog = (const float*)d_in[14];
    const float* dvec = (const float*)d_in[15];
    const float* ow   = (const float*)d_in[16];

    float* ws = (float*)d_ws;
    unsigned short* xz    = (unsigned short*)(ws + 1572864);   // 6,291,456 f
    unsigned short* xc    = (unsigned short*)(ws + 7864320);   // 6,291,456 f
    unsigned short* dty   = (unsigned short*)(ws + 14155776);  // 6,291,456 f
    float*          bcb   = ws + 20447232;                     // 1,572,864 f
    float*          st1   = ws + 22020096;                     // 6,291,456 f (8*NCH*128*16)
    unsigned short* wallb = (unsigned short*)(ws + 28311552);  //    36,864 f
    unsigned short* wib   = (unsigned short*)(ws + 28348416);  //    32,768 f
    unsigned short* owb   = (unsigned short*)(ws + 28381184);  //    16,384 f
    float*          lam   = ws + 28397568;                     //         1

    k_wall  <<<768, 128, 0, stream>>>(dtw, xpw, lq, wi, ow, wallb, lam, wib, owb);
    k_inproj<<<dim3(384, 2), 256, 0, stream>>>(x, n1w, n1b, wib, xz);
    k_xproj <<<dim3(192, 8), 256, 0, stream>>>(xz, wallb, dtb, alog, cw, cb, xc, dty, bcb, st1);
    k_scan2 <<<1024, 512, 0, stream>>>(st1);
    k_scan3 <<<8*NCH, 128, 0, stream>>>(dty, xc, bcb, xz, st1, alog, dvec);
    k_final <<<dim3(192, 2), 256, 0, stream>>>(dty, owb, x, lam, slw, slb, n2w, n2b, (float*)d_out);
}

// Round 15
// 262.764 us; speedup vs baseline: 1.0518x; 1.0115x over previous
//
#include <hip/hip_runtime.h>
#include <math.h>

#define DIMC 128
#define LSEQ 12288
#define NB 2
#define BLR 24576   // NB*LSEQ
#define EPSV 1e-5f
#define NCH 384     // scan chunks per row
#define LC 32       // chunk length (NCH*LC = LSEQ)
#define KP 132      // LDS row pad (ushorts) for MFMA staging
#define FBP 20      // fbuf row pad (floats, 16B-aligned rows)

typedef __bf16 bf16x8 __attribute__((ext_vector_type(8)));
typedef __attribute__((ext_vector_type(4))) float f4_t;

__device__ __forceinline__ float sigf(float x){ return 1.f/(1.f+__expf(-x)); }
__device__ __forceinline__ float softplusf(float x){
    return fmaxf(x,0.f) + __logf(1.f + __expf(-fabsf(x)));
}
__device__ __forceinline__ float bf2f(unsigned short u){
    union { unsigned int i; float f; } v; v.i = ((unsigned int)u) << 16; return v.f;
}
__device__ __forceinline__ unsigned short f2bf(float f){
    union { float f; unsigned int i; } v; v.f = f;
    unsigned int b = v.i + 0x7FFFu + ((v.i >> 16) & 1u);
    return (unsigned short)(b >> 16);
}
__device__ __forceinline__ bf16x8 ld_frag8(const unsigned short* p){   // 8B-aligned LDS
    union { uint2 u[2]; bf16x8 v; } r;
    r.u[0] = *(const uint2*)(p);
    r.u[1] = *(const uint2*)(p+4);
    return r.v;
}
__device__ __forceinline__ bf16x8 ld_frag16g(const unsigned short* p){ // 16B-aligned global
    union { uint4 u; bf16x8 v; } r; r.u = *(const uint4*)p; return r.v;
}

// a[n] = exp(dtv*Av[n]).  FAST: Av[n] == (n+1)*Av[0] (detected at runtime) ->
// 1 transcendental + 7 muls instead of 8 transcendentals.
template<bool FAST>
__device__ __forceinline__ void comp_a8(float dtv, const float* Av, float* a){
    if (FAST){
        float e1 = __expf(dtv*Av[0]);
        float e2 = e1*e1, e4 = e2*e2;
        a[0]=e1; a[1]=e2; a[2]=e2*e1; a[3]=e4;
        a[4]=e4*e1; a[5]=e4*e2; a[6]=a[5]*e1; a[7]=e4*e4;
    } else {
        #pragma unroll
        for (int n = 0; n < 8; n++) a[n] = __expf(dtv*Av[n]);
    }
}

// ---------------------------------------------------------------- W_all (bf16) + lam + wi/ow->bf16 (merged)
// grid 768 x 128: blocks [0,576) build wallb; [576,768) convert wi/ow.
__global__ __launch_bounds__(128) void k_wall(const float* __restrict__ dtw, const float* __restrict__ xpw,
                       const float* __restrict__ lq, const float* __restrict__ wi, const float* __restrict__ ow,
                       unsigned short* __restrict__ wallb, float* __restrict__ lam,
                       unsigned short* __restrict__ wib, unsigned short* __restrict__ owb){
    int b = blockIdx.x, k = threadIdx.x;
    if (b < 576){
        int inst = b & 3, j = b >> 2;
        const float* xp = xpw + (size_t)inst*24*128;
        float v;
        if (j < 128){
            const float* dw = dtw + (size_t)inst*128*8 + (size_t)j*8;
            v = 0.f;
            #pragma unroll
            for (int r = 0; r < 8; r++) v += dw[r]*xp[r*128 + k];
        } else {
            v = xp[(8 + (j-128))*128 + k];
        }
        wallb[((size_t)inst*144 + j)*128 + k] = f2bf(v);
        if (b == 0 && k < 64){
            float s = lq[k] + lq[k+64];
            for (int m = 32; m; m >>= 1) s += __shfl_xor(s, m);
            if (k == 0) *lam = 1.f/(1.f+__expf(-s));
        }
    } else {
        int idx = ((b-576)*128 + k)*4;   // 192 blocks -> 98304 elems
        const float* src; unsigned short* dst; int off;
        if (idx < 65536){ src = wi;  dst = wib; off = idx; }
        else            { src = ow;  dst = owb; off = idx - 65536; }
        float4 v = *(const float4*)&src[off];
        ushort4 o; o.x=f2bf(v.x); o.y=f2bf(v.y); o.z=f2bf(v.z); o.w=f2bf(v.w);
        *(ushort4*)&dst[off] = o;
    }
}

// ---------------------------------------------------------------- FUSED: LN1 + transpose + in_proj MFMA (2-pass N)
// half==1 (z-block columns): silu applied at the epilogue, so scan3 reads
// pre-activated z and skips per-step sigf in its serial loop.
__global__ __launch_bounds__(256,4) void k_inproj(const float* __restrict__ x,
    const float* __restrict__ w1, const float* __restrict__ b1,
    const unsigned short* __restrict__ wib, unsigned short* __restrict__ xz)
{
    __shared__ __align__(16) unsigned short As[64*KP];   // 16896 B
    __shared__ __align__(16) unsigned short ep[64*KP];   // 16896 B
    __shared__ float red1[256], red2[256];
    __shared__ float stt[128];
    const int row0 = blockIdx.x * 64;   // grid.x = 384  (row0 == bb*LSEQ + l0)
    const int bb = blockIdx.x / 192;
    const int l0 = (blockIdx.x % 192) * 64;
    const int j0 = blockIdx.y * 256;    // grid.y = 2
    const int tid = threadIdx.x;
    const int li = tid & 63, cg = tid >> 6;
    const float* xb = x + (size_t)bb*DIMC*LSEQ + l0 + li;
    // pass 1: stats (coalesced, values discarded)
    {
        float s = 0.f, s2 = 0.f;
        #pragma unroll
        for (int p = 0; p < 32; p++){
            float v = xb[(size_t)(p*4 + cg)*LSEQ];
            s += v; s2 += v*v;
        }
        red1[cg*64 + li] = s; red2[cg*64 + li] = s2;
    }
    __syncthreads();
    if (tid < 64){
        float ss = 0.f, ss2 = 0.f;
        #pragma unroll
        for (int g = 0; g < 4; g++){ ss += red1[g*64 + tid]; ss2 += red2[g*64 + tid]; }
        float mu = ss*(1.f/128.f);
        float var = ss2*(1.f/128.f) - mu*mu;
        stt[tid*2] = mu; stt[tid*2+1] = rsqrtf(var + EPSV);
    }
    __syncthreads();
    // pass 2: re-read (cache-hot), normalize, write As bf16
    {
        float mu = stt[li*2], rs = stt[li*2+1];
        #pragma unroll
        for (int p = 0; p < 32; p++){
            int c = p*4 + cg;
            float v = (xb[(size_t)c*LSEQ] - mu)*rs*w1[c] + b1[c];
            As[li*KP + c] = f2bf(v);
        }
    }
    __syncthreads();
    // ---- GEMM: two sequential 128-col passes over the same As
    const int lane = tid & 63, w = tid >> 6;
    const int m15 = lane & 15, q = lane >> 4;
    #pragma unroll
    for (int half = 0; half < 2; half++){
        const int jj = j0 + half*128;
        const unsigned short* wb = wib + ((size_t)jj + m15)*DIMC + q*8;
        bf16x8 bc[8], bn[8];
        #pragma unroll
        for (int nt = 0; nt < 8; nt++) bc[nt] = ld_frag16g(wb + nt*2048);
        f4_t zf = {0.f,0.f,0.f,0.f};
        f4_t acc[8];
        #pragma unroll
        for (int j = 0; j < 8; j++) acc[j] = zf;
        #pragma unroll
        for (int ks = 0; ks < 4; ks++){
            if (ks < 3){
                #pragma unroll
                for (int nt = 0; nt < 8; nt++) bn[nt] = ld_frag16g(wb + nt*2048 + (ks+1)*32);
            }
            bf16x8 a0 = ld_frag8(&As[(w*16 + m15)*KP + ks*32 + q*8]);
            #pragma unroll
            for (int nt = 0; nt < 8; nt++)
                acc[nt] = __builtin_amdgcn_mfma_f32_16x16x32_bf16(a0, bc[nt], acc[nt], 0,0,0);
            #pragma unroll
            for (int nt = 0; nt < 8; nt++) bc[nt] = bn[nt];
        }
        __syncthreads();   // half 0: no-op ordering; half 1: prior ep stores complete
        #pragma unroll
        for (int nt = 0; nt < 8; nt++){
            int row = w*16 + q*4;
            int col = nt*16 + m15;
            #pragma unroll
            for (int i = 0; i < 4; i++){
                float v = acc[nt][i];
                if (half == 1) v = v * sigf(v);   // pre-activate z-block (scan3 consumes silu(z))
                ep[(row+i)*KP + col] = f2bf(v);
            }
        }
        __syncthreads();
        #pragma unroll
        for (int p = 0; p < 4; p++){
            int idx = p*256 + tid; int li2 = idx >> 4; int g = (idx & 15)*8;
            uint2 u0 = *(const uint2*)&ep[li2*KP + g];
            uint2 u1 = *(const uint2*)&ep[li2*KP + g + 4];
            uint4 o; o.x=u0.x; o.y=u0.y; o.z=u1.x; o.w=u1.y;
            *(uint4*)&xz[(size_t)(row0+li2)*512 + jj + g] = o;
        }
    }
}

// ---------------------------------------------------------------- fused scan-chunk reduce (LDS only)
// u from As; dt from Ep (both LDS). Ac via exp-of-sum.
template<bool FAST>
__device__ __forceinline__ void fscan(const unsigned short* __restrict__ As,
    const unsigned short* __restrict__ Ep, const float* __restrict__ fbuf,
    const float* Av, int ch, int d, int dim, float* Ac, float* Bc)
{
    float dts = 0.f;
    #pragma unroll 8
    for (int s = 0; s < LC; s++){
        int r = ch*32 + (d ? 31-s : s);
        float dtv = bf2f(Ep[r*KP + dim]);
        float uv  = bf2f(As[r*KP + dim]);
        float4 b0 = *(const float4*)&fbuf[r*FBP];
        float4 b1 = *(const float4*)&fbuf[r*FBP + 4];
        float bv[8] = {b0.x,b0.y,b0.z,b0.w,b1.x,b1.y,b1.z,b1.w};
        float du = dtv*uv;
        float a[8];
        comp_a8<FAST>(dtv, Av, a);
        #pragma unroll
        for (int n = 0; n < 8; n++)
            Bc[n] = a[n]*Bc[n] + du*bv[n];
        dts += dtv;
    }
    comp_a8<FAST>(dts, Av, Ac);
}

// ---------------------------------------------------------------- FUSED: conv+silu -> x_proj MFMA -> scan S1
// R8 structure (best measured): rolling-window conv Zb->As, Ep aliases Zb after
// the last Zb read, fscan reads As/Ep/fbuf.
__global__ __launch_bounds__(256,4) void k_xproj(const unsigned short* __restrict__ xz,
    const unsigned short* __restrict__ wallb, const float* __restrict__ dtb,
    const float* __restrict__ alog, const float* __restrict__ cw, const float* __restrict__ cbv,
    unsigned short* __restrict__ xc, unsigned short* __restrict__ dty,
    float* __restrict__ bcb, float* __restrict__ st)
{
    __shared__ __align__(16) unsigned short As[64*KP];   // 16896 B (u, stays intact)
    __shared__ __align__(16) unsigned short Zb[67*KP];   // 17688 B (xz halo tile; later Ep)
    __shared__ __align__(16) float fbuf[64*FBP];         //  5120 B (B,C f32)
    const int row0 = blockIdx.x * 64;    // grid.x = 192
    const int ib   = blockIdx.y;         // 0..7
    const int inst = ib >> 1;
    const int bb   = ib & 1;
    const int m    = inst >> 1;
    const int d    = inst & 1;
    const int tid = threadIdx.x;
    const size_t abase = (size_t)ib * LSEQ * DIMC;
    const int lane = tid & 63, w = tid >> 6;
    const int m15 = lane & 15, q = lane >> 4;
    const unsigned short* wb = wallb + ((size_t)inst*144 + m15)*DIMC + q*8;
    bf16x8 bc[9], bn[9];
    #pragma unroll
    for (int nt = 0; nt < 9; nt++) bc[nt] = ld_frag16g(wb + nt*2048);
    // ---- stage xz halo tile: rows [start, start+67)
    const int start = row0 - (d ? 0 : 3);
    for (int idx = tid; idx < 67*16; idx += 256){
        int r = idx >> 4, cq = idx & 15;
        int l = start + r;
        uint4 v = make_uint4(0,0,0,0);
        if (l >= 0 && l < LSEQ)
            v = *(const uint4*)&xz[((size_t)(bb*LSEQ + l))*512 + m*256 + cq*8];
        *(uint4*)&Zb[r*KP + cq*8] = v;
    }
    __syncthreads();
    // ---- conv + silu -> As, rolling window (li = lg*32 + p): 35 LDS reads not 128
    {
        const int dimi = tid & 127, lg = tid >> 7;
        float wk[4];
        #pragma unroll
        for (int k = 0; k < 4; k++){
            int kk = d ? 3-k : k;
            wk[k] = cw[((size_t)inst*DIMC + dimi)*4 + kk];
        }
        const float bsv = cbv[inst*DIMC + dimi];
        const int base = lg*32;
        float t0 = bf2f(Zb[(base  )*KP + dimi]);
        float t1 = bf2f(Zb[(base+1)*KP + dimi]);
        float t2 = bf2f(Zb[(base+2)*KP + dimi]);
        for (int p = 0; p < 32; p++){
            int li = base + p;
            float t3 = bf2f(Zb[(li+3)*KP + dimi]);
            float v = bsv + wk[0]*t0 + wk[1]*t1 + wk[2]*t2 + wk[3]*t3;
            v = v * sigf(v);
            As[li*KP + dimi] = f2bf(v);
            t0 = t1; t1 = t2; t2 = t3;
        }
    }
    __syncthreads();        // As ready; all Zb reads done (Ep alias safe after this)
    // coalesced xc store from As (fire-and-forget ahead of GEMM)
    #pragma unroll
    for (int p = 0; p < 4; p++){
        int idx = p*256 + tid; int li = idx >> 4; int g = (idx & 15)*8;
        uint2 u0 = *(const uint2*)&As[li*KP + g];
        uint2 u1 = *(const uint2*)&As[li*KP + g + 4];
        uint4 o; o.x=u0.x; o.y=u0.y; o.z=u1.x; o.w=u1.y;
        *(uint4*)&xc[abase + (size_t)(row0+li)*DIMC + g] = o;
    }
    f4_t zf = {0.f,0.f,0.f,0.f};
    f4_t acc[9];
    #pragma unroll
    for (int j = 0; j < 9; j++) acc[j] = zf;
    #pragma unroll
    for (int ks = 0; ks < 4; ks++){
        if (ks < 3){
            #pragma unroll
            for (int nt = 0; nt < 9; nt++) bn[nt] = ld_frag16g(wb + nt*2048 + (ks+1)*32);
        }
        bf16x8 a0 = ld_frag8(&As[(w*16 + m15)*KP + ks*32 + q*8]);
        #pragma unroll
        for (int nt = 0; nt < 9; nt++)
            acc[nt] = __builtin_amdgcn_mfma_f32_16x16x32_bf16(a0, bc[nt], acc[nt], 0,0,0);
        #pragma unroll
        for (int nt = 0; nt < 9; nt++) bc[nt] = bn[nt];
    }
    // stage B/C (acc[8]) -> fbuf ; dt (softplus) -> Ep (aliases Zb).
    unsigned short* Ep = Zb;
    {
        int row = w*16 + q*4;
        #pragma unroll
        for (int i = 0; i < 4; i++)
            fbuf[(row+i)*FBP + m15] = acc[8][i];
    }
    #pragma unroll
    for (int nt = 0; nt < 8; nt++){
        int col = nt*16 + m15;
        float bias = dtb[inst*DIMC + col];
        int row = w*16 + q*4;
        #pragma unroll
        for (int i = 0; i < 4; i++)
            Ep[(row+i)*KP + col] = f2bf(softplusf(acc[nt][i] + bias));
    }
    __syncthreads();
    {   // coalesced bcb store
        int row = tid >> 2, j = (tid & 3)*4;
        float4 v = { fbuf[row*FBP + j], fbuf[row*FBP + j + 1],
                     fbuf[row*FBP + j + 2], fbuf[row*FBP + j + 3] };
        *(float4*)&bcb[((size_t)ib*LSEQ + row0 + row)*16 + j] = v;
    }
    #pragma unroll
    for (int p = 0; p < 4; p++){   // dty store from Ep (coalesced)
        int idx = p*256 + tid; int li = idx >> 4; int g = (idx & 15)*8;
        uint2 u0 = *(const uint2*)&Ep[li*KP + g];
        uint2 u1 = *(const uint2*)&Ep[li*KP + g + 4];
        uint4 o; o.x=u0.x; o.y=u0.y; o.z=u1.x; o.w=u1.y;
        *(uint4*)&dty[abase + (size_t)(row0+li)*DIMC + g] = o;
    }
    // ---- fused scan stage 1: thread = (chunk-half, dim)
    const int ch  = tid >> 7;            // 0..1
    const int dim = tid & 127;
    const int bc2 = row0 >> 5;
    const int c   = d ? (NCH-1 - bc2 - ch) : (bc2 + ch);
    float Av[8];
    #pragma unroll
    for (int n = 0; n < 8; n++)
        Av[n] = -__expf(alog[((size_t)inst*DIMC + dim)*8 + n]);
    bool fast = true;
    #pragma unroll
    for (int n = 1; n < 8; n++)
        fast = fast && (fabsf(Av[n] - (float)(n+1)*Av[0]) <= 1e-5f*fabsf(Av[n]));
    float Ac[8], Bc[8];
    #pragma unroll
    for (int n = 0; n < 8; n++){ Ac[n] = 1.f; Bc[n] = 0.f; }
    if (fast) fscan<true >(As, Ep, fbuf, Av, ch, d, dim, Ac, Bc);
    else      fscan<false>(As, Ep, fbuf, Av, ch, d, dim, Ac, Bc);
    float* so = st + (((size_t)ib*NCH + c)*DIMC + dim)*16;
    float4 s0 = {Ac[0],Ac[1],Ac[2],Ac[3]};
    float4 s1 = {Ac[4],Ac[5],Ac[6],Ac[7]};
    float4 s2 = {Bc[0],Bc[1],Bc[2],Bc[3]};
    float4 s3 = {Bc[4],Bc[5],Bc[6],Bc[7]};
    *(float4*)&so[0]  = s0;
    *(float4*)&so[4]  = s1;
    *(float4*)&so[8]  = s2;
    *(float4*)&so[12] = s3;
}

// ---------------------------------------------------------------- scan S2 (cross-chunk exclusive prefix, in-place)
__global__ __launch_bounds__(512) void k_scan2(float* __restrict__ st){
    const int ib   = blockIdx.x >> 7;          // grid = 8*128 = 1024
    const int dim  = blockIdx.x & 127;
    const int n    = threadIdx.x >> 6;         // wave index = state index
    const int lane = threadIdx.x & 63;
    const size_t cstride = (size_t)DIMC*16;
    const size_t base = ((size_t)ib*NCH*DIMC + dim)*16 + n;
    float a[6], b[6];
    float Al = 1.f, Bl = 0.f;
    #pragma unroll
    for (int j = 0; j < 6; j++){
        size_t o = base + (size_t)(lane*6 + j)*cstride;
        float A  = st[o];
        float Bv = st[o + 8];
        a[j] = A; b[j] = Bv;
        Bl = A*Bl + Bv;
        Al *= A;
    }
    #pragma unroll
    for (int off = 1; off < 64; off <<= 1){
        float Ao = __shfl_up(Al, off, 64);
        float Bo = __shfl_up(Bl, off, 64);
        if (lane >= off){
            Bl = Al*Bo + Bl;
            Al = Al*Ao;
        }
    }
    float h = __shfl_up(Bl, 1, 64);            // exclusive carry
    if (lane == 0) h = 0.f;
    #pragma unroll
    for (int j = 0; j < 6; j++){
        size_t o = base + (size_t)(lane*6 + j)*cstride;
        st[o] = h;
        h = a[j]*h + b[j];
    }
}

// ---------------------------------------------------------------- scan S3 (replay, y in place over dt)
// z arrives pre-activated (silu applied in k_inproj) -> y *= zv directly.
template<bool FAST>
__device__ __forceinline__ void scan3_body(unsigned short* __restrict__ dty,
    const unsigned short* __restrict__ sdt, const unsigned short* __restrict__ sxc,
    const unsigned short* __restrict__ sz, const float* __restrict__ sbc,
    const float* Av, float Dv, float* h,
    size_t rbase, size_t lbase, int d, int tid)
{
    #pragma unroll 8
    for (int s = 0; s < LC; s++){
        int r = d ? 31-s : s;
        float dtv = bf2f(sdt[r*128 + tid]);
        float uv  = bf2f(sxc[r*128 + tid]);
        float zv  = bf2f(sz [r*128 + tid]);
        float4 bA = *(const float4*)&sbc[r*16];
        float4 bB = *(const float4*)&sbc[r*16 + 4];
        float4 cA = *(const float4*)&sbc[r*16 + 8];
        float4 cB = *(const float4*)&sbc[r*16 + 12];
        float bv[8] = {bA.x,bA.y,bA.z,bA.w,bB.x,bB.y,bB.z,bB.w};
        float cv[8] = {cA.x,cA.y,cA.z,cA.w,cB.x,cB.y,cB.z,cB.w};
        float du = dtv*uv;
        float y = uv*Dv;
        float a[8];
        comp_a8<FAST>(dtv, Av, a);
        #pragma unroll
        for (int n = 0; n < 8; n++){
            h[n] = a[n]*h[n] + du*bv[n];
            y += h[n]*cv[n];
        }
        y *= zv;                      // zv = silu(z), precomputed in k_inproj
        dty[rbase + (lbase + r)*DIMC + tid] = f2bf(y);
    }
}

__global__ __launch_bounds__(128) void k_scan3(unsigned short* __restrict__ dty,
    const unsigned short* __restrict__ xc, const float* __restrict__ bcb,
    const unsigned short* __restrict__ xz, const float* __restrict__ st,
    const float* __restrict__ alog, const float* __restrict__ dvec)
{
    __shared__ __align__(16) unsigned short sdt[32*128];   // 8 KB
    __shared__ __align__(16) unsigned short sxc[32*128];   // 8 KB
    __shared__ __align__(16) unsigned short sz [32*128];   // 8 KB
    __shared__ __align__(16) float sbc[32*16];             // 2 KB
    const int ib = blockIdx.x & 7;
    const int c  = blockIdx.x >> 3;
    const int inst = ib >> 1, bb = ib & 1;
    const int m = inst >> 1, d = inst & 1;
    const int tid = threadIdx.x;
    const size_t rbase = (size_t)ib*LSEQ*DIMC;
    const size_t zbase = (size_t)bb*LSEQ*512 + m*256 + 128;
    const size_t lbase = d ? (size_t)(LSEQ - 32 - c*32) : (size_t)(c*32);
    #pragma unroll
    for (int p = 0; p < 4; p++){
        int idx = p*128 + tid;          // 512 uint4 per 8KB array
        int r = idx >> 4, g = (idx & 15)*8;
        size_t go = rbase + (lbase + r)*DIMC + g;
        *(uint4*)&sdt[r*128 + g] = *(const uint4*)&dty[go];
        *(uint4*)&sxc[r*128 + g] = *(const uint4*)&xc[go];
        *(uint4*)&sz [r*128 + g] = *(const uint4*)&xz[zbase + (lbase + r)*512 + g];
    }
    {   // bcb: 2KB = 128 x float4
        int r = tid >> 2, j = (tid & 3)*4;
        *(float4*)&sbc[r*16 + j] = *(const float4*)&bcb[((size_t)ib*LSEQ + lbase + r)*16 + j];
    }
    float Av[8];
    #pragma unroll
    for (int n = 0; n < 8; n++)
        Av[n] = -__expf(alog[((size_t)inst*DIMC + tid)*8 + n]);
    bool fast = true;
    #pragma unroll
    for (int n = 1; n < 8; n++)
        fast = fast && (fabsf(Av[n] - (float)(n+1)*Av[0]) <= 1e-5f*fabsf(Av[n]));
    const float Dv = dvec[inst*DIMC + tid];
    float h[8];
    const float* hp = st + (((size_t)ib*NCH + c)*DIMC + tid)*16;
    #pragma unroll
    for (int n = 0; n < 8; n++) h[n] = hp[n];
    __syncthreads();
    if (fast) scan3_body<true >(dty, sdt, sxc, sz, sbc, Av, Dv, h, rbase, lbase, d, tid);
    else      scan3_body<false>(dty, sdt, sxc, sz, sbc, Av, Dv, h, rbase, lbase, d, tid);
}

// ---------------------------------------------------------------- out_proj MFMA + diff + LN + add x + LN + T-store
__global__ __launch_bounds__(256,4) void k_final(const unsigned short* __restrict__ y,
    const unsigned short* __restrict__ owb, const float* __restrict__ x, const float* __restrict__ lamp,
    const float* __restrict__ sw, const float* __restrict__ sb,
    const float* __restrict__ n2w, const float* __restrict__ n2b, float* __restrict__ outp)
{
    __shared__ __align__(16) char smem[36352];
    unsigned short* Ast = (unsigned short*)smem;             // phase 1: [2*64][KP] = 33792 B
    float* yt            = (float*)smem;                     // phase 2: [64][129] f32 = 33024 B (aliases Ast)
    float* red1          = (float*)(smem + 33792);           // 1024 B
    float* red2          = (float*)(smem + 34816);           // 1024 B
    float* stt           = (float*)(smem + 35840);           //  512 B
    const int bb = blockIdx.y;
    const int l0 = blockIdx.x * 64;                  // grid.x = 192
    const int tid = threadIdx.x;
    const float lam = *lamp;
    #pragma unroll
    for (int p = 0; p < 8; p++){
        int idx = p*256 + tid; int mm = idx >> 10; int li = (idx >> 4) & 63; int g = (idx & 15)*8;
        uint4 vf = *(const uint4*)&y[(((size_t)(mm*2+0)*NB + bb)*LSEQ + l0 + li)*DIMC + g];
        uint4 vb = *(const uint4*)&y[(((size_t)(mm*2+1)*NB + bb)*LSEQ + l0 + li)*DIMC + g];
        const unsigned short* uf = (const unsigned short*)&vf;
        const unsigned short* ub = (const unsigned short*)&vb;
        unsigned short o[8];
        #pragma unroll
        for (int j = 0; j < 8; j++) o[j] = f2bf(bf2f(uf[j]) + bf2f(ub[j]));
        *(uint2*)&Ast[(mm*64 + li)*KP + g]     = *(uint2*)&o[0];
        *(uint2*)&Ast[(mm*64 + li)*KP + g + 4] = *(uint2*)&o[4];
    }
    __syncthreads();
    const int lane = tid & 63, w = tid >> 6;
    const int m15 = lane & 15, q = lane >> 4;
    f4_t zf = {0.f,0.f,0.f,0.f};
    f4_t acc[2][8];
    #pragma unroll
    for (int i = 0; i < 2; i++)
        #pragma unroll
        for (int j = 0; j < 8; j++) acc[i][j] = zf;
    #pragma unroll
    for (int ks = 0; ks < 4; ks++){
        int k0 = ks*32 + q*8;
        bf16x8 a0 = ld_frag8(&Ast[(       w*16 + m15)*KP + k0]);
        bf16x8 a1 = ld_frag8(&Ast[(64   + w*16 + m15)*KP + k0]);
        #pragma unroll
        for (int nt = 0; nt < 8; nt++){
            bf16x8 b0 = ld_frag16g(&owb[((size_t)0*DIMC + nt*16 + m15)*DIMC + k0]);
            bf16x8 b1 = ld_frag16g(&owb[((size_t)1*DIMC + nt*16 + m15)*DIMC + k0]);
            acc[0][nt] = __builtin_amdgcn_mfma_f32_16x16x32_bf16(a0, b0, acc[0][nt], 0,0,0);
            acc[1][nt] = __builtin_amdgcn_mfma_f32_16x16x32_bf16(a1, b1, acc[1][nt], 0,0,0);
        }
    }
    __syncthreads();
    #pragma unroll
    for (int nt = 0; nt < 8; nt++){
        int row = w*16 + q*4;
        int col = nt*16 + m15;
        #pragma unroll
        for (int i = 0; i < 4; i++)
            yt[(row+i)*129 + col] = acc[0][nt][i] - lam*acc[1][nt][i];
    }
    __syncthreads();
    const int r = tid & 63, g = tid >> 6;
    float s = 0.f, s2 = 0.f;
    #pragma unroll
    for (int k = 0; k < 32; k++){ float v = yt[r*129 + g*32 + k]; s += v; s2 += v*v; }
    red1[g*64 + r] = s; red2[g*64 + r] = s2;
    __syncthreads();
    if (tid < 64){
        float ss = 0.f, ss2 = 0.f;
        #pragma unroll
        for (int gg = 0; gg < 4; gg++){ ss += red1[gg*64 + tid]; ss2 += red2[gg*64 + tid]; }
        float mu = ss*(1.f/128.f);
        float var = ss2*(1.f/128.f) - mu*mu;
        stt[tid*2] = mu; stt[tid*2+1] = rsqrtf(var + EPSV);
    }
    __syncthreads();
    float mu1 = stt[r*2], rs1 = stt[r*2+1];
    s = 0.f; s2 = 0.f;
    #pragma unroll
    for (int k = 0; k < 32; k++){
        int c = g*32 + k;
        float v = (yt[r*129+c] - mu1)*rs1*sw[c] + sb[c]
                + x[(size_t)bb*DIMC*LSEQ + (size_t)c*LSEQ + l0 + r];
        yt[r*129+c] = v;
        s += v; s2 += v*v;
    }
    __syncthreads();
    red1[g*64 + r] = s; red2[g*64 + r] = s2;
    __syncthreads();
    if (tid < 64){
        float ss = 0.f, ss2 = 0.f;
        #pragma unroll
        for (int gg = 0; gg < 4; gg++){ ss += red1[gg*64 + tid]; ss2 += red2[gg*64 + tid]; }
        float mu = ss*(1.f/128.f);
        float var = ss2*(1.f/128.f) - mu*mu;
        stt[tid*2] = mu; stt[tid*2+1] = rsqrtf(var + EPSV);
    }
    __syncthreads();
    float mu2 = stt[r*2], rs2 = stt[r*2+1];
    #pragma unroll
    for (int k = 0; k < 32; k++){
        int c = g*32 + k;
        float o = (yt[r*129+c] - mu2)*rs2*n2w[c] + n2b[c];
        outp[(size_t)bb*DIMC*LSEQ + (size_t)c*LSEQ + l0 + r] = o;
    }
}

// ----------------------------------------------------------------
extern "C" void kernel_launch(void* const* d_in, const int* in_sizes, int n_in,
                              void* d_out, int out_size, void* d_ws, size_t ws_size,
                              hipStream_t stream)
{
    const float* x    = (const float*)d_in[0];
    const float* n1w  = (const float*)d_in[1];
    const float* n1b  = (const float*)d_in[2];
    const float* n2w  = (const float*)d_in[3];
    const float* n2b  = (const float*)d_in[4];
    const float* slw  = (const float*)d_in[5];
    const float* slb  = (const float*)d_in[6];
    const float* lq   = (const float*)d_in[7];
    const float* wi   = (const float*)d_in[8];
    const float* cw   = (const float*)d_in[9];
    const float* cb   = (const float*)d_in[10];
    const float* xpw  = (const float*)d_in[11];
    const float* dtw  = (const float*)d_in[12];
    const float* dtb  = (const float*)d_in[13];
    const float* alog = (const float*)d_in[14];
    const float* dvec = (const float*)d_in[15];
    const float* ow   = (const float*)d_in[16];

    float* ws = (float*)d_ws;
    unsigned short* xz    = (unsigned short*)(ws + 1572864);   // 6,291,456 f
    unsigned short* xc    = (unsigned short*)(ws + 7864320);   // 6,291,456 f
    unsigned short* dty   = (unsigned short*)(ws + 14155776);  // 6,291,456 f
    float*          bcb   = ws + 20447232;                     // 1,572,864 f
    float*          st1   = ws + 22020096;                     // 6,291,456 f (8*NCH*128*16)
    unsigned short* wallb = (unsigned short*)(ws + 28311552);  //    36,864 f
    unsigned short* wib   = (unsigned short*)(ws + 28348416);  //    32,768 f
    unsigned short* owb   = (unsigned short*)(ws + 28381184);  //    16,384 f
    float*          lam   = ws + 28397568;                     //         1

    k_wall  <<<768, 128, 0, stream>>>(dtw, xpw, lq, wi, ow, wallb, lam, wib, owb);
    k_inproj<<<dim3(384, 2), 256, 0, stream>>>(x, n1w, n1b, wib, xz);
    k_xproj <<<dim3(192, 8), 256, 0, stream>>>(xz, wallb, dtb, alog, cw, cb, xc, dty, bcb, st1);
    k_scan2 <<<1024, 512, 0, stream>>>(st1);
    k_scan3 <<<8*NCH, 128, 0, stream>>>(dty, xc, bcb, xz, st1, alog, dvec);
    k_final <<<dim3(192, 2), 256, 0, stream>>>(dty, owb, x, lam, slw, slb, n2w, n2b, (float*)d_out);
}

// Round 16
// 259.547 us; speedup vs baseline: 1.0649x; 1.0124x over previous
//
#include <hip/hip_runtime.h>
#include <math.h>

#define DIMC 128
#define LSEQ 12288
#define NB 2
#define BLR 24576   // NB*LSEQ
#define EPSV 1e-5f
#define NCH 384     // scan chunks per row
#define LC 32       // chunk length (NCH*LC = LSEQ)
#define KP 132      // LDS row pad (ushorts) for MFMA staging
#define FBP 20      // fbuf row pad (floats, 16B-aligned rows)

typedef __bf16 bf16x8 __attribute__((ext_vector_type(8)));
typedef __attribute__((ext_vector_type(4))) float f4_t;

__device__ __forceinline__ float sigf(float x){ return 1.f/(1.f+__expf(-x)); }
__device__ __forceinline__ float softplusf(float x){
    return fmaxf(x,0.f) + __logf(1.f + __expf(-fabsf(x)));
}
__device__ __forceinline__ float bf2f(unsigned short u){
    union { unsigned int i; float f; } v; v.i = ((unsigned int)u) << 16; return v.f;
}
__device__ __forceinline__ unsigned short f2bf(float f){
    union { float f; unsigned int i; } v; v.f = f;
    unsigned int b = v.i + 0x7FFFu + ((v.i >> 16) & 1u);
    return (unsigned short)(b >> 16);
}
__device__ __forceinline__ bf16x8 ld_frag8(const unsigned short* p){   // 8B-aligned LDS
    union { uint2 u[2]; bf16x8 v; } r;
    r.u[0] = *(const uint2*)(p);
    r.u[1] = *(const uint2*)(p+4);
    return r.v;
}
__device__ __forceinline__ bf16x8 ld_frag16g(const unsigned short* p){ // 16B-aligned global
    union { uint4 u; bf16x8 v; } r; r.u = *(const uint4*)p; return r.v;
}

// a[n] = exp(dtv*Av[n]).  FAST: Av[n] == (n+1)*Av[0] (detected at runtime) ->
// 1 transcendental + 7 muls instead of 8 transcendentals.
template<bool FAST>
__device__ __forceinline__ void comp_a8(float dtv, const float* Av, float* a){
    if (FAST){
        float e1 = __expf(dtv*Av[0]);
        float e2 = e1*e1, e4 = e2*e2;
        a[0]=e1; a[1]=e2; a[2]=e2*e1; a[3]=e4;
        a[4]=e4*e1; a[5]=e4*e2; a[6]=a[5]*e1; a[7]=e4*e4;
    } else {
        #pragma unroll
        for (int n = 0; n < 8; n++) a[n] = __expf(dtv*Av[n]);
    }
}

// ---------------------------------------------------------------- W_all (bf16) + lam + wi/ow->bf16 (merged)
// grid 768 x 128: blocks [0,576) build wallb; [576,768) convert wi/ow.
__global__ __launch_bounds__(128) void k_wall(const float* __restrict__ dtw, const float* __restrict__ xpw,
                       const float* __restrict__ lq, const float* __restrict__ wi, const float* __restrict__ ow,
                       unsigned short* __restrict__ wallb, float* __restrict__ lam,
                       unsigned short* __restrict__ wib, unsigned short* __restrict__ owb){
    int b = blockIdx.x, k = threadIdx.x;
    if (b < 576){
        int inst = b & 3, j = b >> 2;
        const float* xp = xpw + (size_t)inst*24*128;
        float v;
        if (j < 128){
            const float* dw = dtw + (size_t)inst*128*8 + (size_t)j*8;
            v = 0.f;
            #pragma unroll
            for (int r = 0; r < 8; r++) v += dw[r]*xp[r*128 + k];
        } else {
            v = xp[(8 + (j-128))*128 + k];
        }
        wallb[((size_t)inst*144 + j)*128 + k] = f2bf(v);
        if (b == 0 && k < 64){
            float s = lq[k] + lq[k+64];
            for (int m = 32; m; m >>= 1) s += __shfl_xor(s, m);
            if (k == 0) *lam = 1.f/(1.f+__expf(-s));
        }
    } else {
        int idx = ((b-576)*128 + k)*4;   // 192 blocks -> 98304 elems
        const float* src; unsigned short* dst; int off;
        if (idx < 65536){ src = wi;  dst = wib; off = idx; }
        else            { src = ow;  dst = owb; off = idx - 65536; }
        float4 v = *(const float4*)&src[off];
        ushort4 o; o.x=f2bf(v.x); o.y=f2bf(v.y); o.z=f2bf(v.z); o.w=f2bf(v.w);
        *(ushort4*)&dst[off] = o;
    }
}

// ---------------------------------------------------------------- FUSED: LN1 + transpose + in_proj MFMA (2-pass N)
// half==1 (z-block columns): silu applied at the epilogue, so scan3 reads
// pre-activated z and skips per-step sigf in its serial loop.
__global__ __launch_bounds__(256,4) void k_inproj(const float* __restrict__ x,
    const float* __restrict__ w1, const float* __restrict__ b1,
    const unsigned short* __restrict__ wib, unsigned short* __restrict__ xz)
{
    __shared__ __align__(16) unsigned short As[64*KP];   // 16896 B
    __shared__ __align__(16) unsigned short ep[64*KP];   // 16896 B
    __shared__ float red1[256], red2[256];
    __shared__ float stt[128];
    const int row0 = blockIdx.x * 64;   // grid.x = 384  (row0 == bb*LSEQ + l0)
    const int bb = blockIdx.x / 192;
    const int l0 = (blockIdx.x % 192) * 64;
    const int j0 = blockIdx.y * 256;    // grid.y = 2
    const int tid = threadIdx.x;
    const int li = tid & 63, cg = tid >> 6;
    const float* xb = x + (size_t)bb*DIMC*LSEQ + l0 + li;
    // pass 1: stats (coalesced, values discarded)
    {
        float s = 0.f, s2 = 0.f;
        #pragma unroll
        for (int p = 0; p < 32; p++){
            float v = xb[(size_t)(p*4 + cg)*LSEQ];
            s += v; s2 += v*v;
        }
        red1[cg*64 + li] = s; red2[cg*64 + li] = s2;
    }
    __syncthreads();
    if (tid < 64){
        float ss = 0.f, ss2 = 0.f;
        #pragma unroll
        for (int g = 0; g < 4; g++){ ss += red1[g*64 + tid]; ss2 += red2[g*64 + tid]; }
        float mu = ss*(1.f/128.f);
        float var = ss2*(1.f/128.f) - mu*mu;
        stt[tid*2] = mu; stt[tid*2+1] = rsqrtf(var + EPSV);
    }
    __syncthreads();
    // pass 2: re-read (cache-hot), normalize, write As bf16
    {
        float mu = stt[li*2], rs = stt[li*2+1];
        #pragma unroll
        for (int p = 0; p < 32; p++){
            int c = p*4 + cg;
            float v = (xb[(size_t)c*LSEQ] - mu)*rs*w1[c] + b1[c];
            As[li*KP + c] = f2bf(v);
        }
    }
    __syncthreads();
    // ---- GEMM: two sequential 128-col passes over the same As
    const int lane = tid & 63, w = tid >> 6;
    const int m15 = lane & 15, q = lane >> 4;
    #pragma unroll
    for (int half = 0; half < 2; half++){
        const int jj = j0 + half*128;
        const unsigned short* wb = wib + ((size_t)jj + m15)*DIMC + q*8;
        bf16x8 bc[8], bn[8];
        #pragma unroll
        for (int nt = 0; nt < 8; nt++) bc[nt] = ld_frag16g(wb + nt*2048);
        f4_t zf = {0.f,0.f,0.f,0.f};
        f4_t acc[8];
        #pragma unroll
        for (int j = 0; j < 8; j++) acc[j] = zf;
        #pragma unroll
        for (int ks = 0; ks < 4; ks++){
            if (ks < 3){
                #pragma unroll
                for (int nt = 0; nt < 8; nt++) bn[nt] = ld_frag16g(wb + nt*2048 + (ks+1)*32);
            }
            bf16x8 a0 = ld_frag8(&As[(w*16 + m15)*KP + ks*32 + q*8]);
            #pragma unroll
            for (int nt = 0; nt < 8; nt++)
                acc[nt] = __builtin_amdgcn_mfma_f32_16x16x32_bf16(a0, bc[nt], acc[nt], 0,0,0);
            #pragma unroll
            for (int nt = 0; nt < 8; nt++) bc[nt] = bn[nt];
        }
        __syncthreads();   // half 0: no-op ordering; half 1: prior ep stores complete
        #pragma unroll
        for (int nt = 0; nt < 8; nt++){
            int row = w*16 + q*4;
            int col = nt*16 + m15;
            #pragma unroll
            for (int i = 0; i < 4; i++){
                float v = acc[nt][i];
                if (half == 1) v = v * sigf(v);   // pre-activate z-block (scan3 consumes silu(z))
                ep[(row+i)*KP + col] = f2bf(v);
            }
        }
        __syncthreads();
        #pragma unroll
        for (int p = 0; p < 4; p++){
            int idx = p*256 + tid; int li2 = idx >> 4; int g = (idx & 15)*8;
            uint2 u0 = *(const uint2*)&ep[li2*KP + g];
            uint2 u1 = *(const uint2*)&ep[li2*KP + g + 4];
            uint4 o; o.x=u0.x; o.y=u0.y; o.z=u1.x; o.w=u1.y;
            *(uint4*)&xz[(size_t)(row0+li2)*512 + jj + g] = o;
        }
    }
}

// ---------------------------------------------------------------- fused scan-chunk reduce (LDS only)
// u from As; dt from Ep (both LDS). Ac via exp-of-sum.
template<bool FAST>
__device__ __forceinline__ void fscan(const unsigned short* __restrict__ As,
    const unsigned short* __restrict__ Ep, const float* __restrict__ fbuf,
    const float* Av, int ch, int d, int dim, float* Ac, float* Bc)
{
    float dts = 0.f;
    #pragma unroll 8
    for (int s = 0; s < LC; s++){
        int r = ch*32 + (d ? 31-s : s);
        float dtv = bf2f(Ep[r*KP + dim]);
        float uv  = bf2f(As[r*KP + dim]);
        float4 b0 = *(const float4*)&fbuf[r*FBP];
        float4 b1 = *(const float4*)&fbuf[r*FBP + 4];
        float bv[8] = {b0.x,b0.y,b0.z,b0.w,b1.x,b1.y,b1.z,b1.w};
        float du = dtv*uv;
        float a[8];
        comp_a8<FAST>(dtv, Av, a);
        #pragma unroll
        for (int n = 0; n < 8; n++)
            Bc[n] = a[n]*Bc[n] + du*bv[n];
        dts += dtv;
    }
    comp_a8<FAST>(dts, Av, Ac);
}

// ---------------------------------------------------------------- FUSED: conv+silu -> x_proj MFMA -> scan S1
// R8 structure (best measured): rolling-window conv Zb->As, Ep aliases Zb after
// the last Zb read, fscan reads As/Ep/fbuf.
__global__ __launch_bounds__(256,4) void k_xproj(const unsigned short* __restrict__ xz,
    const unsigned short* __restrict__ wallb, const float* __restrict__ dtb,
    const float* __restrict__ alog, const float* __restrict__ cw, const float* __restrict__ cbv,
    unsigned short* __restrict__ xc, unsigned short* __restrict__ dty,
    float* __restrict__ bcb, float* __restrict__ st)
{
    __shared__ __align__(16) unsigned short As[64*KP];   // 16896 B (u, stays intact)
    __shared__ __align__(16) unsigned short Zb[67*KP];   // 17688 B (xz halo tile; later Ep)
    __shared__ __align__(16) float fbuf[64*FBP];         //  5120 B (B,C f32)
    const int row0 = blockIdx.x * 64;    // grid.x = 192
    const int ib   = blockIdx.y;         // 0..7
    const int inst = ib >> 1;
    const int bb   = ib & 1;
    const int m    = inst >> 1;
    const int d    = inst & 1;
    const int tid = threadIdx.x;
    const size_t abase = (size_t)ib * LSEQ * DIMC;
    const int lane = tid & 63, w = tid >> 6;
    const int m15 = lane & 15, q = lane >> 4;
    const unsigned short* wb = wallb + ((size_t)inst*144 + m15)*DIMC + q*8;
    bf16x8 bc[9], bn[9];
    #pragma unroll
    for (int nt = 0; nt < 9; nt++) bc[nt] = ld_frag16g(wb + nt*2048);
    // ---- stage xz halo tile: rows [start, start+67)
    const int start = row0 - (d ? 0 : 3);
    for (int idx = tid; idx < 67*16; idx += 256){
        int r = idx >> 4, cq = idx & 15;
        int l = start + r;
        uint4 v = make_uint4(0,0,0,0);
        if (l >= 0 && l < LSEQ)
            v = *(const uint4*)&xz[((size_t)(bb*LSEQ + l))*512 + m*256 + cq*8];
        *(uint4*)&Zb[r*KP + cq*8] = v;
    }
    __syncthreads();
    // ---- conv + silu -> As, rolling window (li = lg*32 + p): 35 LDS reads not 128
    {
        const int dimi = tid & 127, lg = tid >> 7;
        float wk[4];
        #pragma unroll
        for (int k = 0; k < 4; k++){
            int kk = d ? 3-k : k;
            wk[k] = cw[((size_t)inst*DIMC + dimi)*4 + kk];
        }
        const float bsv = cbv[inst*DIMC + dimi];
        const int base = lg*32;
        float t0 = bf2f(Zb[(base  )*KP + dimi]);
        float t1 = bf2f(Zb[(base+1)*KP + dimi]);
        float t2 = bf2f(Zb[(base+2)*KP + dimi]);
        for (int p = 0; p < 32; p++){
            int li = base + p;
            float t3 = bf2f(Zb[(li+3)*KP + dimi]);
            float v = bsv + wk[0]*t0 + wk[1]*t1 + wk[2]*t2 + wk[3]*t3;
            v = v * sigf(v);
            As[li*KP + dimi] = f2bf(v);
            t0 = t1; t1 = t2; t2 = t3;
        }
    }
    __syncthreads();        // As ready; all Zb reads done (Ep alias safe after this)
    // coalesced xc store from As (fire-and-forget ahead of GEMM)
    #pragma unroll
    for (int p = 0; p < 4; p++){
        int idx = p*256 + tid; int li = idx >> 4; int g = (idx & 15)*8;
        uint2 u0 = *(const uint2*)&As[li*KP + g];
        uint2 u1 = *(const uint2*)&As[li*KP + g + 4];
        uint4 o; o.x=u0.x; o.y=u0.y; o.z=u1.x; o.w=u1.y;
        *(uint4*)&xc[abase + (size_t)(row0+li)*DIMC + g] = o;
    }
    f4_t zf = {0.f,0.f,0.f,0.f};
    f4_t acc[9];
    #pragma unroll
    for (int j = 0; j < 9; j++) acc[j] = zf;
    #pragma unroll
    for (int ks = 0; ks < 4; ks++){
        if (ks < 3){
            #pragma unroll
            for (int nt = 0; nt < 9; nt++) bn[nt] = ld_frag16g(wb + nt*2048 + (ks+1)*32);
        }
        bf16x8 a0 = ld_frag8(&As[(w*16 + m15)*KP + ks*32 + q*8]);
        #pragma unroll
        for (int nt = 0; nt < 9; nt++)
            acc[nt] = __builtin_amdgcn_mfma_f32_16x16x32_bf16(a0, bc[nt], acc[nt], 0,0,0);
        #pragma unroll
        for (int nt = 0; nt < 9; nt++) bc[nt] = bn[nt];
    }
    // stage B/C (acc[8]) -> fbuf ; dt (softplus) -> Ep (aliases Zb).
    unsigned short* Ep = Zb;
    {
        int row = w*16 + q*4;
        #pragma unroll
        for (int i = 0; i < 4; i++)
            fbuf[(row+i)*FBP + m15] = acc[8][i];
    }
    #pragma unroll
    for (int nt = 0; nt < 8; nt++){
        int col = nt*16 + m15;
        float bias = dtb[inst*DIMC + col];
        int row = w*16 + q*4;
        #pragma unroll
        for (int i = 0; i < 4; i++)
            Ep[(row+i)*KP + col] = f2bf(softplusf(acc[nt][i] + bias));
    }
    __syncthreads();
    {   // coalesced bcb store
        int row = tid >> 2, j = (tid & 3)*4;
        float4 v = { fbuf[row*FBP + j], fbuf[row*FBP + j + 1],
                     fbuf[row*FBP + j + 2], fbuf[row*FBP + j + 3] };
        *(float4*)&bcb[((size_t)ib*LSEQ + row0 + row)*16 + j] = v;
    }
    #pragma unroll
    for (int p = 0; p < 4; p++){   // dty store from Ep (coalesced)
        int idx = p*256 + tid; int li = idx >> 4; int g = (idx & 15)*8;
        uint2 u0 = *(const uint2*)&Ep[li*KP + g];
        uint2 u1 = *(const uint2*)&Ep[li*KP + g + 4];
        uint4 o; o.x=u0.x; o.y=u0.y; o.z=u1.x; o.w=u1.y;
        *(uint4*)&dty[abase + (size_t)(row0+li)*DIMC + g] = o;
    }
    // ---- fused scan stage 1: thread = (chunk-half, dim)
    const int ch  = tid >> 7;            // 0..1
    const int dim = tid & 127;
    const int bc2 = row0 >> 5;
    const int c   = d ? (NCH-1 - bc2 - ch) : (bc2 + ch);
    float Av[8];
    #pragma unroll
    for (int n = 0; n < 8; n++)
        Av[n] = -__expf(alog[((size_t)inst*DIMC + dim)*8 + n]);
    bool fast = true;
    #pragma unroll
    for (int n = 1; n < 8; n++)
        fast = fast && (fabsf(Av[n] - (float)(n+1)*Av[0]) <= 1e-5f*fabsf(Av[n]));
    float Ac[8], Bc[8];
    #pragma unroll
    for (int n = 0; n < 8; n++){ Ac[n] = 1.f; Bc[n] = 0.f; }
    if (fast) fscan<true >(As, Ep, fbuf, Av, ch, d, dim, Ac, Bc);
    else      fscan<false>(As, Ep, fbuf, Av, ch, d, dim, Ac, Bc);
    float* so = st + (((size_t)ib*NCH + c)*DIMC + dim)*16;
    float4 s0 = {Ac[0],Ac[1],Ac[2],Ac[3]};
    float4 s1 = {Ac[4],Ac[5],Ac[6],Ac[7]};
    float4 s2 = {Bc[0],Bc[1],Bc[2],Bc[3]};
    float4 s3 = {Bc[4],Bc[5],Bc[6],Bc[7]};
    *(float4*)&so[0]  = s0;
    *(float4*)&so[4]  = s1;
    *(float4*)&so[8]  = s2;
    *(float4*)&so[12] = s3;
}

// ---------------------------------------------------------------- scan S2 (cross-chunk exclusive prefix, in-place)
__global__ __launch_bounds__(512) void k_scan2(float* __restrict__ st){
    const int ib   = blockIdx.x >> 7;          // grid = 8*128 = 1024
    const int dim  = blockIdx.x & 127;
    const int n    = threadIdx.x >> 6;         // wave index = state index
    const int lane = threadIdx.x & 63;
    const size_t cstride = (size_t)DIMC*16;
    const size_t base = ((size_t)ib*NCH*DIMC + dim)*16 + n;
    float a[6], b[6];
    float Al = 1.f, Bl = 0.f;
    #pragma unroll
    for (int j = 0; j < 6; j++){
        size_t o = base + (size_t)(lane*6 + j)*cstride;
        float A  = st[o];
        float Bv = st[o + 8];
        a[j] = A; b[j] = Bv;
        Bl = A*Bl + Bv;
        Al *= A;
    }
    #pragma unroll
    for (int off = 1; off < 64; off <<= 1){
        float Ao = __shfl_up(Al, off, 64);
        float Bo = __shfl_up(Bl, off, 64);
        if (lane >= off){
            Bl = Al*Bo + Bl;
            Al = Al*Ao;
        }
    }
    float h = __shfl_up(Bl, 1, 64);            // exclusive carry
    if (lane == 0) h = 0.f;
    #pragma unroll
    for (int j = 0; j < 6; j++){
        size_t o = base + (size_t)(lane*6 + j)*cstride;
        st[o] = h;
        h = a[j]*h + b[j];
    }
}

// ---------------------------------------------------------------- scan S3 (replay, y in place over dt)
// z arrives pre-activated (silu applied in k_inproj) -> y *= zv directly.
template<bool FAST>
__device__ __forceinline__ void scan3_body(unsigned short* __restrict__ dty,
    const unsigned short* __restrict__ sdt, const unsigned short* __restrict__ sxc,
    const unsigned short* __restrict__ sz, const float* __restrict__ sbc,
    const float* Av, float Dv, float* h,
    size_t rbase, size_t lbase, int d, int tid)
{
    #pragma unroll 8
    for (int s = 0; s < LC; s++){
        int r = d ? 31-s : s;
        float dtv = bf2f(sdt[r*128 + tid]);
        float uv  = bf2f(sxc[r*128 + tid]);
        float zv  = bf2f(sz [r*128 + tid]);
        float4 bA = *(const float4*)&sbc[r*16];
        float4 bB = *(const float4*)&sbc[r*16 + 4];
        float4 cA = *(const float4*)&sbc[r*16 + 8];
        float4 cB = *(const float4*)&sbc[r*16 + 12];
        float bv[8] = {bA.x,bA.y,bA.z,bA.w,bB.x,bB.y,bB.z,bB.w};
        float cv[8] = {cA.x,cA.y,cA.z,cA.w,cB.x,cB.y,cB.z,cB.w};
        float du = dtv*uv;
        float y = uv*Dv;
        float a[8];
        comp_a8<FAST>(dtv, Av, a);
        #pragma unroll
        for (int n = 0; n < 8; n++){
            h[n] = a[n]*h[n] + du*bv[n];
            y += h[n]*cv[n];
        }
        y *= zv;                      // zv = silu(z), precomputed in k_inproj
        dty[rbase + (lbase + r)*DIMC + tid] = f2bf(y);
    }
}

__global__ __launch_bounds__(128) void k_scan3(unsigned short* __restrict__ dty,
    const unsigned short* __restrict__ xc, const float* __restrict__ bcb,
    const unsigned short* __restrict__ xz, const float* __restrict__ st,
    const float* __restrict__ alog, const float* __restrict__ dvec)
{
    __shared__ __align__(16) unsigned short sdt[32*128];   // 8 KB
    __shared__ __align__(16) unsigned short sxc[32*128];   // 8 KB
    __shared__ __align__(16) unsigned short sz [32*128];   // 8 KB
    __shared__ __align__(16) float sbc[32*16];             // 2 KB
    const int ib = blockIdx.x & 7;
    const int c  = blockIdx.x >> 3;
    const int inst = ib >> 1, bb = ib & 1;
    const int m = inst >> 1, d = inst & 1;
    const int tid = threadIdx.x;
    const size_t rbase = (size_t)ib*LSEQ*DIMC;
    const size_t zbase = (size_t)bb*LSEQ*512 + m*256 + 128;
    const size_t lbase = d ? (size_t)(LSEQ - 32 - c*32) : (size_t)(c*32);
    #pragma unroll
    for (int p = 0; p < 4; p++){
        int idx = p*128 + tid;          // 512 uint4 per 8KB array
        int r = idx >> 4, g = (idx & 15)*8;
        size_t go = rbase + (lbase + r)*DIMC + g;
        *(uint4*)&sdt[r*128 + g] = *(const uint4*)&dty[go];
        *(uint4*)&sxc[r*128 + g] = *(const uint4*)&xc[go];
        *(uint4*)&sz [r*128 + g] = *(const uint4*)&xz[zbase + (lbase + r)*512 + g];
    }
    {   // bcb: 2KB = 128 x float4
        int r = tid >> 2, j = (tid & 3)*4;
        *(float4*)&sbc[r*16 + j] = *(const float4*)&bcb[((size_t)ib*LSEQ + lbase + r)*16 + j];
    }
    float Av[8];
    #pragma unroll
    for (int n = 0; n < 8; n++)
        Av[n] = -__expf(alog[((size_t)inst*DIMC + tid)*8 + n]);
    bool fast = true;
    #pragma unroll
    for (int n = 1; n < 8; n++)
        fast = fast && (fabsf(Av[n] - (float)(n+1)*Av[0]) <= 1e-5f*fabsf(Av[n]));
    const float Dv = dvec[inst*DIMC + tid];
    float h[8];
    const float* hp = st + (((size_t)ib*NCH + c)*DIMC + tid)*16;
    #pragma unroll
    for (int n = 0; n < 8; n++) h[n] = hp[n];
    __syncthreads();
    if (fast) scan3_body<true >(dty, sdt, sxc, sz, sbc, Av, Dv, h, rbase, lbase, d, tid);
    else      scan3_body<false>(dty, sdt, sxc, sz, sbc, Av, Dv, h, rbase, lbase, d, tid);
}

// ---------------------------------------------------------------- out_proj MFMA + diff + LN + add x + LN + T-store
// 32-row L-tiles, 128-thread blocks, grid (384,2) = 768 blocks (even 3/CU, was
// 384 blocks = 1.5/CU imbalanced). Each wave computes BOTH m-halves (acc[2][8])
// for its 16 rows so the diff stays wave-local. LDS 18.2KB -> 8 blocks/CU.
__global__ __launch_bounds__(128,4) void k_final(const unsigned short* __restrict__ y,
    const unsigned short* __restrict__ owb, const float* __restrict__ x, const float* __restrict__ lamp,
    const float* __restrict__ sw, const float* __restrict__ sb,
    const float* __restrict__ n2w, const float* __restrict__ n2b, float* __restrict__ outp)
{
    __shared__ __align__(16) char smem[18176];
    unsigned short* Ast = (unsigned short*)smem;             // [2*32][KP] = 16896 B
    float* yt            = (float*)smem;                     // [32][129] f32 = 16512 B (aliases Ast)
    float* red1          = (float*)(smem + 16896);           // 512 B
    float* red2          = (float*)(smem + 17408);           // 512 B
    float* stt           = (float*)(smem + 17920);           // 256 B
    const int bb = blockIdx.y;
    const int l0 = blockIdx.x * 32;                  // grid.x = 384
    const int tid = threadIdx.x;                     // 128 threads
    const float lam = *lamp;
    // stage y (fwd+bwd sum) for both m-halves: 2*32*16 = 1024 items / 128 thr = 8
    #pragma unroll
    for (int p = 0; p < 8; p++){
        int idx = p*128 + tid; int mm = idx >> 9; int li = (idx >> 4) & 31; int g = (idx & 15)*8;
        uint4 vf = *(const uint4*)&y[(((size_t)(mm*2+0)*NB + bb)*LSEQ + l0 + li)*DIMC + g];
        uint4 vb = *(const uint4*)&y[(((size_t)(mm*2+1)*NB + bb)*LSEQ + l0 + li)*DIMC + g];
        const unsigned short* uf = (const unsigned short*)&vf;
        const unsigned short* ub = (const unsigned short*)&vb;
        unsigned short o[8];
        #pragma unroll
        for (int j = 0; j < 8; j++) o[j] = f2bf(bf2f(uf[j]) + bf2f(ub[j]));
        *(uint2*)&Ast[(mm*32 + li)*KP + g]     = *(uint2*)&o[0];
        *(uint2*)&Ast[(mm*32 + li)*KP + g + 4] = *(uint2*)&o[4];
    }
    __syncthreads();
    const int lane = tid & 63, w = tid >> 6;         // w in {0,1}
    const int m15 = lane & 15, q = lane >> 4;
    f4_t zf = {0.f,0.f,0.f,0.f};
    f4_t acc[2][8];
    #pragma unroll
    for (int i = 0; i < 2; i++)
        #pragma unroll
        for (int j = 0; j < 8; j++) acc[i][j] = zf;
    #pragma unroll
    for (int ks = 0; ks < 4; ks++){
        int k0 = ks*32 + q*8;
        bf16x8 a0 = ld_frag8(&Ast[(     w*16 + m15)*KP + k0]);   // m=0 rows
        bf16x8 a1 = ld_frag8(&Ast[(32 + w*16 + m15)*KP + k0]);   // m=1 rows
        #pragma unroll
        for (int nt = 0; nt < 8; nt++){
            bf16x8 b0 = ld_frag16g(&owb[((size_t)0*DIMC + nt*16 + m15)*DIMC + k0]);
            bf16x8 b1 = ld_frag16g(&owb[((size_t)1*DIMC + nt*16 + m15)*DIMC + k0]);
            acc[0][nt] = __builtin_amdgcn_mfma_f32_16x16x32_bf16(a0, b0, acc[0][nt], 0,0,0);
            acc[1][nt] = __builtin_amdgcn_mfma_f32_16x16x32_bf16(a1, b1, acc[1][nt], 0,0,0);
        }
    }
    __syncthreads();
    #pragma unroll
    for (int nt = 0; nt < 8; nt++){
        int row = w*16 + q*4;
        int col = nt*16 + m15;
        #pragma unroll
        for (int i = 0; i < 4; i++)
            yt[(row+i)*129 + col] = acc[0][nt][i] - lam*acc[1][nt][i];
    }
    __syncthreads();
    // LN1 stats: r = tid>>2 (0..31), qg = tid&3 sums 32 cols each
    {
        int r = tid >> 2, qg = tid & 3;
        float s = 0.f, s2 = 0.f;
        #pragma unroll
        for (int j = 0; j < 32; j++){ float v = yt[r*129 + qg*32 + j]; s += v; s2 += v*v; }
        red1[qg*32 + r] = s; red2[qg*32 + r] = s2;
    }
    __syncthreads();
    if (tid < 32){
        float ss = 0.f, ss2 = 0.f;
        #pragma unroll
        for (int gg = 0; gg < 4; gg++){ ss += red1[gg*32 + tid]; ss2 += red2[gg*32 + tid]; }
        float mu = ss*(1.f/128.f);
        float var = ss2*(1.f/128.f) - mu*mu;
        stt[tid*2] = mu; stt[tid*2+1] = rsqrtf(var + EPSV);
    }
    __syncthreads();
    const int r = tid & 31, g = tid >> 5;            // g in 0..3, 32 cols each
    float mu1 = stt[r*2], rs1 = stt[r*2+1];
    float s = 0.f, s2 = 0.f;
    #pragma unroll
    for (int k = 0; k < 32; k++){
        int c = g*32 + k;
        float v = (yt[r*129+c] - mu1)*rs1*sw[c] + sb[c]
                + x[(size_t)bb*DIMC*LSEQ + (size_t)c*LSEQ + l0 + r];
        yt[r*129+c] = v;
        s += v; s2 += v*v;
    }
    __syncthreads();
    red1[g*32 + r] = s; red2[g*32 + r] = s2;
    __syncthreads();
    if (tid < 32){
        float ss = 0.f, ss2 = 0.f;
        #pragma unroll
        for (int gg = 0; gg < 4; gg++){ ss += red1[gg*32 + tid]; ss2 += red2[gg*32 + tid]; }
        float mu = ss*(1.f/128.f);
        float var = ss2*(1.f/128.f) - mu*mu;
        stt[tid*2] = mu; stt[tid*2+1] = rsqrtf(var + EPSV);
    }
    __syncthreads();
    float mu2 = stt[r*2], rs2 = stt[r*2+1];
    #pragma unroll
    for (int k = 0; k < 32; k++){
        int c = g*32 + k;
        float o = (yt[r*129+c] - mu2)*rs2*n2w[c] + n2b[c];
        outp[(size_t)bb*DIMC*LSEQ + (size_t)c*LSEQ + l0 + r] = o;
    }
}

// ----------------------------------------------------------------
extern "C" void kernel_launch(void* const* d_in, const int* in_sizes, int n_in,
                              void* d_out, int out_size, void* d_ws, size_t ws_size,
                              hipStream_t stream)
{
    const float* x    = (const float*)d_in[0];
    const float* n1w  = (const float*)d_in[1];
    const float* n1b  = (const float*)d_in[2];
    const float* n2w  = (const float*)d_in[3];
    const float* n2b  = (const float*)d_in[4];
    const float* slw  = (const float*)d_in[5];
    const float* slb  = (const float*)d_in[6];
    const float* lq   = (const float*)d_in[7];
    const float* wi   = (const float*)d_in[8];
    const float* cw   = (const float*)d_in[9];
    const float* cb   = (const float*)d_in[10];
    const float* xpw  = (const float*)d_in[11];
    const float* dtw  = (const float*)d_in[12];
    const float* dtb  = (const float*)d_in[13];
    const float* alog = (const float*)d_in[14];
    const float* dvec = (const float*)d_in[15];
    const float* ow   = (const float*)d_in[16];

    float* ws = (float*)d_ws;
    unsigned short* xz    = (unsigned short*)(ws + 1572864);   // 6,291,456 f
    unsigned short* xc    = (unsigned short*)(ws + 7864320);   // 6,291,456 f
    unsigned short* dty   = (unsigned short*)(ws + 14155776);  // 6,291,456 f
    float*          bcb   = ws + 20447232;                     // 1,572,864 f
    float*          st1   = ws + 22020096;                     // 6,291,456 f (8*NCH*128*16)
    unsigned short* wallb = (unsigned short*)(ws + 28311552);  //    36,864 f
    unsigned short* wib   = (unsigned short*)(ws + 28348416);  //    32,768 f
    unsigned short* owb   = (unsigned short*)(ws + 28381184);  //    16,384 f
    float*          lam   = ws + 28397568;                     //         1

    k_wall  <<<768, 128, 0, stream>>>(dtw, xpw, lq, wi, ow, wallb, lam, wib, owb);
    k_inproj<<<dim3(384, 2), 256, 0, stream>>>(x, n1w, n1b, wib, xz);
    k_xproj <<<dim3(192, 8), 256, 0, stream>>>(xz, wallb, dtb, alog, cw, cb, xc, dty, bcb, st1);
    k_scan2 <<<1024, 512, 0, stream>>>(st1);
    k_scan3 <<<8*NCH, 128, 0, stream>>>(dty, xc, bcb, xz, st1, alog, dvec);
    k_final <<<dim3(384, 2), 128, 0, stream>>>(dty, owb, x, lam, slw, slb, n2w, n2b, (float*)d_out);
}